// Round 17
// baseline (419.439 us; speedup 1.0000x reference)
//
#include <hip/hip_runtime.h>
#include <hip/hip_bf16.h>
#include <cstdint>
#include <cstddef>

constexpr int NF = 100000;
constexpr int NA = 400;
constexpr int NC = 30;
constexpr int NN = NF + NA + NC;     // 100430
constexpr int D  = 256;
constexpr int DD = D * D;            // 65536
constexpr int E  = 250000;
constexpr int NSL = 128;             // slices for r0/r2 counting sort

typedef __attribute__((ext_vector_type(8))) short bf16x8;
typedef __attribute__((ext_vector_type(4))) float f32x4;
typedef __attribute__((ext_vector_type(8))) ushort u16x8;

__device__ inline ushort f2bf(float f) {
    __hip_bfloat16 h = __float2bfloat16(f);
    return __builtin_bit_cast(ushort, h);
}
__device__ inline float bf2f(ushort u) {
    __hip_bfloat16 h = __builtin_bit_cast(__hip_bfloat16, u);
    return __bfloat162float(h);
}

// async global->LDS, 16B per lane: LDS dest = base + lane*16 (wave-linear)
__device__ inline void gload_lds16(const ushort* g, ushort* l) {
    __builtin_amdgcn_global_load_lds(
        (const __attribute__((address_space(1))) void*)g,
        (__attribute__((address_space(3))) void*)l, 16, 0, 0);
}

// ---------------- per-type encoders: h = relu(x @ W + b) -> bf16 ------------
template<int K, int ROWS>
__global__ __launch_bounds__(256) void encode_kernel(
    const float* __restrict__ x, const float* __restrict__ W,
    const float* __restrict__ b, ushort* __restrict__ hH,
    int rows, int row_off)
{
    int c = threadIdx.x;
    int base = blockIdx.x * ROWS;
    float wcol[K];
    #pragma unroll
    for (int k = 0; k < K; ++k) wcol[k] = W[k * D + c];
    float bias = b[c];
    for (int i = 0; i < ROWS; ++i) {
        int row = base + i;
        if (row >= rows) return;
        const float* xr = x + (size_t)row * K;
        float acc = bias;
        #pragma unroll
        for (int k = 0; k < K; ++k) acc += xr[k] * wcol[k];
        hH[(size_t)(row_off + row) * D + c] = f2bf(fmaxf(acc, 0.f));
    }
}

// ---------------- weight split+transpose: root[k][n] -> WtH/WtL[n][k] -------
__global__ __launch_bounds__(256) void wsplit_kernel(
    const float* __restrict__ root, ushort* __restrict__ WtH, ushort* __restrict__ WtL)
{
    int n = blockIdx.x, k = threadIdx.x;
    float w = root[(size_t)k * D + n];
    ushort hi = f2bf(w);
    WtH[(size_t)n * D + k] = hi;
    WtL[(size_t)n * D + k] = f2bf(w - bf2f(hi));
}

// ---------------- basis combine: Wr[r] = sum_b comp[r,b] * basis[b] ---------
__global__ __launch_bounds__(256) void wr_kernel(
    const float* __restrict__ basis, const float* __restrict__ comp,
    float* __restrict__ wr)
{
    int idx = blockIdx.x * 256 + threadIdx.x;   // < 4*DD
    int r = idx >> 16;
    int io = idx & (DD - 1);
    wr[idx] = comp[r * 3 + 0] * basis[io]
            + comp[r * 3 + 1] * basis[DD + io]
            + comp[r * 3 + 2] * basis[2 * DD + io];
}

// ---------------- r1/r3 degree count (low contention: 100K dsts) ----------
__global__ __launch_bounds__(256) void deg_count_kernel(
    const int* __restrict__ dst1, const int* __restrict__ dst3,
    int* __restrict__ deg1, int* __restrict__ deg3)
{
    int idx = blockIdx.x * 256 + threadIdx.x;
    if (idx >= 2 * E) return;
    if (idx < E) atomicAdd(&deg1[dst1[idx]], 1);
    else         atomicAdd(&deg3[dst3[idx - E]], 1);
}

// ---------------- r0/r2: per-slice LDS histograms (contention-free) --------
__global__ __launch_bounds__(256) void hist02_kernel(
    const int* __restrict__ dst0, const int* __restrict__ dst2,
    int* __restrict__ bh0, int* __restrict__ bh2)
{
    __shared__ int hist[NA];
    int b = blockIdx.x;                 // 0..2*NSL-1
    bool isR2 = (b >= NSL);
    int sl = isR2 ? b - NSL : b;
    const int* dst = isR2 ? dst2 : dst0;
    int nb = isR2 ? NC : NA;
    for (int i = threadIdx.x; i < nb; i += 256) hist[i] = 0;
    __syncthreads();
    int lo = (int)((long long)E * sl / NSL);
    int hi = (int)((long long)E * (sl + 1) / NSL);
    for (int e = lo + threadIdx.x; e < hi; e += 256)
        atomicAdd(&hist[dst[e]], 1);
    __syncthreads();
    int* bh = isR2 ? (bh2 + sl * NC) : (bh0 + sl * NA);
    for (int i = threadIdx.x; i < nb; i += 256) bh[i] = hist[i];
}

// -------- scan: per-bin over slices + cross-bin; emits rp/inv + abs offsets -
__global__ __launch_bounds__(512) void scan02_kernel(
    int* __restrict__ bh0, int* __restrict__ bh2,
    int* __restrict__ rp0, int* __restrict__ rp2,
    float* __restrict__ inv0, float* __restrict__ inv2)
{
    __shared__ int tot[512];
    __shared__ int exc[512];
    int t = threadIdx.x;
    int cnt = 0;
    if (t < NA) {
        int s = 0;
        for (int sl = 0; sl < NSL; ++sl) {
            int v = bh0[sl * NA + t]; bh0[sl * NA + t] = s; s += v;
        }
        cnt = s;
    } else if (t < NA + NC) {
        int bin = t - NA; int s = 0;
        for (int sl = 0; sl < NSL; ++sl) {
            int v = bh2[sl * NC + bin]; bh2[sl * NC + bin] = s; s += v;
        }
        cnt = s;
    }
    tot[t] = cnt;
    __syncthreads();
    for (int ofs = 1; ofs < 512; ofs <<= 1) {
        int v = (t >= ofs) ? tot[t - ofs] : 0;
        __syncthreads();
        tot[t] += v;
        __syncthreads();
    }
    int ex = tot[t] - cnt;              // exclusive over combined [r0 | r2]
    if (t < NA) {
        exc[t] = ex;
        rp0[t] = ex;
        inv0[t] = 1.0f / (float)(cnt > 1 ? cnt : 1);
        if (t == 0) { rp0[NA] = E; rp2[NC] = E; }
    } else if (t < NA + NC) {
        exc[t] = ex - E;                // r2 csr buffer is its own array
        rp2[t - NA] = ex - E;
        inv2[t - NA] = 1.0f / (float)(cnt > 1 ? cnt : 1);
    } else exc[t] = 0;
    __syncthreads();
    for (int idx = t; idx < NSL * NA; idx += 512) {
        int sl = idx / NA; int bin = idx - sl * NA;
        bh0[idx] += exc[bin];
    }
    for (int idx = t; idx < NSL * NC; idx += 512) {
        int sl = idx / NC; int bin = idx - sl * NC;
        bh2[idx] += exc[NA + bin];
    }
}

// ---------------- r0/r2 CSR fill with LDS cursors --------------------------
__global__ __launch_bounds__(256) void fill02_kernel(
    const int* __restrict__ src0, const int* __restrict__ dst0,
    const int* __restrict__ src2, const int* __restrict__ dst2,
    const int* __restrict__ bh0, const int* __restrict__ bh2,
    int* __restrict__ csr0, int* __restrict__ csr2)
{
    __shared__ int cur[NA];
    int b = blockIdx.x;
    bool isR2 = (b >= NSL);
    int sl = isR2 ? b - NSL : b;
    const int* src = isR2 ? src2 : src0;
    const int* dst = isR2 ? dst2 : dst0;
    const int* bh  = isR2 ? (bh2 + sl * NC) : (bh0 + sl * NA);
    int* csr       = isR2 ? csr2 : csr0;
    int nb = isR2 ? NC : NA;
    for (int i = threadIdx.x; i < nb; i += 256) cur[i] = bh[i];
    __syncthreads();
    int lo = (int)((long long)E * sl / NSL);
    int hi = (int)((long long)E * (sl + 1) / NSL);
    for (int e = lo + threadIdx.x; e < hi; e += 256) {
        int pos = atomicAdd(&cur[dst[e]], 1);
        csr[pos] = src[e];
    }
}

// ---------------- r1/r3 scan chain -----------------------------------------
__global__ __launch_bounds__(1024) void scanA_kernel(
    const int* __restrict__ deg1, const int* __restrict__ deg3, int* __restrict__ bsum)
{
    __shared__ int s[1024];
    int b = blockIdx.x;                    // 0..195
    bool isR3 = (b >= 98);
    const int* deg = isR3 ? deg3 : deg1;
    int chunk = isR3 ? b - 98 : b;
    int i = chunk * 1024 + threadIdx.x;
    int v = (i < NF) ? deg[i] : 0;
    s[threadIdx.x] = v;
    __syncthreads();
    for (int ofs = 512; ofs > 0; ofs >>= 1) {
        if ((int)threadIdx.x < ofs) s[threadIdx.x] += s[threadIdx.x + ofs];
        __syncthreads();
    }
    if (threadIdx.x == 0) bsum[(isR3 ? 128 : 0) + chunk] = s[0];
}

__global__ __launch_bounds__(256) void scanB_kernel(int* __restrict__ bsum)
{
    __shared__ int s[256];
    int t = threadIdx.x;
    int v = ((t & 127) < 98) ? bsum[t] : 0;
    s[t] = v;
    __syncthreads();
    for (int ofs = 1; ofs < 128; ofs <<= 1) {
        int a = ((t & 127) >= ofs) ? s[t - ofs] : 0;
        __syncthreads();
        s[t] += a;
        __syncthreads();
    }
    bsum[t] = s[t] - v;   // exclusive (segmented per 128-half)
}

__global__ __launch_bounds__(1024) void scanC_kernel(
    const int* __restrict__ deg1, const int* __restrict__ deg3,
    const int* __restrict__ bsum,
    int* __restrict__ rp1, int* __restrict__ rp3,
    int* __restrict__ cu1, int* __restrict__ cu3,
    float* __restrict__ inv1, float* __restrict__ inv3)
{
    __shared__ int s[1024];
    int b = blockIdx.x;                    // 0..195
    const int* deg; int* rp; int* cu; float* inv; int chunk; int prefix;
    if (b < 98) { deg = deg1; rp = rp1; cu = cu1; inv = inv1; chunk = b;      prefix = bsum[chunk]; }
    else        { deg = deg3; rp = rp3; cu = cu3; inv = inv3; chunk = b - 98; prefix = bsum[128 + chunk]; }
    int tid = threadIdx.x;
    int i = chunk * 1024 + tid;
    int v = (i < NF) ? deg[i] : 0;
    s[tid] = v;
    __syncthreads();
    for (int ofs = 1; ofs < 1024; ofs <<= 1) {
        int a = (tid >= ofs) ? s[tid - ofs] : 0;
        __syncthreads();
        s[tid] += a;
        __syncthreads();
    }
    int ex = prefix + s[tid] - v;
    if (i < NF) {
        rp[i] = ex;
        cu[i] = ex;
        inv[i] = 1.0f / (float)(v > 1 ? v : 1);
    }
    if (i == 0) rp[NF] = E;
}

__global__ __launch_bounds__(256) void csr_fill13_kernel(
    const int* __restrict__ src1, const int* __restrict__ dst1,
    const int* __restrict__ src3, const int* __restrict__ dst3,
    int* __restrict__ cu1, int* __restrict__ cu3,
    int* __restrict__ csr1, int* __restrict__ csr3)
{
    int idx = blockIdx.x * 256 + threadIdx.x;
    if (idx >= 2 * E) return;
    if (idx < E) {
        int pos = atomicAdd(&cu1[dst1[idx]], 1);
        csr1[pos] = src1[idx];
    } else {
        int e = idx - E;
        int pos = atomicAdd(&cu3[dst3[e]], 1);
        csr3[pos] = src3[e];
    }
}

// ------- y = h[src-type rows] @ Wr[rel]  (Wr precomputed) -------------------
__global__ __launch_bounds__(256) void y_kernel(
    const ushort* __restrict__ hH, const float* __restrict__ wr,
    float* __restrict__ y)
{
    int row = blockIdx.x;            // 0..429  (airports then carriers)
    int c = threadIdx.x;
    const ushort* sH = hH + (size_t)(NF + row) * D;
    const float* W = wr + (size_t)((row < NA) ? 1 : 3) * DD;
    float acc = 0.f;
    #pragma unroll 8
    for (int k = 0; k < D; ++k) acc += bf2f(sH[k]) * W[k * D + c];
    y[(size_t)row * D + c] = acc;
}

// ---- bf16 MFMA GEMM: G = A @ root^T + bias (A single-plane, W split) ------
// 8 waves, 64x32 sub-tiles, fragment-major global_load_lds staging, 3-buffer
// pipeline with COUNTED vmcnt (never drains): 2 stages stay in flight across
// every barrier, so per-iteration exposed latency ~0 and memory stays busy.
__global__ __launch_bounds__(512) void gemm_mfma(
    const ushort* __restrict__ A,
    const ushort* __restrict__ WtH, const ushort* __restrict__ WtL,
    const float* __restrict__ bias,
    ushort* __restrict__ G, int nrows)
{
    constexpr int BM = 128, BK = 32;
    constexpr int PLANE = BM * BK;          // 4096 ushorts = 8 KB
    constexpr int BUF = 3 * PLANE;          // 12288 ushorts = 24 KB
    constexpr int LDW = 36;                 // fp32 epilogue scratch stride
    __shared__ __align__(16) ushort lds[3 * BUF];   // 73728 B (3 buffers)
    const int t = threadIdx.x;
    const int row0 = blockIdx.x * BM;
    const int col0 = blockIdx.y * BM;
    const int w = t >> 6, lane = t & 63;    // 8 waves
    const int wm = w >> 2, wn = w & 3;      // 2x4 wave grid, 64x32 per wave
    const int lr = lane & 15;
    const int lk = lane >> 4;
    f32x4 acc[4][2] = {};

    // staging: 24 (plane,group) units, wave w handles 3 consecutive
    const ushort* sp[3];
    int dofs[3];
    #pragma unroll
    for (int i = 0; i < 3; ++i) {
        int idx = w * 3 + i;
        int plane = idx >> 3, g = idx & 7;
        const ushort* base = (plane == 0) ? A : (plane == 1) ? WtH : WtL;
        int r = ((plane == 0) ? row0 : col0) + g * 16 + lr;
        if (plane == 0 && r >= nrows) r = nrows - 1;
        sp[i] = base + (size_t)r * D + lk * 8;
        dofs[i] = plane * PLANE + g * 512;
    }

    auto stage = [&](int kt, int buf) {
        ushort* bb = lds + buf * BUF;
        int k0 = kt * BK;
        #pragma unroll
        for (int i = 0; i < 3; ++i)
            gload_lds16(sp[i] + k0, bb + dofs[i]);
    };
    auto compute = [&](int buf) {
        const ushort* base = lds + buf * BUF;
        const ushort* As  = base;
        const ushort* WsH = base + PLANE;
        const ushort* WsL = base + 2 * PLANE;
        bf16x8 bh[2], bl[2];
        #pragma unroll
        for (int ni = 0; ni < 2; ++ni) {
            int off = (wn * 2 + ni) * 512 + lane * 8;
            bh[ni] = *(const bf16x8*)(&WsH[off]);
            bl[ni] = *(const bf16x8*)(&WsL[off]);
        }
        #pragma unroll
        for (int mi = 0; mi < 4; ++mi) {
            int off = (wm * 4 + mi) * 512 + lane * 8;
            bf16x8 ah = *(const bf16x8*)(&As[off]);
            #pragma unroll
            for (int ni = 0; ni < 2; ++ni) {
                acc[mi][ni] = __builtin_amdgcn_mfma_f32_16x16x32_bf16(ah, bh[ni], acc[mi][ni], 0, 0, 0);
                acc[mi][ni] = __builtin_amdgcn_mfma_f32_16x16x32_bf16(ah, bl[ni], acc[mi][ni], 0, 0, 0);
            }
        }
    };

    // prologue: 3 stages in flight (9 loads/wave)
    stage(0, 0);
    stage(1, 1);
    stage(2, 2);
    // PEND = 3 * (#stages still allowed in flight when computing KT)
#define PIPE_ITER(KT, PEND)                                        \
    asm volatile("s_waitcnt vmcnt(" #PEND ")" ::: "memory");       \
    __builtin_amdgcn_s_barrier();                                  \
    __builtin_amdgcn_sched_barrier(0);                             \
    compute((KT) % 3);                                             \
    __builtin_amdgcn_s_barrier();                                  \
    __builtin_amdgcn_sched_barrier(0);                             \
    if ((KT) + 3 < 8) stage((KT) + 3, (KT) % 3);
    PIPE_ITER(0, 6)
    PIPE_ITER(1, 6)
    PIPE_ITER(2, 6)
    PIPE_ITER(3, 6)
    PIPE_ITER(4, 6)
    PIPE_ITER(5, 6)
    PIPE_ITER(6, 3)
    PIPE_ITER(7, 0)
#undef PIPE_ITER

    // ---- epilogue: per-mi 16x32 pass through LDS, coalesced 16B stores -----
    __syncthreads();                         // everyone done with buffers
    float* S = (float*)lds + (size_t)w * 16 * LDW;   // per-wave 16x36 fp32
    const int rrow = lane >> 2;            // 0..15 read-back row
    const int grp  = lane & 3;             // col octet (8 bf16)
    #pragma unroll
    for (int mi = 0; mi < 4; ++mi) {
        __syncthreads();
        #pragma unroll
        for (int ni = 0; ni < 2; ++ni)
            #pragma unroll
            for (int reg = 0; reg < 4; ++reg)
                S[(lk * 4 + reg) * LDW + ni * 16 + lr] = acc[mi][ni][reg];
        __syncthreads();
        int gr = row0 + wm * 64 + mi * 16 + rrow;
        int gc = col0 + wn * 32 + grp * 8;
        if (gr >= nrows) continue;
        float4 f0 = *(const float4*)(&S[rrow * LDW + grp * 8]);
        float4 f1 = *(const float4*)(&S[rrow * LDW + grp * 8 + 4]);
        float4 b0 = *(const float4*)(bias + gc);
        float4 b1 = *(const float4*)(bias + gc + 4);
        float v[8] = {f0.x + b0.x, f0.y + b0.y, f0.z + b0.z, f0.w + b0.w,
                      f1.x + b1.x, f1.y + b1.y, f1.z + b1.z, f1.w + b1.w};
        u16x8 hh;
        #pragma unroll
        for (int j = 0; j < 8; ++j) hh[j] = f2bf(v[j]);
        *(u16x8*)(G + (size_t)gr * D + gc) = hh;
    }
}

// ---- layer-0 flight rows: G = relu(G + inv1*Σy1 + inv3*Σy3) in place ------
// 4 rows per wave (16 lanes x 16 ch each): 4 independent edge-walk chains.
__global__ __launch_bounds__(256) void msg_relu_kernel(
    ushort* __restrict__ G,
    const float* __restrict__ y,
    const int* __restrict__ rp1, const int* __restrict__ csr1, const float* __restrict__ inv1,
    const int* __restrict__ rp3, const int* __restrict__ csr3, const float* __restrict__ inv3)
{
    int wid = (blockIdx.x * 256 + threadIdx.x) >> 6;
    int lane = threadIdx.x & 63;
    int row = wid * 4 + (lane >> 4);
    if (row >= NF) return;
    int c = (lane & 15) * 16;
    size_t o = (size_t)row * D + c;
    u16x8 g0 = *(const u16x8*)(G + o);
    u16x8 g1 = *(const u16x8*)(G + o + 8);
    float v[16];
    #pragma unroll
    for (int j = 0; j < 8; ++j) { v[j] = bf2f(g0[j]); v[8 + j] = bf2f(g1[j]); }
    float m[16] = {};
    int e0 = rp1[row], e1 = rp1[row + 1];
    for (int e = e0; e < e1; ++e) {
        const float* yr = y + (size_t)csr1[e] * D + c;
        #pragma unroll
        for (int q = 0; q < 4; ++q) {
            float4 u = *(const float4*)(yr + q * 4);
            m[q * 4 + 0] += u.x; m[q * 4 + 1] += u.y;
            m[q * 4 + 2] += u.z; m[q * 4 + 3] += u.w;
        }
    }
    float s1 = inv1[row];
    #pragma unroll
    for (int j = 0; j < 16; ++j) { v[j] += s1 * m[j]; m[j] = 0.f; }
    e0 = rp3[row]; e1 = rp3[row + 1];
    for (int e = e0; e < e1; ++e) {
        const float* yr = y + (size_t)(NA + csr3[e]) * D + c;
        #pragma unroll
        for (int q = 0; q < 4; ++q) {
            float4 u = *(const float4*)(yr + q * 4);
            m[q * 4 + 0] += u.x; m[q * 4 + 1] += u.y;
            m[q * 4 + 2] += u.z; m[q * 4 + 3] += u.w;
        }
    }
    float s3 = inv3[row];
    u16x8 o0, o1;
    #pragma unroll
    for (int j = 0; j < 8; ++j) {
        o0[j] = f2bf(fmaxf(v[j] + s3 * m[j], 0.f));
        o1[j] = f2bf(fmaxf(v[8 + j] + s3 * m[8 + j], 0.f));
    }
    *(u16x8*)(G + o) = o0;
    *(u16x8*)(G + o + 8) = o1;
}

// ---- layer-1: out[f] = relu(G2+msgs) . W_out + b_out (fused readout) -------
__global__ __launch_bounds__(256) void msg_readout_kernel(
    const ushort* __restrict__ G,
    const float* __restrict__ y,
    const int* __restrict__ rp1, const int* __restrict__ csr1, const float* __restrict__ inv1,
    const int* __restrict__ rp3, const int* __restrict__ csr3, const float* __restrict__ inv3,
    const float* __restrict__ wout, const float* __restrict__ bout,
    float* __restrict__ out)
{
    int wid = (blockIdx.x * 256 + threadIdx.x) >> 6;
    int lane = threadIdx.x & 63;
    int row = wid * 4 + (lane >> 4);
    if (row >= NF) return;
    int c = (lane & 15) * 16;
    size_t o = (size_t)row * D + c;
    u16x8 g0 = *(const u16x8*)(G + o);
    u16x8 g1 = *(const u16x8*)(G + o + 8);
    float v[16];
    #pragma unroll
    for (int j = 0; j < 8; ++j) { v[j] = bf2f(g0[j]); v[8 + j] = bf2f(g1[j]); }
    float m[16] = {};
    int e0 = rp1[row], e1 = rp1[row + 1];
    for (int e = e0; e < e1; ++e) {
        const float* yr = y + (size_t)csr1[e] * D + c;
        #pragma unroll
        for (int q = 0; q < 4; ++q) {
            float4 u = *(const float4*)(yr + q * 4);
            m[q * 4 + 0] += u.x; m[q * 4 + 1] += u.y;
            m[q * 4 + 2] += u.z; m[q * 4 + 3] += u.w;
        }
    }
    float s1 = inv1[row];
    #pragma unroll
    for (int j = 0; j < 16; ++j) { v[j] += s1 * m[j]; m[j] = 0.f; }
    e0 = rp3[row]; e1 = rp3[row + 1];
    for (int e = e0; e < e1; ++e) {
        const float* yr = y + (size_t)(NA + csr3[e]) * D + c;
        #pragma unroll
        for (int q = 0; q < 4; ++q) {
            float4 u = *(const float4*)(yr + q * 4);
            m[q * 4 + 0] += u.x; m[q * 4 + 1] += u.y;
            m[q * 4 + 2] += u.z; m[q * 4 + 3] += u.w;
        }
    }
    float s3 = inv3[row];
    float pr = 0.f;
    #pragma unroll
    for (int q = 0; q < 4; ++q) {
        float4 wq = *(const float4*)(wout + c + q * 4);
        pr += fmaxf(v[q*4+0] + s3 * m[q*4+0], 0.f) * wq.x
            + fmaxf(v[q*4+1] + s3 * m[q*4+1], 0.f) * wq.y
            + fmaxf(v[q*4+2] + s3 * m[q*4+2], 0.f) * wq.z
            + fmaxf(v[q*4+3] + s3 * m[q*4+3], 0.f) * wq.w;
    }
    pr += __shfl_xor(pr, 1);
    pr += __shfl_xor(pr, 2);
    pr += __shfl_xor(pr, 4);
    pr += __shfl_xor(pr, 8);
    if ((lane & 15) == 0) out[row] = pr + bout[0];
}

// ---- r0/r2: agg[dst] += hH[src] — 2 edges per wave, 16B/lane loads ---------
__global__ __launch_bounds__(256) void agg_small_kernel(
    const ushort* __restrict__ hH,
    const int* __restrict__ rp0, const int* __restrict__ csr0,
    const int* __restrict__ rp2, const int* __restrict__ csr2,
    float* __restrict__ agg)
{
    __shared__ float red[4][256];
    int b = blockIdx.x;
    const int* rp; const int* csr; int dstn, chunk, nch; float* arow;
    if (b < NA * 4) { dstn = b >> 2; chunk = b & 3; nch = 4;  rp = rp0; csr = csr0; arow = agg + (size_t)dstn * D; }
    else { int bb = b - NA * 4; dstn = bb >> 6; chunk = bb & 63; nch = 64; rp = rp2; csr = csr2; arow = agg + (size_t)(NA + dstn) * D; }
    int s = rp[dstn], e = rp[dstn + 1];
    int cnt = e - s;
    int lo = s + (int)((long long)cnt * chunk / nch);
    int hi = s + (int)((long long)cnt * (chunk + 1) / nch);
    int w = threadIdx.x >> 6, lane = threadIdx.x & 63;
    int span = hi - lo;
    int wlo = lo + (int)((long long)span * w / 4);
    int whi = lo + (int)((long long)span * (w + 1) / 4);
    int half = lane >> 5;                  // 0: edge p, 1: edge p+1
    int ch8 = (lane & 31) * 8;
    float acc[8] = {};
    int p = wlo;
    for (; p + 1 < whi; p += 2) {
        int r = csr[p + half];
        u16x8 v = *(const u16x8*)(hH + (size_t)r * D + ch8);
        #pragma unroll
        for (int j = 0; j < 8; ++j) acc[j] += bf2f(v[j]);
    }
    if (p < whi && half == 0) {
        int r = csr[p];
        u16x8 v = *(const u16x8*)(hH + (size_t)r * D + ch8);
        #pragma unroll
        for (int j = 0; j < 8; ++j) acc[j] += bf2f(v[j]);
    }
    #pragma unroll
    for (int j = 0; j < 8; ++j) acc[j] += __shfl_xor(acc[j], 32);
    if (lane < 32) {
        #pragma unroll
        for (int j = 0; j < 8; ++j) red[w][ch8 + j] = acc[j];
    }
    __syncthreads();
    int c = threadIdx.x;
    float total = red[0][c] + red[1][c] + red[2][c] + red[3][c];
    atomicAdd(arow + c, total);
}

// -- r0/r2 transform: G = relu(G + inv_deg*(agg @ Wr[rel])) in place ---------
__global__ __launch_bounds__(256) void smallT_kernel(
    const float* __restrict__ agg, const float* __restrict__ wr,
    const float* __restrict__ inv0, const float* __restrict__ inv2,
    ushort* __restrict__ G)
{
    int row = blockIdx.x;            // 0..429
    int c = threadIdx.x;
    const float* a = agg + (size_t)row * D;
    const float* W = wr + (size_t)((row < NA) ? 0 : 2) * DD;
    float scale = (row < NA) ? inv0[row] : inv2[row - NA];
    float acc = 0.f;
    #pragma unroll 8
    for (int k = 0; k < D; ++k) acc += a[k] * W[k * D + c];
    size_t o = (size_t)(NF + row) * D + c;
    G[o] = f2bf(fmaxf(bf2f(G[o]) + scale * acc, 0.f));
}

extern "C" void kernel_launch(void* const* d_in, const int* in_sizes, int n_in,
                              void* d_out, int out_size, void* d_ws, size_t ws_size,
                              hipStream_t stream)
{
    const float* xf = (const float*)d_in[0];
    const float* xa = (const float*)d_in[1];
    const float* xc = (const float*)d_in[2];
    const float* Wf = (const float*)d_in[3];
    const float* bf = (const float*)d_in[4];
    const float* Wa = (const float*)d_in[5];
    const float* ba = (const float*)d_in[6];
    const float* Wc = (const float*)d_in[7];
    const float* bc = (const float*)d_in[8];
    const float* basis0 = (const float*)d_in[9];
    const float* comp0  = (const float*)d_in[10];
    const float* root0  = (const float*)d_in[11];
    const float* bias0  = (const float*)d_in[12];
    const float* basis1 = (const float*)d_in[13];
    const float* comp1  = (const float*)d_in[14];
    const float* root1  = (const float*)d_in[15];
    const float* bias1  = (const float*)d_in[16];
    const float* Wout = (const float*)d_in[17];
    const float* bout = (const float*)d_in[18];
    const int* src0 = (const int*)d_in[19];
    const int* dst0 = (const int*)d_in[20];
    const int* src1 = (const int*)d_in[21];
    const int* dst1 = (const int*)d_in[22];
    const int* src2 = (const int*)d_in[23];
    const int* dst2 = (const int*)d_in[24];
    const int* src3 = (const int*)d_in[25];
    const int* dst3 = (const int*)d_in[26];
    float* out = (float*)d_out;

    char* ws = (char*)d_ws;
    size_t off = 0;
    auto alloc = [&](size_t bytes) -> char* {
        char* p = ws + off;
        off = (off + bytes + 255) & ~(size_t)255;
        return p;
    };
    ushort* hH  = (ushort*)alloc((size_t)NN * D * 2);
    ushort* gH  = (ushort*)alloc((size_t)NN * D * 2);
    // layer-1 GEMM output reuses hH (dead after layer-0 consumers)
    ushort* g2H = hH;
    ushort* WtH = (ushort*)alloc((size_t)DD * 2);
    ushort* WtL = (ushort*)alloc((size_t)DD * 2);
    float* wrbuf  = (float*)alloc((size_t)4 * DD * 4);
    float* ybuf   = (float*)alloc((size_t)(NA + NC) * D * 4);
    float* aggbuf = (float*)alloc((size_t)(NA + NC) * D * 4);
    int*   deg13  = (int*)  alloc((size_t)2 * NF * 4);
    int* deg1 = deg13; int* deg3 = deg13 + NF;
    float* inv1 = (float*)alloc((size_t)NF * 4);
    float* inv3 = (float*)alloc((size_t)NF * 4);
    float* inv0 = (float*)alloc((size_t)NA * 4);
    float* inv2 = (float*)alloc((size_t)NC * 4);
    int* rp0 = (int*)alloc((NA + 1) * 4);
    int* rp1 = (int*)alloc((size_t)(NF + 1) * 4);
    int* rp2 = (int*)alloc((NC + 1) * 4);
    int* rp3 = (int*)alloc((size_t)(NF + 1) * 4);
    int* cu1 = (int*)alloc((size_t)(NF + 1) * 4);
    int* cu3 = (int*)alloc((size_t)(NF + 1) * 4);
    int* csr0 = (int*)alloc((size_t)E * 4);
    int* csr1 = (int*)alloc((size_t)E * 4);
    int* csr2 = (int*)alloc((size_t)E * 4);
    int* csr3 = (int*)alloc((size_t)E * 4);
    int* bsum = (int*)alloc(256 * 4);
    int* bh0  = (int*)alloc((size_t)NSL * NA * 4);
    int* bh2  = (int*)alloc((size_t)NSL * NC * 4);
    (void)ws_size; (void)in_sizes; (void)n_in; (void)out_size;

    // ---- CSR build: r0/r2 via contention-free counting sort
    hist02_kernel<<<2 * NSL, 256, 0, stream>>>(dst0, dst2, bh0, bh2);
    scan02_kernel<<<1, 512, 0, stream>>>(bh0, bh2, rp0, rp2, inv0, inv2);
    fill02_kernel<<<2 * NSL, 256, 0, stream>>>(src0, dst0, src2, dst2, bh0, bh2, csr0, csr2);

    // ---- CSR build: r1/r3 via atomics (100K dsts, avg degree 2.5 — cheap)
    hipMemsetAsync(deg13, 0, (size_t)2 * NF * 4, stream);
    deg_count_kernel<<<(2 * E + 255) / 256, 256, 0, stream>>>(dst1, dst3, deg1, deg3);
    scanA_kernel<<<196, 1024, 0, stream>>>(deg1, deg3, bsum);
    scanB_kernel<<<1, 256, 0, stream>>>(bsum);
    scanC_kernel<<<196, 1024, 0, stream>>>(deg1, deg3, bsum, rp1, rp3, cu1, cu3, inv1, inv3);
    csr_fill13_kernel<<<(2 * E + 255) / 256, 256, 0, stream>>>(
        src1, dst1, src3, dst3, cu1, cu3, csr1, csr3);

    // ---- encoders (single bf16 plane)
    encode_kernel<32, 8><<<NF / 8, 256, 0, stream>>>(xf, Wf, bf, hH, NF, 0);
    encode_kernel<16, 8><<<(NA + 7) / 8, 256, 0, stream>>>(xa, Wa, ba, hH, NA, NF);
    encode_kernel<8, 8><<<(NC + 7) / 8, 256, 0, stream>>>(xc, Wc, bc, hH, NC, NF + NA);

    // ---- layer 0: pure MFMA gemm -> G; then per-row-type finishers in place
    wsplit_kernel<<<D, D, 0, stream>>>(root0, WtH, WtL);
    wr_kernel<<<4 * DD / 256, 256, 0, stream>>>(basis0, comp0, wrbuf);
    y_kernel<<<NA + NC, 256, 0, stream>>>(hH, wrbuf, ybuf);
    gemm_mfma<<<dim3((NN + 127) / 128, 2), 512, 0, stream>>>(
        hH, WtH, WtL, bias0, gH, NN);
    hipMemsetAsync(aggbuf, 0, (size_t)(NA + NC) * D * 4, stream);
    agg_small_kernel<<<NA * 4 + NC * 64, 256, 0, stream>>>(
        hH, rp0, csr0, rp2, csr2, aggbuf);
    smallT_kernel<<<NA + NC, 256, 0, stream>>>(aggbuf, wrbuf, inv0, inv2, gH);
    msg_relu_kernel<<<(NF / 4 * 64 + 255) / 256, 256, 0, stream>>>(
        gH, ybuf, rp1, csr1, inv1, rp3, csr3, inv3);

    // ---- layer 1 (flights only): pure gemm -> G2 (aliases h); readout -> out
    wsplit_kernel<<<D, D, 0, stream>>>(root1, WtH, WtL);
    wr_kernel<<<4 * DD / 256, 256, 0, stream>>>(basis1, comp1, wrbuf);
    y_kernel<<<NA + NC, 256, 0, stream>>>(gH, wrbuf, ybuf);
    gemm_mfma<<<dim3((NF + 127) / 128, 2), 512, 0, stream>>>(
        gH, WtH, WtL, bias1, g2H, NF);
    msg_readout_kernel<<<(NF / 4 * 64 + 255) / 256, 256, 0, stream>>>(
        g2H, ybuf, rp1, csr1, inv1, rp3, csr3, inv3, Wout, bout, out);
}

// Round 18
// 397.619 us; speedup vs baseline: 1.0549x; 1.0549x over previous
//
#include <hip/hip_runtime.h>
#include <hip/hip_bf16.h>
#include <cstdint>
#include <cstddef>

constexpr int NF = 100000;
constexpr int NA = 400;
constexpr int NC = 30;
constexpr int NN = NF + NA + NC;     // 100430
constexpr int D  = 256;
constexpr int DD = D * D;            // 65536
constexpr int E  = 250000;
constexpr int NSL = 128;             // slices for r0/r2 counting sort

typedef __attribute__((ext_vector_type(8))) short bf16x8;
typedef __attribute__((ext_vector_type(4))) float f32x4;
typedef __attribute__((ext_vector_type(8))) ushort u16x8;

__device__ inline ushort f2bf(float f) {
    __hip_bfloat16 h = __float2bfloat16(f);
    return __builtin_bit_cast(ushort, h);
}
__device__ inline float bf2f(ushort u) {
    __hip_bfloat16 h = __builtin_bit_cast(__hip_bfloat16, u);
    return __bfloat162float(h);
}

// async global->LDS, 16B per lane: LDS dest = base + lane*16 (wave-linear)
__device__ inline void gload_lds16(const ushort* g, ushort* l) {
    __builtin_amdgcn_global_load_lds(
        (const __attribute__((address_space(1))) void*)g,
        (__attribute__((address_space(3))) void*)l, 16, 0, 0);
}

// ---------------- per-type encoders: h = relu(x @ W + b) -> bf16 ------------
template<int K, int ROWS>
__global__ __launch_bounds__(256) void encode_kernel(
    const float* __restrict__ x, const float* __restrict__ W,
    const float* __restrict__ b, ushort* __restrict__ hH,
    int rows, int row_off)
{
    int c = threadIdx.x;
    int base = blockIdx.x * ROWS;
    float wcol[K];
    #pragma unroll
    for (int k = 0; k < K; ++k) wcol[k] = W[k * D + c];
    float bias = b[c];
    for (int i = 0; i < ROWS; ++i) {
        int row = base + i;
        if (row >= rows) return;
        const float* xr = x + (size_t)row * K;
        float acc = bias;
        #pragma unroll
        for (int k = 0; k < K; ++k) acc += xr[k] * wcol[k];
        hH[(size_t)(row_off + row) * D + c] = f2bf(fmaxf(acc, 0.f));
    }
}

// ---------------- weight split+transpose: root[k][n] -> WtH/WtL[n][k] -------
__global__ __launch_bounds__(256) void wsplit_kernel(
    const float* __restrict__ root, ushort* __restrict__ WtH, ushort* __restrict__ WtL)
{
    int n = blockIdx.x, k = threadIdx.x;
    float w = root[(size_t)k * D + n];
    ushort hi = f2bf(w);
    WtH[(size_t)n * D + k] = hi;
    WtL[(size_t)n * D + k] = f2bf(w - bf2f(hi));
}

// ---------------- basis combine: Wr[r] = sum_b comp[r,b] * basis[b] ---------
__global__ __launch_bounds__(256) void wr_kernel(
    const float* __restrict__ basis, const float* __restrict__ comp,
    float* __restrict__ wr)
{
    int idx = blockIdx.x * 256 + threadIdx.x;   // < 4*DD
    int r = idx >> 16;
    int io = idx & (DD - 1);
    wr[idx] = comp[r * 3 + 0] * basis[io]
            + comp[r * 3 + 1] * basis[DD + io]
            + comp[r * 3 + 2] * basis[2 * DD + io];
}

// ---------------- r1/r3 degree count (low contention: 100K dsts) ----------
__global__ __launch_bounds__(256) void deg_count_kernel(
    const int* __restrict__ dst1, const int* __restrict__ dst3,
    int* __restrict__ deg1, int* __restrict__ deg3)
{
    int idx = blockIdx.x * 256 + threadIdx.x;
    if (idx >= 2 * E) return;
    if (idx < E) atomicAdd(&deg1[dst1[idx]], 1);
    else         atomicAdd(&deg3[dst3[idx - E]], 1);
}

// ---------------- r0/r2: per-slice LDS histograms (contention-free) --------
__global__ __launch_bounds__(256) void hist02_kernel(
    const int* __restrict__ dst0, const int* __restrict__ dst2,
    int* __restrict__ bh0, int* __restrict__ bh2)
{
    __shared__ int hist[NA];
    int b = blockIdx.x;                 // 0..2*NSL-1
    bool isR2 = (b >= NSL);
    int sl = isR2 ? b - NSL : b;
    const int* dst = isR2 ? dst2 : dst0;
    int nb = isR2 ? NC : NA;
    for (int i = threadIdx.x; i < nb; i += 256) hist[i] = 0;
    __syncthreads();
    int lo = (int)((long long)E * sl / NSL);
    int hi = (int)((long long)E * (sl + 1) / NSL);
    for (int e = lo + threadIdx.x; e < hi; e += 256)
        atomicAdd(&hist[dst[e]], 1);
    __syncthreads();
    int* bh = isR2 ? (bh2 + sl * NC) : (bh0 + sl * NA);
    for (int i = threadIdx.x; i < nb; i += 256) bh[i] = hist[i];
}

// -------- scan: per-bin over slices + cross-bin; emits rp/inv + abs offsets -
__global__ __launch_bounds__(512) void scan02_kernel(
    int* __restrict__ bh0, int* __restrict__ bh2,
    int* __restrict__ rp0, int* __restrict__ rp2,
    float* __restrict__ inv0, float* __restrict__ inv2)
{
    __shared__ int tot[512];
    __shared__ int exc[512];
    int t = threadIdx.x;
    int cnt = 0;
    if (t < NA) {
        int s = 0;
        for (int sl = 0; sl < NSL; ++sl) {
            int v = bh0[sl * NA + t]; bh0[sl * NA + t] = s; s += v;
        }
        cnt = s;
    } else if (t < NA + NC) {
        int bin = t - NA; int s = 0;
        for (int sl = 0; sl < NSL; ++sl) {
            int v = bh2[sl * NC + bin]; bh2[sl * NC + bin] = s; s += v;
        }
        cnt = s;
    }
    tot[t] = cnt;
    __syncthreads();
    for (int ofs = 1; ofs < 512; ofs <<= 1) {
        int v = (t >= ofs) ? tot[t - ofs] : 0;
        __syncthreads();
        tot[t] += v;
        __syncthreads();
    }
    int ex = tot[t] - cnt;              // exclusive over combined [r0 | r2]
    if (t < NA) {
        exc[t] = ex;
        rp0[t] = ex;
        inv0[t] = 1.0f / (float)(cnt > 1 ? cnt : 1);
        if (t == 0) { rp0[NA] = E; rp2[NC] = E; }
    } else if (t < NA + NC) {
        exc[t] = ex - E;                // r2 csr buffer is its own array
        rp2[t - NA] = ex - E;
        inv2[t - NA] = 1.0f / (float)(cnt > 1 ? cnt : 1);
    } else exc[t] = 0;
    __syncthreads();
    for (int idx = t; idx < NSL * NA; idx += 512) {
        int sl = idx / NA; int bin = idx - sl * NA;
        bh0[idx] += exc[bin];
    }
    for (int idx = t; idx < NSL * NC; idx += 512) {
        int sl = idx / NC; int bin = idx - sl * NC;
        bh2[idx] += exc[NA + bin];
    }
}

// ---------------- r0/r2 CSR fill with LDS cursors --------------------------
__global__ __launch_bounds__(256) void fill02_kernel(
    const int* __restrict__ src0, const int* __restrict__ dst0,
    const int* __restrict__ src2, const int* __restrict__ dst2,
    const int* __restrict__ bh0, const int* __restrict__ bh2,
    int* __restrict__ csr0, int* __restrict__ csr2)
{
    __shared__ int cur[NA];
    int b = blockIdx.x;
    bool isR2 = (b >= NSL);
    int sl = isR2 ? b - NSL : b;
    const int* src = isR2 ? src2 : src0;
    const int* dst = isR2 ? dst2 : dst0;
    const int* bh  = isR2 ? (bh2 + sl * NC) : (bh0 + sl * NA);
    int* csr       = isR2 ? csr2 : csr0;
    int nb = isR2 ? NC : NA;
    for (int i = threadIdx.x; i < nb; i += 256) cur[i] = bh[i];
    __syncthreads();
    int lo = (int)((long long)E * sl / NSL);
    int hi = (int)((long long)E * (sl + 1) / NSL);
    for (int e = lo + threadIdx.x; e < hi; e += 256) {
        int pos = atomicAdd(&cur[dst[e]], 1);
        csr[pos] = src[e];
    }
}

// ---------------- r1/r3 scan chain -----------------------------------------
__global__ __launch_bounds__(1024) void scanA_kernel(
    const int* __restrict__ deg1, const int* __restrict__ deg3, int* __restrict__ bsum)
{
    __shared__ int s[1024];
    int b = blockIdx.x;                    // 0..195
    bool isR3 = (b >= 98);
    const int* deg = isR3 ? deg3 : deg1;
    int chunk = isR3 ? b - 98 : b;
    int i = chunk * 1024 + threadIdx.x;
    int v = (i < NF) ? deg[i] : 0;
    s[threadIdx.x] = v;
    __syncthreads();
    for (int ofs = 512; ofs > 0; ofs >>= 1) {
        if ((int)threadIdx.x < ofs) s[threadIdx.x] += s[threadIdx.x + ofs];
        __syncthreads();
    }
    if (threadIdx.x == 0) bsum[(isR3 ? 128 : 0) + chunk] = s[0];
}

__global__ __launch_bounds__(256) void scanB_kernel(int* __restrict__ bsum)
{
    __shared__ int s[256];
    int t = threadIdx.x;
    int v = ((t & 127) < 98) ? bsum[t] : 0;
    s[t] = v;
    __syncthreads();
    for (int ofs = 1; ofs < 128; ofs <<= 1) {
        int a = ((t & 127) >= ofs) ? s[t - ofs] : 0;
        __syncthreads();
        s[t] += a;
        __syncthreads();
    }
    bsum[t] = s[t] - v;   // exclusive (segmented per 128-half)
}

__global__ __launch_bounds__(1024) void scanC_kernel(
    const int* __restrict__ deg1, const int* __restrict__ deg3,
    const int* __restrict__ bsum,
    int* __restrict__ rp1, int* __restrict__ rp3,
    int* __restrict__ cu1, int* __restrict__ cu3,
    float* __restrict__ inv1, float* __restrict__ inv3)
{
    __shared__ int s[1024];
    int b = blockIdx.x;                    // 0..195
    const int* deg; int* rp; int* cu; float* inv; int chunk; int prefix;
    if (b < 98) { deg = deg1; rp = rp1; cu = cu1; inv = inv1; chunk = b;      prefix = bsum[chunk]; }
    else        { deg = deg3; rp = rp3; cu = cu3; inv = inv3; chunk = b - 98; prefix = bsum[128 + chunk]; }
    int tid = threadIdx.x;
    int i = chunk * 1024 + tid;
    int v = (i < NF) ? deg[i] : 0;
    s[tid] = v;
    __syncthreads();
    for (int ofs = 1; ofs < 1024; ofs <<= 1) {
        int a = (tid >= ofs) ? s[tid - ofs] : 0;
        __syncthreads();
        s[tid] += a;
        __syncthreads();
    }
    int ex = prefix + s[tid] - v;
    if (i < NF) {
        rp[i] = ex;
        cu[i] = ex;
        inv[i] = 1.0f / (float)(v > 1 ? v : 1);
    }
    if (i == 0) rp[NF] = E;
}

__global__ __launch_bounds__(256) void csr_fill13_kernel(
    const int* __restrict__ src1, const int* __restrict__ dst1,
    const int* __restrict__ src3, const int* __restrict__ dst3,
    int* __restrict__ cu1, int* __restrict__ cu3,
    int* __restrict__ csr1, int* __restrict__ csr3)
{
    int idx = blockIdx.x * 256 + threadIdx.x;
    if (idx >= 2 * E) return;
    if (idx < E) {
        int pos = atomicAdd(&cu1[dst1[idx]], 1);
        csr1[pos] = src1[idx];
    } else {
        int e = idx - E;
        int pos = atomicAdd(&cu3[dst3[e]], 1);
        csr3[pos] = src3[e];
    }
}

// ------- y = h[src-type rows] @ Wr[rel]  (Wr precomputed) -------------------
__global__ __launch_bounds__(256) void y_kernel(
    const ushort* __restrict__ hH, const float* __restrict__ wr,
    float* __restrict__ y)
{
    int row = blockIdx.x;            // 0..429  (airports then carriers)
    int c = threadIdx.x;
    const ushort* sH = hH + (size_t)(NF + row) * D;
    const float* W = wr + (size_t)((row < NA) ? 1 : 3) * DD;
    float acc = 0.f;
    #pragma unroll 8
    for (int k = 0; k < D; ++k) acc += bf2f(sH[k]) * W[k * D + c];
    y[(size_t)row * D + c] = acc;
}

// ---- bf16 MFMA GEMM: G = A @ root^T + bias (A single-plane, W split) ------
// 8 waves, 64x32 sub-tiles, fragment-major global_load_lds staging, 3-buffer
// pipeline with COUNTED vmcnt (never drains in steady state).
__global__ __launch_bounds__(512) void gemm_mfma(
    const ushort* __restrict__ A,
    const ushort* __restrict__ WtH, const ushort* __restrict__ WtL,
    const float* __restrict__ bias,
    ushort* __restrict__ G, int nrows)
{
    constexpr int BM = 128, BK = 32;
    constexpr int PLANE = BM * BK;          // 4096 ushorts = 8 KB
    constexpr int BUF = 3 * PLANE;          // 12288 ushorts = 24 KB
    constexpr int LDW = 36;                 // fp32 epilogue scratch stride
    __shared__ __align__(16) ushort lds[3 * BUF];   // 73728 B (3 buffers)
    const int t = threadIdx.x;
    const int row0 = blockIdx.x * BM;
    const int col0 = blockIdx.y * BM;
    const int w = t >> 6, lane = t & 63;    // 8 waves
    const int wm = w >> 2, wn = w & 3;      // 2x4 wave grid, 64x32 per wave
    const int lr = lane & 15;
    const int lk = lane >> 4;
    f32x4 acc[4][2] = {};

    // staging: 24 (plane,group) units, wave w handles 3 consecutive
    const ushort* sp[3];
    int dofs[3];
    #pragma unroll
    for (int i = 0; i < 3; ++i) {
        int idx = w * 3 + i;
        int plane = idx >> 3, g = idx & 7;
        const ushort* base = (plane == 0) ? A : (plane == 1) ? WtH : WtL;
        int r = ((plane == 0) ? row0 : col0) + g * 16 + lr;
        if (plane == 0 && r >= nrows) r = nrows - 1;
        sp[i] = base + (size_t)r * D + lk * 8;
        dofs[i] = plane * PLANE + g * 512;
    }

    auto stage = [&](int kt, int buf) {
        ushort* bb = lds + buf * BUF;
        int k0 = kt * BK;
        #pragma unroll
        for (int i = 0; i < 3; ++i)
            gload_lds16(sp[i] + k0, bb + dofs[i]);
    };
    auto compute = [&](int buf) {
        const ushort* base = lds + buf * BUF;
        const ushort* As  = base;
        const ushort* WsH = base + PLANE;
        const ushort* WsL = base + 2 * PLANE;
        bf16x8 bh[2], bl[2];
        #pragma unroll
        for (int ni = 0; ni < 2; ++ni) {
            int off = (wn * 2 + ni) * 512 + lane * 8;
            bh[ni] = *(const bf16x8*)(&WsH[off]);
            bl[ni] = *(const bf16x8*)(&WsL[off]);
        }
        #pragma unroll
        for (int mi = 0; mi < 4; ++mi) {
            int off = (wm * 4 + mi) * 512 + lane * 8;
            bf16x8 ah = *(const bf16x8*)(&As[off]);
            #pragma unroll
            for (int ni = 0; ni < 2; ++ni) {
                acc[mi][ni] = __builtin_amdgcn_mfma_f32_16x16x32_bf16(ah, bh[ni], acc[mi][ni], 0, 0, 0);
                acc[mi][ni] = __builtin_amdgcn_mfma_f32_16x16x32_bf16(ah, bl[ni], acc[mi][ni], 0, 0, 0);
            }
        }
    };

    // prologue: 3 stages in flight (9 loads/wave)
    stage(0, 0);
    stage(1, 1);
    stage(2, 2);
#define PIPE_ITER(KT, PEND)                                        \
    asm volatile("s_waitcnt vmcnt(" #PEND ")" ::: "memory");       \
    __builtin_amdgcn_s_barrier();                                  \
    __builtin_amdgcn_sched_barrier(0);                             \
    compute((KT) % 3);                                             \
    __builtin_amdgcn_s_barrier();                                  \
    __builtin_amdgcn_sched_barrier(0);                             \
    if ((KT) + 3 < 8) stage((KT) + 3, (KT) % 3);
    PIPE_ITER(0, 6)
    PIPE_ITER(1, 6)
    PIPE_ITER(2, 6)
    PIPE_ITER(3, 6)
    PIPE_ITER(4, 6)
    PIPE_ITER(5, 6)
    PIPE_ITER(6, 3)
    PIPE_ITER(7, 0)
#undef PIPE_ITER

    // ---- epilogue: per-mi 16x32 pass through LDS, coalesced 16B stores -----
    __syncthreads();                         // everyone done with buffers
    float* S = (float*)lds + (size_t)w * 16 * LDW;   // per-wave 16x36 fp32
    const int rrow = lane >> 2;            // 0..15 read-back row
    const int grp  = lane & 3;             // col octet (8 bf16)
    #pragma unroll
    for (int mi = 0; mi < 4; ++mi) {
        __syncthreads();
        #pragma unroll
        for (int ni = 0; ni < 2; ++ni)
            #pragma unroll
            for (int reg = 0; reg < 4; ++reg)
                S[(lk * 4 + reg) * LDW + ni * 16 + lr] = acc[mi][ni][reg];
        __syncthreads();
        int gr = row0 + wm * 64 + mi * 16 + rrow;
        int gc = col0 + wn * 32 + grp * 8;
        if (gr >= nrows) continue;
        float4 f0 = *(const float4*)(&S[rrow * LDW + grp * 8]);
        float4 f1 = *(const float4*)(&S[rrow * LDW + grp * 8 + 4]);
        float4 b0 = *(const float4*)(bias + gc);
        float4 b1 = *(const float4*)(bias + gc + 4);
        float v[8] = {f0.x + b0.x, f0.y + b0.y, f0.z + b0.z, f0.w + b0.w,
                      f1.x + b1.x, f1.y + b1.y, f1.z + b1.z, f1.w + b1.w};
        u16x8 hh;
        #pragma unroll
        for (int j = 0; j < 8; ++j) hh[j] = f2bf(v[j]);
        *(u16x8*)(G + (size_t)gr * D + gc) = hh;
    }
}

// ---- layer-0 flight rows: G = relu(G + inv1*Σy1 + inv3*Σy3) in place ------
// 2 rows per wave: lanes 0-31 row 2w, lanes 32-63 row 2w+1; 8 ch/lane.
__global__ __launch_bounds__(256) void msg_relu_kernel(
    ushort* __restrict__ G,
    const float* __restrict__ y,
    const int* __restrict__ rp1, const int* __restrict__ csr1, const float* __restrict__ inv1,
    const int* __restrict__ rp3, const int* __restrict__ csr3, const float* __restrict__ inv3)
{
    int wid = (blockIdx.x * 256 + threadIdx.x) >> 6;
    int lane = threadIdx.x & 63;
    int row = wid * 2 + (lane >> 5);
    if (row >= NF) return;
    int c = (lane & 31) * 8;
    size_t o = (size_t)row * D + c;
    u16x8 gh = *(const u16x8*)(G + o);
    float v[8];
    #pragma unroll
    for (int j = 0; j < 8; ++j) v[j] = bf2f(gh[j]);
    float m[8] = {};
    int e0 = rp1[row], e1 = rp1[row + 1];
    for (int e = e0; e < e1; ++e) {
        const float* yr = y + (size_t)csr1[e] * D + c;
        float4 u0 = *(const float4*)yr;
        float4 u1 = *(const float4*)(yr + 4);
        m[0] += u0.x; m[1] += u0.y; m[2] += u0.z; m[3] += u0.w;
        m[4] += u1.x; m[5] += u1.y; m[6] += u1.z; m[7] += u1.w;
    }
    float s1 = inv1[row];
    #pragma unroll
    for (int j = 0; j < 8; ++j) { v[j] += s1 * m[j]; m[j] = 0.f; }
    e0 = rp3[row]; e1 = rp3[row + 1];
    for (int e = e0; e < e1; ++e) {
        const float* yr = y + (size_t)(NA + csr3[e]) * D + c;
        float4 u0 = *(const float4*)yr;
        float4 u1 = *(const float4*)(yr + 4);
        m[0] += u0.x; m[1] += u0.y; m[2] += u0.z; m[3] += u0.w;
        m[4] += u1.x; m[5] += u1.y; m[6] += u1.z; m[7] += u1.w;
    }
    float s3 = inv3[row];
    u16x8 oh;
    #pragma unroll
    for (int j = 0; j < 8; ++j) oh[j] = f2bf(fmaxf(v[j] + s3 * m[j], 0.f));
    *(u16x8*)(G + o) = oh;
}

// ---- layer-1: out[f] = relu(G2+msgs) . W_out + b_out (fused readout) -------
__global__ __launch_bounds__(256) void msg_readout_kernel(
    const ushort* __restrict__ G,
    const float* __restrict__ y,
    const int* __restrict__ rp1, const int* __restrict__ csr1, const float* __restrict__ inv1,
    const int* __restrict__ rp3, const int* __restrict__ csr3, const float* __restrict__ inv3,
    const float* __restrict__ wout, const float* __restrict__ bout,
    float* __restrict__ out)
{
    int wid = (blockIdx.x * 256 + threadIdx.x) >> 6;
    int lane = threadIdx.x & 63;
    int row = wid * 2 + (lane >> 5);
    if (row >= NF) return;
    int c = (lane & 31) * 8;
    size_t o = (size_t)row * D + c;
    u16x8 gh = *(const u16x8*)(G + o);
    float v[8];
    #pragma unroll
    for (int j = 0; j < 8; ++j) v[j] = bf2f(gh[j]);
    float m[8] = {};
    int e0 = rp1[row], e1 = rp1[row + 1];
    for (int e = e0; e < e1; ++e) {
        const float* yr = y + (size_t)csr1[e] * D + c;
        float4 u0 = *(const float4*)yr;
        float4 u1 = *(const float4*)(yr + 4);
        m[0] += u0.x; m[1] += u0.y; m[2] += u0.z; m[3] += u0.w;
        m[4] += u1.x; m[5] += u1.y; m[6] += u1.z; m[7] += u1.w;
    }
    float s1 = inv1[row];
    #pragma unroll
    for (int j = 0; j < 8; ++j) { v[j] += s1 * m[j]; m[j] = 0.f; }
    e0 = rp3[row]; e1 = rp3[row + 1];
    for (int e = e0; e < e1; ++e) {
        const float* yr = y + (size_t)(NA + csr3[e]) * D + c;
        float4 u0 = *(const float4*)yr;
        float4 u1 = *(const float4*)(yr + 4);
        m[0] += u0.x; m[1] += u0.y; m[2] += u0.z; m[3] += u0.w;
        m[4] += u1.x; m[5] += u1.y; m[6] += u1.z; m[7] += u1.w;
    }
    float s3 = inv3[row];
    float4 w0 = *(const float4*)(wout + c);
    float4 w1 = *(const float4*)(wout + c + 4);
    float wv[8] = {w0.x, w0.y, w0.z, w0.w, w1.x, w1.y, w1.z, w1.w};
    float pr = 0.f;
    #pragma unroll
    for (int j = 0; j < 8; ++j) pr += fmaxf(v[j] + s3 * m[j], 0.f) * wv[j];
    pr += __shfl_xor(pr, 1);
    pr += __shfl_xor(pr, 2);
    pr += __shfl_xor(pr, 4);
    pr += __shfl_xor(pr, 8);
    pr += __shfl_xor(pr, 16);
    if ((lane & 31) == 0) out[row] = pr + bout[0];
}

// ---- r0/r2: agg[dst] += hH[src] — 2 edges per wave, 16B/lane loads ---------
__global__ __launch_bounds__(256) void agg_small_kernel(
    const ushort* __restrict__ hH,
    const int* __restrict__ rp0, const int* __restrict__ csr0,
    const int* __restrict__ rp2, const int* __restrict__ csr2,
    float* __restrict__ agg)
{
    __shared__ float red[4][256];
    int b = blockIdx.x;
    const int* rp; const int* csr; int dstn, chunk, nch; float* arow;
    if (b < NA * 4) { dstn = b >> 2; chunk = b & 3; nch = 4;  rp = rp0; csr = csr0; arow = agg + (size_t)dstn * D; }
    else { int bb = b - NA * 4; dstn = bb >> 6; chunk = bb & 63; nch = 64; rp = rp2; csr = csr2; arow = agg + (size_t)(NA + dstn) * D; }
    int s = rp[dstn], e = rp[dstn + 1];
    int cnt = e - s;
    int lo = s + (int)((long long)cnt * chunk / nch);
    int hi = s + (int)((long long)cnt * (chunk + 1) / nch);
    int w = threadIdx.x >> 6, lane = threadIdx.x & 63;
    int span = hi - lo;
    int wlo = lo + (int)((long long)span * w / 4);
    int whi = lo + (int)((long long)span * (w + 1) / 4);
    int half = lane >> 5;                  // 0: edge p, 1: edge p+1
    int ch8 = (lane & 31) * 8;
    float acc[8] = {};
    int p = wlo;
    for (; p + 1 < whi; p += 2) {
        int r = csr[p + half];
        u16x8 v = *(const u16x8*)(hH + (size_t)r * D + ch8);
        #pragma unroll
        for (int j = 0; j < 8; ++j) acc[j] += bf2f(v[j]);
    }
    if (p < whi && half == 0) {
        int r = csr[p];
        u16x8 v = *(const u16x8*)(hH + (size_t)r * D + ch8);
        #pragma unroll
        for (int j = 0; j < 8; ++j) acc[j] += bf2f(v[j]);
    }
    #pragma unroll
    for (int j = 0; j < 8; ++j) acc[j] += __shfl_xor(acc[j], 32);
    if (lane < 32) {
        #pragma unroll
        for (int j = 0; j < 8; ++j) red[w][ch8 + j] = acc[j];
    }
    __syncthreads();
    int c = threadIdx.x;
    float total = red[0][c] + red[1][c] + red[2][c] + red[3][c];
    atomicAdd(arow + c, total);
}

// -- r0/r2 transform: G = relu(G + inv_deg*(agg @ Wr[rel])) in place ---------
__global__ __launch_bounds__(256) void smallT_kernel(
    const float* __restrict__ agg, const float* __restrict__ wr,
    const float* __restrict__ inv0, const float* __restrict__ inv2,
    ushort* __restrict__ G)
{
    int row = blockIdx.x;            // 0..429
    int c = threadIdx.x;
    const float* a = agg + (size_t)row * D;
    const float* W = wr + (size_t)((row < NA) ? 0 : 2) * DD;
    float scale = (row < NA) ? inv0[row] : inv2[row - NA];
    float acc = 0.f;
    #pragma unroll 8
    for (int k = 0; k < D; ++k) acc += a[k] * W[k * D + c];
    size_t o = (size_t)(NF + row) * D + c;
    G[o] = f2bf(fmaxf(bf2f(G[o]) + scale * acc, 0.f));
}

extern "C" void kernel_launch(void* const* d_in, const int* in_sizes, int n_in,
                              void* d_out, int out_size, void* d_ws, size_t ws_size,
                              hipStream_t stream)
{
    const float* xf = (const float*)d_in[0];
    const float* xa = (const float*)d_in[1];
    const float* xc = (const float*)d_in[2];
    const float* Wf = (const float*)d_in[3];
    const float* bf = (const float*)d_in[4];
    const float* Wa = (const float*)d_in[5];
    const float* ba = (const float*)d_in[6];
    const float* Wc = (const float*)d_in[7];
    const float* bc = (const float*)d_in[8];
    const float* basis0 = (const float*)d_in[9];
    const float* comp0  = (const float*)d_in[10];
    const float* root0  = (const float*)d_in[11];
    const float* bias0  = (const float*)d_in[12];
    const float* basis1 = (const float*)d_in[13];
    const float* comp1  = (const float*)d_in[14];
    const float* root1  = (const float*)d_in[15];
    const float* bias1  = (const float*)d_in[16];
    const float* Wout = (const float*)d_in[17];
    const float* bout = (const float*)d_in[18];
    const int* src0 = (const int*)d_in[19];
    const int* dst0 = (const int*)d_in[20];
    const int* src1 = (const int*)d_in[21];
    const int* dst1 = (const int*)d_in[22];
    const int* src2 = (const int*)d_in[23];
    const int* dst2 = (const int*)d_in[24];
    const int* src3 = (const int*)d_in[25];
    const int* dst3 = (const int*)d_in[26];
    float* out = (float*)d_out;

    char* ws = (char*)d_ws;
    size_t off = 0;
    auto alloc = [&](size_t bytes) -> char* {
        char* p = ws + off;
        off = (off + bytes + 255) & ~(size_t)255;
        return p;
    };
    ushort* hH  = (ushort*)alloc((size_t)NN * D * 2);
    ushort* gH  = (ushort*)alloc((size_t)NN * D * 2);
    // layer-1 GEMM output reuses hH (dead after layer-0 consumers)
    ushort* g2H = hH;
    ushort* WtH = (ushort*)alloc((size_t)DD * 2);
    ushort* WtL = (ushort*)alloc((size_t)DD * 2);
    float* wrbuf  = (float*)alloc((size_t)4 * DD * 4);
    float* ybuf   = (float*)alloc((size_t)(NA + NC) * D * 4);
    float* aggbuf = (float*)alloc((size_t)(NA + NC) * D * 4);
    int*   deg13  = (int*)  alloc((size_t)2 * NF * 4);
    int* deg1 = deg13; int* deg3 = deg13 + NF;
    float* inv1 = (float*)alloc((size_t)NF * 4);
    float* inv3 = (float*)alloc((size_t)NF * 4);
    float* inv0 = (float*)alloc((size_t)NA * 4);
    float* inv2 = (float*)alloc((size_t)NC * 4);
    int* rp0 = (int*)alloc((NA + 1) * 4);
    int* rp1 = (int*)alloc((size_t)(NF + 1) * 4);
    int* rp2 = (int*)alloc((NC + 1) * 4);
    int* rp3 = (int*)alloc((size_t)(NF + 1) * 4);
    int* cu1 = (int*)alloc((size_t)(NF + 1) * 4);
    int* cu3 = (int*)alloc((size_t)(NF + 1) * 4);
    int* csr0 = (int*)alloc((size_t)E * 4);
    int* csr1 = (int*)alloc((size_t)E * 4);
    int* csr2 = (int*)alloc((size_t)E * 4);
    int* csr3 = (int*)alloc((size_t)E * 4);
    int* bsum = (int*)alloc(256 * 4);
    int* bh0  = (int*)alloc((size_t)NSL * NA * 4);
    int* bh2  = (int*)alloc((size_t)NSL * NC * 4);
    (void)ws_size; (void)in_sizes; (void)n_in; (void)out_size;

    // ---- CSR build: r0/r2 via contention-free counting sort
    hist02_kernel<<<2 * NSL, 256, 0, stream>>>(dst0, dst2, bh0, bh2);
    scan02_kernel<<<1, 512, 0, stream>>>(bh0, bh2, rp0, rp2, inv0, inv2);
    fill02_kernel<<<2 * NSL, 256, 0, stream>>>(src0, dst0, src2, dst2, bh0, bh2, csr0, csr2);

    // ---- CSR build: r1/r3 via atomics (100K dsts, avg degree 2.5 — cheap)
    hipMemsetAsync(deg13, 0, (size_t)2 * NF * 4, stream);
    deg_count_kernel<<<(2 * E + 255) / 256, 256, 0, stream>>>(dst1, dst3, deg1, deg3);
    scanA_kernel<<<196, 1024, 0, stream>>>(deg1, deg3, bsum);
    scanB_kernel<<<1, 256, 0, stream>>>(bsum);
    scanC_kernel<<<196, 1024, 0, stream>>>(deg1, deg3, bsum, rp1, rp3, cu1, cu3, inv1, inv3);
    csr_fill13_kernel<<<(2 * E + 255) / 256, 256, 0, stream>>>(
        src1, dst1, src3, dst3, cu1, cu3, csr1, csr3);

    // ---- encoders (single bf16 plane)
    encode_kernel<32, 8><<<NF / 8, 256, 0, stream>>>(xf, Wf, bf, hH, NF, 0);
    encode_kernel<16, 8><<<(NA + 7) / 8, 256, 0, stream>>>(xa, Wa, ba, hH, NA, NF);
    encode_kernel<8, 8><<<(NC + 7) / 8, 256, 0, stream>>>(xc, Wc, bc, hH, NC, NF + NA);

    // ---- layer 0: pure MFMA gemm -> G; then per-row-type finishers in place
    wsplit_kernel<<<D, D, 0, stream>>>(root0, WtH, WtL);
    wr_kernel<<<4 * DD / 256, 256, 0, stream>>>(basis0, comp0, wrbuf);
    y_kernel<<<NA + NC, 256, 0, stream>>>(hH, wrbuf, ybuf);
    gemm_mfma<<<dim3((NN + 127) / 128, 2), 512, 0, stream>>>(
        hH, WtH, WtL, bias0, gH, NN);
    hipMemsetAsync(aggbuf, 0, (size_t)(NA + NC) * D * 4, stream);
    agg_small_kernel<<<NA * 4 + NC * 64, 256, 0, stream>>>(
        hH, rp0, csr0, rp2, csr2, aggbuf);
    smallT_kernel<<<NA + NC, 256, 0, stream>>>(aggbuf, wrbuf, inv0, inv2, gH);
    msg_relu_kernel<<<(NF / 2 * 64 + 255) / 256, 256, 0, stream>>>(
        gH, ybuf, rp1, csr1, inv1, rp3, csr3, inv3);

    // ---- layer 1 (flights only): pure gemm -> G2 (aliases h); readout -> out
    wsplit_kernel<<<D, D, 0, stream>>>(root1, WtH, WtL);
    wr_kernel<<<4 * DD / 256, 256, 0, stream>>>(basis1, comp1, wrbuf);
    y_kernel<<<NA + NC, 256, 0, stream>>>(gH, wrbuf, ybuf);
    gemm_mfma<<<dim3((NF + 127) / 128, 2), 512, 0, stream>>>(
        gH, WtH, WtL, bias1, g2H, NF);
    msg_readout_kernel<<<(NF / 2 * 64 + 255) / 256, 256, 0, stream>>>(
        g2H, ybuf, rp1, csr1, inv1, rp3, csr3, inv3, Wout, bout, out);
}

// Round 19
// 393.590 us; speedup vs baseline: 1.0657x; 1.0102x over previous
//
#include <hip/hip_runtime.h>
#include <hip/hip_bf16.h>
#include <cstdint>
#include <cstddef>

constexpr int NF = 100000;
constexpr int NA = 400;
constexpr int NC = 30;
constexpr int NN = NF + NA + NC;     // 100430
constexpr int D  = 256;
constexpr int DD = D * D;            // 65536
constexpr int E  = 250000;
constexpr int NSL = 128;             // slices for r0/r2 counting sort

typedef __attribute__((ext_vector_type(8))) short bf16x8;
typedef __attribute__((ext_vector_type(4))) float f32x4;
typedef __attribute__((ext_vector_type(8))) ushort u16x8;

__device__ inline ushort f2bf(float f) {
    __hip_bfloat16 h = __float2bfloat16(f);
    return __builtin_bit_cast(ushort, h);
}
__device__ inline float bf2f(ushort u) {
    __hip_bfloat16 h = __builtin_bit_cast(__hip_bfloat16, u);
    return __bfloat162float(h);
}

// async global->LDS, 16B per lane: LDS dest = base + lane*16 (wave-linear)
__device__ inline void gload_lds16(const ushort* g, ushort* l) {
    __builtin_amdgcn_global_load_lds(
        (const __attribute__((address_space(1))) void*)g,
        (__attribute__((address_space(3))) void*)l, 16, 0, 0);
}

// ---- fused per-type encoders: h = relu(x @ W + b) -> bf16 (all 3 types) ----
__global__ __launch_bounds__(256) void encode_all_kernel(
    const float* __restrict__ xf, const float* __restrict__ Wf, const float* __restrict__ bf,
    const float* __restrict__ xa, const float* __restrict__ Wa, const float* __restrict__ ba,
    const float* __restrict__ xc, const float* __restrict__ Wc, const float* __restrict__ bc,
    ushort* __restrict__ hH)
{
    constexpr int FB = NF / 8;               // 12500 flight blocks
    constexpr int AB = (NA + 7) / 8;         // 50 airport blocks
    int c = threadIdx.x;
    int b = blockIdx.x;
    if (b < FB) {                            // flights, K=32
        int base = b * 8;
        float wcol[32];
        #pragma unroll
        for (int k = 0; k < 32; ++k) wcol[k] = Wf[k * D + c];
        float bias = bf[c];
        #pragma unroll
        for (int i = 0; i < 8; ++i) {
            int row = base + i;
            const float* xr = xf + (size_t)row * 32;
            float acc = bias;
            #pragma unroll
            for (int k = 0; k < 32; ++k) acc += xr[k] * wcol[k];
            hH[(size_t)row * D + c] = f2bf(fmaxf(acc, 0.f));
        }
    } else if (b < FB + AB) {                // airports, K=16
        int base = (b - FB) * 8;
        float wcol[16];
        #pragma unroll
        for (int k = 0; k < 16; ++k) wcol[k] = Wa[k * D + c];
        float bias = ba[c];
        for (int i = 0; i < 8; ++i) {
            int row = base + i;
            if (row >= NA) break;
            const float* xr = xa + (size_t)row * 16;
            float acc = bias;
            #pragma unroll
            for (int k = 0; k < 16; ++k) acc += xr[k] * wcol[k];
            hH[(size_t)(NF + row) * D + c] = f2bf(fmaxf(acc, 0.f));
        }
    } else {                                 // carriers, K=8
        int base = (b - FB - AB) * 8;
        float wcol[8];
        #pragma unroll
        for (int k = 0; k < 8; ++k) wcol[k] = Wc[k * D + c];
        float bias = bc[c];
        for (int i = 0; i < 8; ++i) {
            int row = base + i;
            if (row >= NC) break;
            const float* xr = xc + (size_t)row * 8;
            float acc = bias;
            #pragma unroll
            for (int k = 0; k < 8; ++k) acc += xr[k] * wcol[k];
            hH[(size_t)(NF + NA + row) * D + c] = f2bf(fmaxf(acc, 0.f));
        }
    }
}

// ---------------- weight split+transpose: root[k][n] -> WtH/WtL[n][k] -------
__global__ __launch_bounds__(256) void wsplit_kernel(
    const float* __restrict__ root, ushort* __restrict__ WtH, ushort* __restrict__ WtL)
{
    int n = blockIdx.x, k = threadIdx.x;
    float w = root[(size_t)k * D + n];
    ushort hi = f2bf(w);
    WtH[(size_t)n * D + k] = hi;
    WtL[(size_t)n * D + k] = f2bf(w - bf2f(hi));
}

// ---------------- basis combine: Wr[r] = sum_b comp[r,b] * basis[b] ---------
__global__ __launch_bounds__(256) void wr_kernel(
    const float* __restrict__ basis, const float* __restrict__ comp,
    float* __restrict__ wr)
{
    int idx = blockIdx.x * 256 + threadIdx.x;   // < 4*DD
    int r = idx >> 16;
    int io = idx & (DD - 1);
    wr[idx] = comp[r * 3 + 0] * basis[io]
            + comp[r * 3 + 1] * basis[DD + io]
            + comp[r * 3 + 2] * basis[2 * DD + io];
}

// ---------------- r1/r3 degree count (low contention: 100K dsts) ----------
__global__ __launch_bounds__(256) void deg_count_kernel(
    const int* __restrict__ dst1, const int* __restrict__ dst3,
    int* __restrict__ deg1, int* __restrict__ deg3)
{
    int idx = blockIdx.x * 256 + threadIdx.x;
    if (idx >= 2 * E) return;
    if (idx < E) atomicAdd(&deg1[dst1[idx]], 1);
    else         atomicAdd(&deg3[dst3[idx - E]], 1);
}

// ---- r0/r2 per-slice LDS histograms; also zeroes deg13 & aggbuf (folded
// memsets: stream order guarantees completion before deg_count / agg_small) --
__global__ __launch_bounds__(256) void hist02_kernel(
    const int* __restrict__ dst0, const int* __restrict__ dst2,
    int* __restrict__ bh0, int* __restrict__ bh2,
    int* __restrict__ deg13z, float* __restrict__ aggz)
{
    __shared__ int hist[NA];
    int b = blockIdx.x;                 // 0..2*NSL-1
    // folded memsets (grid-strided)
    for (int i = b * 256 + threadIdx.x; i < 2 * NF; i += 2 * NSL * 256)
        deg13z[i] = 0;
    for (int i = b * 256 + threadIdx.x; i < (NA + NC) * D; i += 2 * NSL * 256)
        aggz[i] = 0.f;
    bool isR2 = (b >= NSL);
    int sl = isR2 ? b - NSL : b;
    const int* dst = isR2 ? dst2 : dst0;
    int nb = isR2 ? NC : NA;
    for (int i = threadIdx.x; i < nb; i += 256) hist[i] = 0;
    __syncthreads();
    int lo = (int)((long long)E * sl / NSL);
    int hi = (int)((long long)E * (sl + 1) / NSL);
    for (int e = lo + threadIdx.x; e < hi; e += 256)
        atomicAdd(&hist[dst[e]], 1);
    __syncthreads();
    int* bh = isR2 ? (bh2 + sl * NC) : (bh0 + sl * NA);
    for (int i = threadIdx.x; i < nb; i += 256) bh[i] = hist[i];
}

// -------- scan: per-bin over slices + cross-bin; emits rp/inv + abs offsets -
__global__ __launch_bounds__(512) void scan02_kernel(
    int* __restrict__ bh0, int* __restrict__ bh2,
    int* __restrict__ rp0, int* __restrict__ rp2,
    float* __restrict__ inv0, float* __restrict__ inv2)
{
    __shared__ int tot[512];
    __shared__ int exc[512];
    int t = threadIdx.x;
    int cnt = 0;
    if (t < NA) {
        int s = 0;
        for (int sl = 0; sl < NSL; ++sl) {
            int v = bh0[sl * NA + t]; bh0[sl * NA + t] = s; s += v;
        }
        cnt = s;
    } else if (t < NA + NC) {
        int bin = t - NA; int s = 0;
        for (int sl = 0; sl < NSL; ++sl) {
            int v = bh2[sl * NC + bin]; bh2[sl * NC + bin] = s; s += v;
        }
        cnt = s;
    }
    tot[t] = cnt;
    __syncthreads();
    for (int ofs = 1; ofs < 512; ofs <<= 1) {
        int v = (t >= ofs) ? tot[t - ofs] : 0;
        __syncthreads();
        tot[t] += v;
        __syncthreads();
    }
    int ex = tot[t] - cnt;              // exclusive over combined [r0 | r2]
    if (t < NA) {
        exc[t] = ex;
        rp0[t] = ex;
        inv0[t] = 1.0f / (float)(cnt > 1 ? cnt : 1);
        if (t == 0) { rp0[NA] = E; rp2[NC] = E; }
    } else if (t < NA + NC) {
        exc[t] = ex - E;                // r2 csr buffer is its own array
        rp2[t - NA] = ex - E;
        inv2[t - NA] = 1.0f / (float)(cnt > 1 ? cnt : 1);
    } else exc[t] = 0;
    __syncthreads();
    for (int idx = t; idx < NSL * NA; idx += 512) {
        int sl = idx / NA; int bin = idx - sl * NA;
        bh0[idx] += exc[bin];
    }
    for (int idx = t; idx < NSL * NC; idx += 512) {
        int sl = idx / NC; int bin = idx - sl * NC;
        bh2[idx] += exc[NA + bin];
    }
}

// ---------------- r0/r2 CSR fill with LDS cursors --------------------------
__global__ __launch_bounds__(256) void fill02_kernel(
    const int* __restrict__ src0, const int* __restrict__ dst0,
    const int* __restrict__ src2, const int* __restrict__ dst2,
    const int* __restrict__ bh0, const int* __restrict__ bh2,
    int* __restrict__ csr0, int* __restrict__ csr2)
{
    __shared__ int cur[NA];
    int b = blockIdx.x;
    bool isR2 = (b >= NSL);
    int sl = isR2 ? b - NSL : b;
    const int* src = isR2 ? src2 : src0;
    const int* dst = isR2 ? dst2 : dst0;
    const int* bh  = isR2 ? (bh2 + sl * NC) : (bh0 + sl * NA);
    int* csr       = isR2 ? csr2 : csr0;
    int nb = isR2 ? NC : NA;
    for (int i = threadIdx.x; i < nb; i += 256) cur[i] = bh[i];
    __syncthreads();
    int lo = (int)((long long)E * sl / NSL);
    int hi = (int)((long long)E * (sl + 1) / NSL);
    for (int e = lo + threadIdx.x; e < hi; e += 256) {
        int pos = atomicAdd(&cur[dst[e]], 1);
        csr[pos] = src[e];
    }
}

// ---------------- r1/r3 scan chain -----------------------------------------
__global__ __launch_bounds__(1024) void scanA_kernel(
    const int* __restrict__ deg1, const int* __restrict__ deg3, int* __restrict__ bsum)
{
    __shared__ int s[1024];
    int b = blockIdx.x;                    // 0..195
    bool isR3 = (b >= 98);
    const int* deg = isR3 ? deg3 : deg1;
    int chunk = isR3 ? b - 98 : b;
    int i = chunk * 1024 + threadIdx.x;
    int v = (i < NF) ? deg[i] : 0;
    s[threadIdx.x] = v;
    __syncthreads();
    for (int ofs = 512; ofs > 0; ofs >>= 1) {
        if ((int)threadIdx.x < ofs) s[threadIdx.x] += s[threadIdx.x + ofs];
        __syncthreads();
    }
    if (threadIdx.x == 0) bsum[(isR3 ? 128 : 0) + chunk] = s[0];
}

// scanC with the scanB 196-entry exclusive scan inlined (each block
// recomputes it redundantly in LDS — trivial work, saves a dispatch).
__global__ __launch_bounds__(1024) void scanC_kernel(
    const int* __restrict__ deg1, const int* __restrict__ deg3,
    const int* __restrict__ bsum,
    int* __restrict__ rp1, int* __restrict__ rp3,
    int* __restrict__ cu1, int* __restrict__ cu3,
    float* __restrict__ inv1, float* __restrict__ inv3)
{
    __shared__ int s[1024];
    __shared__ int s2[256];
    int tid = threadIdx.x;
    int b = blockIdx.x;                    // 0..195
    // inline scanB: segmented (per 128-half) exclusive scan of bsum
    int vb = 0;
    if (tid < 256) {
        vb = ((tid & 127) < 98) ? bsum[tid] : 0;
        s2[tid] = vb;
    }
    __syncthreads();
    for (int ofs = 1; ofs < 128; ofs <<= 1) {
        int a = 0;
        if (tid < 256 && (tid & 127) >= ofs) a = s2[tid - ofs];
        __syncthreads();
        if (tid < 256) s2[tid] += a;
        __syncthreads();
    }
    if (tid < 256) s2[tid] -= vb;          // exclusive
    __syncthreads();
    const int* deg; int* rp; int* cu; float* inv; int chunk; int prefix;
    if (b < 98) { deg = deg1; rp = rp1; cu = cu1; inv = inv1; chunk = b;      prefix = s2[chunk]; }
    else        { deg = deg3; rp = rp3; cu = cu3; inv = inv3; chunk = b - 98; prefix = s2[128 + chunk]; }
    int i = chunk * 1024 + tid;
    int v = (i < NF) ? deg[i] : 0;
    s[tid] = v;
    __syncthreads();
    for (int ofs = 1; ofs < 1024; ofs <<= 1) {
        int a = (tid >= ofs) ? s[tid - ofs] : 0;
        __syncthreads();
        s[tid] += a;
        __syncthreads();
    }
    int ex = prefix + s[tid] - v;
    if (i < NF) {
        rp[i] = ex;
        cu[i] = ex;
        inv[i] = 1.0f / (float)(v > 1 ? v : 1);
    }
    if (i == 0) rp[NF] = E;
}

__global__ __launch_bounds__(256) void csr_fill13_kernel(
    const int* __restrict__ src1, const int* __restrict__ dst1,
    const int* __restrict__ src3, const int* __restrict__ dst3,
    int* __restrict__ cu1, int* __restrict__ cu3,
    int* __restrict__ csr1, int* __restrict__ csr3)
{
    int idx = blockIdx.x * 256 + threadIdx.x;
    if (idx >= 2 * E) return;
    if (idx < E) {
        int pos = atomicAdd(&cu1[dst1[idx]], 1);
        csr1[pos] = src1[idx];
    } else {
        int e = idx - E;
        int pos = atomicAdd(&cu3[dst3[e]], 1);
        csr3[pos] = src3[e];
    }
}

// ------- y = h[src-type rows] @ Wr[rel]  (Wr precomputed) -------------------
__global__ __launch_bounds__(256) void y_kernel(
    const ushort* __restrict__ hH, const float* __restrict__ wr,
    float* __restrict__ y)
{
    int row = blockIdx.x;            // 0..429  (airports then carriers)
    int c = threadIdx.x;
    const ushort* sH = hH + (size_t)(NF + row) * D;
    const float* W = wr + (size_t)((row < NA) ? 1 : 3) * DD;
    float acc = 0.f;
    #pragma unroll 8
    for (int k = 0; k < D; ++k) acc += bf2f(sH[k]) * W[k * D + c];
    y[(size_t)row * D + c] = acc;
}

// ---- bf16 MFMA GEMM: G = A @ root^T + bias (A single-plane, W split) ------
// 8 waves, 64x32 sub-tiles, fragment-major global_load_lds staging, 3-buffer
// pipeline with COUNTED vmcnt (never drains in steady state).
__global__ __launch_bounds__(512) void gemm_mfma(
    const ushort* __restrict__ A,
    const ushort* __restrict__ WtH, const ushort* __restrict__ WtL,
    const float* __restrict__ bias,
    ushort* __restrict__ G, int nrows)
{
    constexpr int BM = 128, BK = 32;
    constexpr int PLANE = BM * BK;          // 4096 ushorts = 8 KB
    constexpr int BUF = 3 * PLANE;          // 12288 ushorts = 24 KB
    constexpr int LDW = 36;                 // fp32 epilogue scratch stride
    __shared__ __align__(16) ushort lds[3 * BUF];   // 73728 B (3 buffers)
    const int t = threadIdx.x;
    const int row0 = blockIdx.x * BM;
    const int col0 = blockIdx.y * BM;
    const int w = t >> 6, lane = t & 63;    // 8 waves
    const int wm = w >> 2, wn = w & 3;      // 2x4 wave grid, 64x32 per wave
    const int lr = lane & 15;
    const int lk = lane >> 4;
    f32x4 acc[4][2] = {};

    // staging: 24 (plane,group) units, wave w handles 3 consecutive
    const ushort* sp[3];
    int dofs[3];
    #pragma unroll
    for (int i = 0; i < 3; ++i) {
        int idx = w * 3 + i;
        int plane = idx >> 3, g = idx & 7;
        const ushort* base = (plane == 0) ? A : (plane == 1) ? WtH : WtL;
        int r = ((plane == 0) ? row0 : col0) + g * 16 + lr;
        if (plane == 0 && r >= nrows) r = nrows - 1;
        sp[i] = base + (size_t)r * D + lk * 8;
        dofs[i] = plane * PLANE + g * 512;
    }

    auto stage = [&](int kt, int buf) {
        ushort* bb = lds + buf * BUF;
        int k0 = kt * BK;
        #pragma unroll
        for (int i = 0; i < 3; ++i)
            gload_lds16(sp[i] + k0, bb + dofs[i]);
    };
    auto compute = [&](int buf) {
        const ushort* base = lds + buf * BUF;
        const ushort* As  = base;
        const ushort* WsH = base + PLANE;
        const ushort* WsL = base + 2 * PLANE;
        bf16x8 bh[2], bl[2];
        #pragma unroll
        for (int ni = 0; ni < 2; ++ni) {
            int off = (wn * 2 + ni) * 512 + lane * 8;
            bh[ni] = *(const bf16x8*)(&WsH[off]);
            bl[ni] = *(const bf16x8*)(&WsL[off]);
        }
        #pragma unroll
        for (int mi = 0; mi < 4; ++mi) {
            int off = (wm * 4 + mi) * 512 + lane * 8;
            bf16x8 ah = *(const bf16x8*)(&As[off]);
            #pragma unroll
            for (int ni = 0; ni < 2; ++ni) {
                acc[mi][ni] = __builtin_amdgcn_mfma_f32_16x16x32_bf16(ah, bh[ni], acc[mi][ni], 0, 0, 0);
                acc[mi][ni] = __builtin_amdgcn_mfma_f32_16x16x32_bf16(ah, bl[ni], acc[mi][ni], 0, 0, 0);
            }
        }
    };

    // prologue: 3 stages in flight (9 loads/wave)
    stage(0, 0);
    stage(1, 1);
    stage(2, 2);
#define PIPE_ITER(KT, PEND)                                        \
    asm volatile("s_waitcnt vmcnt(" #PEND ")" ::: "memory");       \
    __builtin_amdgcn_s_barrier();                                  \
    __builtin_amdgcn_sched_barrier(0);                             \
    compute((KT) % 3);                                             \
    __builtin_amdgcn_s_barrier();                                  \
    __builtin_amdgcn_sched_barrier(0);                             \
    if ((KT) + 3 < 8) stage((KT) + 3, (KT) % 3);
    PIPE_ITER(0, 6)
    PIPE_ITER(1, 6)
    PIPE_ITER(2, 6)
    PIPE_ITER(3, 6)
    PIPE_ITER(4, 6)
    PIPE_ITER(5, 6)
    PIPE_ITER(6, 3)
    PIPE_ITER(7, 0)
#undef PIPE_ITER

    // ---- epilogue: per-mi 16x32 pass through LDS, coalesced 16B stores -----
    __syncthreads();                         // everyone done with buffers
    float* S = (float*)lds + (size_t)w * 16 * LDW;   // per-wave 16x36 fp32
    const int rrow = lane >> 2;            // 0..15 read-back row
    const int grp  = lane & 3;             // col octet (8 bf16)
    #pragma unroll
    for (int mi = 0; mi < 4; ++mi) {
        __syncthreads();
        #pragma unroll
        for (int ni = 0; ni < 2; ++ni)
            #pragma unroll
            for (int reg = 0; reg < 4; ++reg)
                S[(lk * 4 + reg) * LDW + ni * 16 + lr] = acc[mi][ni][reg];
        __syncthreads();
        int gr = row0 + wm * 64 + mi * 16 + rrow;
        int gc = col0 + wn * 32 + grp * 8;
        if (gr >= nrows) continue;
        float4 f0 = *(const float4*)(&S[rrow * LDW + grp * 8]);
        float4 f1 = *(const float4*)(&S[rrow * LDW + grp * 8 + 4]);
        float4 b0 = *(const float4*)(bias + gc);
        float4 b1 = *(const float4*)(bias + gc + 4);
        float v[8] = {f0.x + b0.x, f0.y + b0.y, f0.z + b0.z, f0.w + b0.w,
                      f1.x + b1.x, f1.y + b1.y, f1.z + b1.z, f1.w + b1.w};
        u16x8 hh;
        #pragma unroll
        for (int j = 0; j < 8; ++j) hh[j] = f2bf(v[j]);
        *(u16x8*)(G + (size_t)gr * D + gc) = hh;
    }
}

// ---- layer-0 flight rows: G = relu(G + inv1*Σy1 + inv3*Σy3) in place ------
// 2 rows per wave: lanes 0-31 row 2w, lanes 32-63 row 2w+1; 8 ch/lane.
__global__ __launch_bounds__(256) void msg_relu_kernel(
    ushort* __restrict__ G,
    const float* __restrict__ y,
    const int* __restrict__ rp1, const int* __restrict__ csr1, const float* __restrict__ inv1,
    const int* __restrict__ rp3, const int* __restrict__ csr3, const float* __restrict__ inv3)
{
    int wid = (blockIdx.x * 256 + threadIdx.x) >> 6;
    int lane = threadIdx.x & 63;
    int row = wid * 2 + (lane >> 5);
    if (row >= NF) return;
    int c = (lane & 31) * 8;
    size_t o = (size_t)row * D + c;
    u16x8 gh = *(const u16x8*)(G + o);
    float v[8];
    #pragma unroll
    for (int j = 0; j < 8; ++j) v[j] = bf2f(gh[j]);
    float m[8] = {};
    int e0 = rp1[row], e1 = rp1[row + 1];
    for (int e = e0; e < e1; ++e) {
        const float* yr = y + (size_t)csr1[e] * D + c;
        float4 u0 = *(const float4*)yr;
        float4 u1 = *(const float4*)(yr + 4);
        m[0] += u0.x; m[1] += u0.y; m[2] += u0.z; m[3] += u0.w;
        m[4] += u1.x; m[5] += u1.y; m[6] += u1.z; m[7] += u1.w;
    }
    float s1 = inv1[row];
    #pragma unroll
    for (int j = 0; j < 8; ++j) { v[j] += s1 * m[j]; m[j] = 0.f; }
    e0 = rp3[row]; e1 = rp3[row + 1];
    for (int e = e0; e < e1; ++e) {
        const float* yr = y + (size_t)(NA + csr3[e]) * D + c;
        float4 u0 = *(const float4*)yr;
        float4 u1 = *(const float4*)(yr + 4);
        m[0] += u0.x; m[1] += u0.y; m[2] += u0.z; m[3] += u0.w;
        m[4] += u1.x; m[5] += u1.y; m[6] += u1.z; m[7] += u1.w;
    }
    float s3 = inv3[row];
    u16x8 oh;
    #pragma unroll
    for (int j = 0; j < 8; ++j) oh[j] = f2bf(fmaxf(v[j] + s3 * m[j], 0.f));
    *(u16x8*)(G + o) = oh;
}

// ---- layer-1: out[f] = relu(G2+msgs) . W_out + b_out (fused readout) -------
__global__ __launch_bounds__(256) void msg_readout_kernel(
    const ushort* __restrict__ G,
    const float* __restrict__ y,
    const int* __restrict__ rp1, const int* __restrict__ csr1, const float* __restrict__ inv1,
    const int* __restrict__ rp3, const int* __restrict__ csr3, const float* __restrict__ inv3,
    const float* __restrict__ wout, const float* __restrict__ bout,
    float* __restrict__ out)
{
    int wid = (blockIdx.x * 256 + threadIdx.x) >> 6;
    int lane = threadIdx.x & 63;
    int row = wid * 2 + (lane >> 5);
    if (row >= NF) return;
    int c = (lane & 31) * 8;
    size_t o = (size_t)row * D + c;
    u16x8 gh = *(const u16x8*)(G + o);
    float v[8];
    #pragma unroll
    for (int j = 0; j < 8; ++j) v[j] = bf2f(gh[j]);
    float m[8] = {};
    int e0 = rp1[row], e1 = rp1[row + 1];
    for (int e = e0; e < e1; ++e) {
        const float* yr = y + (size_t)csr1[e] * D + c;
        float4 u0 = *(const float4*)yr;
        float4 u1 = *(const float4*)(yr + 4);
        m[0] += u0.x; m[1] += u0.y; m[2] += u0.z; m[3] += u0.w;
        m[4] += u1.x; m[5] += u1.y; m[6] += u1.z; m[7] += u1.w;
    }
    float s1 = inv1[row];
    #pragma unroll
    for (int j = 0; j < 8; ++j) { v[j] += s1 * m[j]; m[j] = 0.f; }
    e0 = rp3[row]; e1 = rp3[row + 1];
    for (int e = e0; e < e1; ++e) {
        const float* yr = y + (size_t)(NA + csr3[e]) * D + c;
        float4 u0 = *(const float4*)yr;
        float4 u1 = *(const float4*)(yr + 4);
        m[0] += u0.x; m[1] += u0.y; m[2] += u0.z; m[3] += u0.w;
        m[4] += u1.x; m[5] += u1.y; m[6] += u1.z; m[7] += u1.w;
    }
    float s3 = inv3[row];
    float4 w0 = *(const float4*)(wout + c);
    float4 w1 = *(const float4*)(wout + c + 4);
    float wv[8] = {w0.x, w0.y, w0.z, w0.w, w1.x, w1.y, w1.z, w1.w};
    float pr = 0.f;
    #pragma unroll
    for (int j = 0; j < 8; ++j) pr += fmaxf(v[j] + s3 * m[j], 0.f) * wv[j];
    pr += __shfl_xor(pr, 1);
    pr += __shfl_xor(pr, 2);
    pr += __shfl_xor(pr, 4);
    pr += __shfl_xor(pr, 8);
    pr += __shfl_xor(pr, 16);
    if ((lane & 31) == 0) out[row] = pr + bout[0];
}

// ---- r0/r2: agg[dst] += hH[src] — 2 edges per wave, 16B/lane loads ---------
__global__ __launch_bounds__(256) void agg_small_kernel(
    const ushort* __restrict__ hH,
    const int* __restrict__ rp0, const int* __restrict__ csr0,
    const int* __restrict__ rp2, const int* __restrict__ csr2,
    float* __restrict__ agg)
{
    __shared__ float red[4][256];
    int b = blockIdx.x;
    const int* rp; const int* csr; int dstn, chunk, nch; float* arow;
    if (b < NA * 4) { dstn = b >> 2; chunk = b & 3; nch = 4;  rp = rp0; csr = csr0; arow = agg + (size_t)dstn * D; }
    else { int bb = b - NA * 4; dstn = bb >> 6; chunk = bb & 63; nch = 64; rp = rp2; csr = csr2; arow = agg + (size_t)(NA + dstn) * D; }
    int s = rp[dstn], e = rp[dstn + 1];
    int cnt = e - s;
    int lo = s + (int)((long long)cnt * chunk / nch);
    int hi = s + (int)((long long)cnt * (chunk + 1) / nch);
    int w = threadIdx.x >> 6, lane = threadIdx.x & 63;
    int span = hi - lo;
    int wlo = lo + (int)((long long)span * w / 4);
    int whi = lo + (int)((long long)span * (w + 1) / 4);
    int half = lane >> 5;                  // 0: edge p, 1: edge p+1
    int ch8 = (lane & 31) * 8;
    float acc[8] = {};
    int p = wlo;
    for (; p + 1 < whi; p += 2) {
        int r = csr[p + half];
        u16x8 v = *(const u16x8*)(hH + (size_t)r * D + ch8);
        #pragma unroll
        for (int j = 0; j < 8; ++j) acc[j] += bf2f(v[j]);
    }
    if (p < whi && half == 0) {
        int r = csr[p];
        u16x8 v = *(const u16x8*)(hH + (size_t)r * D + ch8);
        #pragma unroll
        for (int j = 0; j < 8; ++j) acc[j] += bf2f(v[j]);
    }
    #pragma unroll
    for (int j = 0; j < 8; ++j) acc[j] += __shfl_xor(acc[j], 32);
    if (lane < 32) {
        #pragma unroll
        for (int j = 0; j < 8; ++j) red[w][ch8 + j] = acc[j];
    }
    __syncthreads();
    int c = threadIdx.x;
    float total = red[0][c] + red[1][c] + red[2][c] + red[3][c];
    atomicAdd(arow + c, total);
}

// -- r0/r2 transform: G = relu(G + inv_deg*(agg @ Wr[rel])) in place ---------
__global__ __launch_bounds__(256) void smallT_kernel(
    const float* __restrict__ agg, const float* __restrict__ wr,
    const float* __restrict__ inv0, const float* __restrict__ inv2,
    ushort* __restrict__ G)
{
    int row = blockIdx.x;            // 0..429
    int c = threadIdx.x;
    const float* a = agg + (size_t)row * D;
    const float* W = wr + (size_t)((row < NA) ? 0 : 2) * DD;
    float scale = (row < NA) ? inv0[row] : inv2[row - NA];
    float acc = 0.f;
    #pragma unroll 8
    for (int k = 0; k < D; ++k) acc += a[k] * W[k * D + c];
    size_t o = (size_t)(NF + row) * D + c;
    G[o] = f2bf(fmaxf(bf2f(G[o]) + scale * acc, 0.f));
}

extern "C" void kernel_launch(void* const* d_in, const int* in_sizes, int n_in,
                              void* d_out, int out_size, void* d_ws, size_t ws_size,
                              hipStream_t stream)
{
    const float* xf = (const float*)d_in[0];
    const float* xa = (const float*)d_in[1];
    const float* xc = (const float*)d_in[2];
    const float* Wf = (const float*)d_in[3];
    const float* bf = (const float*)d_in[4];
    const float* Wa = (const float*)d_in[5];
    const float* ba = (const float*)d_in[6];
    const float* Wc = (const float*)d_in[7];
    const float* bc = (const float*)d_in[8];
    const float* basis0 = (const float*)d_in[9];
    const float* comp0  = (const float*)d_in[10];
    const float* root0  = (const float*)d_in[11];
    const float* bias0  = (const float*)d_in[12];
    const float* basis1 = (const float*)d_in[13];
    const float* comp1  = (const float*)d_in[14];
    const float* root1  = (const float*)d_in[15];
    const float* bias1  = (const float*)d_in[16];
    const float* Wout = (const float*)d_in[17];
    const float* bout = (const float*)d_in[18];
    const int* src0 = (const int*)d_in[19];
    const int* dst0 = (const int*)d_in[20];
    const int* src1 = (const int*)d_in[21];
    const int* dst1 = (const int*)d_in[22];
    const int* src2 = (const int*)d_in[23];
    const int* dst2 = (const int*)d_in[24];
    const int* src3 = (const int*)d_in[25];
    const int* dst3 = (const int*)d_in[26];
    float* out = (float*)d_out;

    char* ws = (char*)d_ws;
    size_t off = 0;
    auto alloc = [&](size_t bytes) -> char* {
        char* p = ws + off;
        off = (off + bytes + 255) & ~(size_t)255;
        return p;
    };
    ushort* hH  = (ushort*)alloc((size_t)NN * D * 2);
    ushort* gH  = (ushort*)alloc((size_t)NN * D * 2);
    // layer-1 GEMM output reuses hH (dead after layer-0 consumers)
    ushort* g2H = hH;
    ushort* WtH = (ushort*)alloc((size_t)DD * 2);
    ushort* WtL = (ushort*)alloc((size_t)DD * 2);
    float* wrbuf  = (float*)alloc((size_t)4 * DD * 4);
    float* ybuf   = (float*)alloc((size_t)(NA + NC) * D * 4);
    float* aggbuf = (float*)alloc((size_t)(NA + NC) * D * 4);
    int*   deg13  = (int*)  alloc((size_t)2 * NF * 4);
    int* deg1 = deg13; int* deg3 = deg13 + NF;
    float* inv1 = (float*)alloc((size_t)NF * 4);
    float* inv3 = (float*)alloc((size_t)NF * 4);
    float* inv0 = (float*)alloc((size_t)NA * 4);
    float* inv2 = (float*)alloc((size_t)NC * 4);
    int* rp0 = (int*)alloc((NA + 1) * 4);
    int* rp1 = (int*)alloc((size_t)(NF + 1) * 4);
    int* rp2 = (int*)alloc((NC + 1) * 4);
    int* rp3 = (int*)alloc((size_t)(NF + 1) * 4);
    int* cu1 = (int*)alloc((size_t)(NF + 1) * 4);
    int* cu3 = (int*)alloc((size_t)(NF + 1) * 4);
    int* csr0 = (int*)alloc((size_t)E * 4);
    int* csr1 = (int*)alloc((size_t)E * 4);
    int* csr2 = (int*)alloc((size_t)E * 4);
    int* csr3 = (int*)alloc((size_t)E * 4);
    int* bsum = (int*)alloc(256 * 4);
    int* bh0  = (int*)alloc((size_t)NSL * NA * 4);
    int* bh2  = (int*)alloc((size_t)NSL * NC * 4);
    (void)ws_size; (void)in_sizes; (void)n_in; (void)out_size;

    // ---- CSR build: r0/r2 counting sort; hist02 also zeroes deg13 + aggbuf
    hist02_kernel<<<2 * NSL, 256, 0, stream>>>(dst0, dst2, bh0, bh2, deg13, aggbuf);
    scan02_kernel<<<1, 512, 0, stream>>>(bh0, bh2, rp0, rp2, inv0, inv2);
    fill02_kernel<<<2 * NSL, 256, 0, stream>>>(src0, dst0, src2, dst2, bh0, bh2, csr0, csr2);

    // ---- CSR build: r1/r3 via atomics (100K dsts, avg degree 2.5 — cheap)
    deg_count_kernel<<<(2 * E + 255) / 256, 256, 0, stream>>>(dst1, dst3, deg1, deg3);
    scanA_kernel<<<196, 1024, 0, stream>>>(deg1, deg3, bsum);
    scanC_kernel<<<196, 1024, 0, stream>>>(deg1, deg3, bsum, rp1, rp3, cu1, cu3, inv1, inv3);
    csr_fill13_kernel<<<(2 * E + 255) / 256, 256, 0, stream>>>(
        src1, dst1, src3, dst3, cu1, cu3, csr1, csr3);

    // ---- fused encoders (single dispatch, all node types)
    encode_all_kernel<<<NF / 8 + (NA + 7) / 8 + (NC + 7) / 8, 256, 0, stream>>>(
        xf, Wf, bf, xa, Wa, ba, xc, Wc, bc, hH);

    // ---- layer 0: pure MFMA gemm -> G; then per-row-type finishers in place
    wsplit_kernel<<<D, D, 0, stream>>>(root0, WtH, WtL);
    wr_kernel<<<4 * DD / 256, 256, 0, stream>>>(basis0, comp0, wrbuf);
    y_kernel<<<NA + NC, 256, 0, stream>>>(hH, wrbuf, ybuf);
    gemm_mfma<<<dim3((NN + 127) / 128, 2), 512, 0, stream>>>(
        hH, WtH, WtL, bias0, gH, NN);
    agg_small_kernel<<<NA * 4 + NC * 64, 256, 0, stream>>>(
        hH, rp0, csr0, rp2, csr2, aggbuf);
    smallT_kernel<<<NA + NC, 256, 0, stream>>>(aggbuf, wrbuf, inv0, inv2, gH);
    msg_relu_kernel<<<(NF / 2 * 64 + 255) / 256, 256, 0, stream>>>(
        gH, ybuf, rp1, csr1, inv1, rp3, csr3, inv3);

    // ---- layer 1 (flights only): pure gemm -> G2 (aliases h); readout -> out
    wsplit_kernel<<<D, D, 0, stream>>>(root1, WtH, WtL);
    wr_kernel<<<4 * DD / 256, 256, 0, stream>>>(basis1, comp1, wrbuf);
    y_kernel<<<NA + NC, 256, 0, stream>>>(gH, wrbuf, ybuf);
    gemm_mfma<<<dim3((NF + 127) / 128, 2), 512, 0, stream>>>(
        gH, WtH, WtL, bias1, g2H, NF);
    msg_readout_kernel<<<(NF / 2 * 64 + 255) / 256, 256, 0, stream>>>(
        g2H, ybuf, rp1, csr1, inv1, rp3, csr3, inv3, Wout, bout, out);
}

// Round 20
// 369.919 us; speedup vs baseline: 1.1339x; 1.0640x over previous
//
#include <hip/hip_runtime.h>
#include <hip/hip_bf16.h>
#include <cstdint>
#include <cstddef>

constexpr int NF = 100000;
constexpr int NA = 400;
constexpr int NC = 30;
constexpr int NN = NF + NA + NC;     // 100430
constexpr int D  = 256;
constexpr int DD = D * D;            // 65536
constexpr int E  = 250000;
constexpr int NSL = 128;             // slices for r0/r2 counting sort
constexpr int FBLK = (NF + 127) / 128;   // 782 flight-encoder blocks

typedef __attribute__((ext_vector_type(8))) short bf16x8;
typedef __attribute__((ext_vector_type(4))) float f32x4;
typedef __attribute__((ext_vector_type(8))) ushort u16x8;

__device__ inline ushort f2bf(float f) {
    __hip_bfloat16 h = __float2bfloat16(f);
    return __builtin_bit_cast(ushort, h);
}
__device__ inline float bf2f(ushort u) {
    __hip_bfloat16 h = __builtin_bit_cast(__hip_bfloat16, u);
    return __bfloat162float(h);
}

// async global->LDS, 16B per lane: LDS dest = base + lane*16 (wave-linear)
__device__ inline void gload_lds16(const ushort* g, ushort* l) {
    __builtin_amdgcn_global_load_lds(
        (const __attribute__((address_space(1))) void*)g,
        (__attribute__((address_space(3))) void*)l, 16, 0, 0);
}

// ---- MFMA flight encoder + scalar tail for airports/carriers --------------
// Flights: h = relu(x @ Wf + bf) as [128x32]@[32x256] per block, bf16 x
// (in-register cvt) x split-Wf (WfTH+WfTL, exact), K=32 single MFMA step.
__global__ __launch_bounds__(512) void encode_mfma_kernel(
    const float* __restrict__ xf,
    const ushort* __restrict__ WtH8, const ushort* __restrict__ WtL8,
    const float* __restrict__ bfl,
    const float* __restrict__ xa, const float* __restrict__ Wa, const float* __restrict__ ba,
    const float* __restrict__ xc, const float* __restrict__ Wc, const float* __restrict__ bc,
    ushort* __restrict__ hH)
{
    const int t = threadIdx.x;
    const int b = blockIdx.x;
    if (b >= FBLK) {
        // ---- airports + carriers scalar path (54 tail blocks, 8 rows each)
        int c = t & 255;
        int i0 = t >> 8;                     // 0 or 1 (512 threads -> 2 rows/pass)
        int base = (b - FBLK) * 8;
        for (int i = i0; i < 8; i += 2) {
            int row = base + i;
            if (row >= NA + NC) break;
            float acc;
            if (row < NA) {
                const float* xr = xa + (size_t)row * 16;
                acc = ba[c];
                #pragma unroll
                for (int k = 0; k < 16; ++k) acc += xr[k] * Wa[k * D + c];
            } else {
                const float* xr = xc + (size_t)(row - NA) * 8;
                acc = bc[c];
                #pragma unroll
                for (int k = 0; k < 8; ++k) acc += xr[k] * Wc[k * D + c];
            }
            hH[(size_t)(NF + row) * D + c] = f2bf(fmaxf(acc, 0.f));
        }
        return;
    }
    // ---- flight MFMA path
    constexpr int AOFF = 0, WHOFF = 4096, WLOFF = 12288;   // ushort offsets
    __shared__ __align__(16) ushort lds[20480];            // 40960 B
    const int row0 = b * 128;
    const int w = t >> 6, lane = t & 63;     // 8 waves
    const int wm = w >> 2, wn = w & 3;       // 2x4 grid, 64 rows x 64 cols/wave
    const int lr = lane & 15;
    const int lk = lane >> 4;
    // stage A: thread t loads 8 fp32 of row (t>>2), cvt->bf16, fragment-major
    {
        int r = t >> 2;                      // 0..127
        int seg = (t & 3) * 8;               // 0,8,16,24
        int gr = row0 + r; if (gr >= NF) gr = NF - 1;
        const float* xr = xf + (size_t)gr * 32 + seg;
        float4 a0 = *(const float4*)xr;
        float4 a1 = *(const float4*)(xr + 4);
        u16x8 bb;
        bb[0] = f2bf(a0.x); bb[1] = f2bf(a0.y); bb[2] = f2bf(a0.z); bb[3] = f2bf(a0.w);
        bb[4] = f2bf(a1.x); bb[5] = f2bf(a1.y); bb[6] = f2bf(a1.z); bb[7] = f2bf(a1.w);
        int g = r >> 4, rr = r & 15, kg = seg >> 3;
        *(u16x8*)(lds + AOFF + g * 512 + (rr + 16 * kg) * 8) = bb;
    }
    // stage W via gload_lds16: 32 (plane,colgroup) units, 4 per wave
    #pragma unroll
    for (int i = 0; i < 4; ++i) {
        int u = w * 4 + i;                   // 0..31
        int plane = u >> 4, g = u & 15;
        const ushort* src = (plane ? WtL8 : WtH8) + ((size_t)(g * 16 + lr)) * 32 + lk * 8;
        ushort* dst = lds + (plane ? WLOFF : WHOFF) + g * 512;
        gload_lds16(src, dst);
    }
    __syncthreads();                         // drains vmcnt+lgkm: tiles ready
    f32x4 acc[4][4] = {};
    bf16x8 bhv[4], blv[4];
    #pragma unroll
    for (int ni = 0; ni < 4; ++ni) {
        int off = (wn * 4 + ni) * 512 + lane * 8;
        bhv[ni] = *(const bf16x8*)(lds + WHOFF + off);
        blv[ni] = *(const bf16x8*)(lds + WLOFF + off);
    }
    #pragma unroll
    for (int mi = 0; mi < 4; ++mi) {
        bf16x8 ah = *(const bf16x8*)(lds + AOFF + (wm * 4 + mi) * 512 + lane * 8);
        #pragma unroll
        for (int ni = 0; ni < 4; ++ni) {
            acc[mi][ni] = __builtin_amdgcn_mfma_f32_16x16x32_bf16(ah, bhv[ni], acc[mi][ni], 0, 0, 0);
            acc[mi][ni] = __builtin_amdgcn_mfma_f32_16x16x32_bf16(ah, blv[ni], acc[mi][ni], 0, 0, 0);
        }
    }
    // epilogue: per-mi 16x64 pass through LDS; bias + relu + coalesced stores
    constexpr int ELDW = 68;
    float* S = (float*)lds + (size_t)w * 16 * ELDW;   // 4352 B/wave * 8 = 34816
    const int rrow = lane >> 3;              // 0..7
    const int grp  = lane & 7;               // 8 cols each
    #pragma unroll
    for (int mi = 0; mi < 4; ++mi) {
        __syncthreads();
        #pragma unroll
        for (int ni = 0; ni < 4; ++ni)
            #pragma unroll
            for (int reg = 0; reg < 4; ++reg)
                S[(lk * 4 + reg) * ELDW + ni * 16 + lr] = acc[mi][ni][reg];
        __syncthreads();
        #pragma unroll
        for (int it = 0; it < 2; ++it) {
            int row_i = rrow + it * 8;
            int gr = row0 + wm * 64 + mi * 16 + row_i;
            int gc = wn * 64 + grp * 8;
            if (gr >= NF) continue;
            float4 f0 = *(const float4*)(&S[row_i * ELDW + grp * 8]);
            float4 f1 = *(const float4*)(&S[row_i * ELDW + grp * 8 + 4]);
            float4 b0 = *(const float4*)(bfl + gc);
            float4 b1 = *(const float4*)(bfl + gc + 4);
            u16x8 hh;
            hh[0] = f2bf(fmaxf(f0.x + b0.x, 0.f));
            hh[1] = f2bf(fmaxf(f0.y + b0.y, 0.f));
            hh[2] = f2bf(fmaxf(f0.z + b0.z, 0.f));
            hh[3] = f2bf(fmaxf(f0.w + b0.w, 0.f));
            hh[4] = f2bf(fmaxf(f1.x + b1.x, 0.f));
            hh[5] = f2bf(fmaxf(f1.y + b1.y, 0.f));
            hh[6] = f2bf(fmaxf(f1.z + b1.z, 0.f));
            hh[7] = f2bf(fmaxf(f1.w + b1.w, 0.f));
            *(u16x8*)(hH + (size_t)gr * D + gc) = hh;
        }
    }
}

// ---------------- weight split+transpose: root[k][n] -> WtH/WtL[n][k] -------
__global__ __launch_bounds__(256) void wsplit_kernel(
    const float* __restrict__ root, ushort* __restrict__ WtH, ushort* __restrict__ WtL)
{
    int n = blockIdx.x, k = threadIdx.x;
    float w = root[(size_t)k * D + n];
    ushort hi = f2bf(w);
    WtH[(size_t)n * D + k] = hi;
    WtL[(size_t)n * D + k] = f2bf(w - bf2f(hi));
}

// ---------------- basis combine: Wr[r] = sum_b comp[r,b] * basis[b] ---------
__global__ __launch_bounds__(256) void wr_kernel(
    const float* __restrict__ basis, const float* __restrict__ comp,
    float* __restrict__ wr)
{
    int idx = blockIdx.x * 256 + threadIdx.x;   // < 4*DD
    int r = idx >> 16;
    int io = idx & (DD - 1);
    wr[idx] = comp[r * 3 + 0] * basis[io]
            + comp[r * 3 + 1] * basis[DD + io]
            + comp[r * 3 + 2] * basis[2 * DD + io];
}

// ---------------- r1/r3 degree count (low contention: 100K dsts) ----------
__global__ __launch_bounds__(256) void deg_count_kernel(
    const int* __restrict__ dst1, const int* __restrict__ dst3,
    int* __restrict__ deg1, int* __restrict__ deg3)
{
    int idx = blockIdx.x * 256 + threadIdx.x;
    if (idx >= 2 * E) return;
    if (idx < E) atomicAdd(&deg1[dst1[idx]], 1);
    else         atomicAdd(&deg3[dst3[idx - E]], 1);
}

// ---- r0/r2 per-slice LDS histograms; also zeroes deg13 & aggbuf and
// produces the flight-encoder weight transpose split (blocks 0..31) ---------
__global__ __launch_bounds__(256) void hist02_kernel(
    const int* __restrict__ dst0, const int* __restrict__ dst2,
    int* __restrict__ bh0, int* __restrict__ bh2,
    int* __restrict__ deg13z, float* __restrict__ aggz,
    const float* __restrict__ Wf, ushort* __restrict__ WfTH, ushort* __restrict__ WfTL)
{
    __shared__ int hist[NA];
    int b = blockIdx.x;                 // 0..2*NSL-1
    // folded memsets (grid-strided)
    for (int i = b * 256 + threadIdx.x; i < 2 * NF; i += 2 * NSL * 256)
        deg13z[i] = 0;
    for (int i = b * 256 + threadIdx.x; i < (NA + NC) * D; i += 2 * NSL * 256)
        aggz[i] = 0.f;
    // folded flight-W transpose+split: block b<32 handles k=b, thread=col n
    if (b < 32) {
        int n = threadIdx.x;
        float wv = Wf[(size_t)b * D + n];
        ushort hi = f2bf(wv);
        WfTH[(size_t)n * 32 + b] = hi;
        WfTL[(size_t)n * 32 + b] = f2bf(wv - bf2f(hi));
    }
    bool isR2 = (b >= NSL);
    int sl = isR2 ? b - NSL : b;
    const int* dst = isR2 ? dst2 : dst0;
    int nb = isR2 ? NC : NA;
    for (int i = threadIdx.x; i < nb; i += 256) hist[i] = 0;
    __syncthreads();
    int lo = (int)((long long)E * sl / NSL);
    int hi = (int)((long long)E * (sl + 1) / NSL);
    for (int e = lo + threadIdx.x; e < hi; e += 256)
        atomicAdd(&hist[dst[e]], 1);
    __syncthreads();
    int* bh = isR2 ? (bh2 + sl * NC) : (bh0 + sl * NA);
    for (int i = threadIdx.x; i < nb; i += 256) bh[i] = hist[i];
}

// -------- scan: per-bin over slices + cross-bin; emits rp/inv + abs offsets -
__global__ __launch_bounds__(512) void scan02_kernel(
    int* __restrict__ bh0, int* __restrict__ bh2,
    int* __restrict__ rp0, int* __restrict__ rp2,
    float* __restrict__ inv0, float* __restrict__ inv2)
{
    __shared__ int tot[512];
    __shared__ int exc[512];
    int t = threadIdx.x;
    int cnt = 0;
    if (t < NA) {
        int s = 0;
        for (int sl = 0; sl < NSL; ++sl) {
            int v = bh0[sl * NA + t]; bh0[sl * NA + t] = s; s += v;
        }
        cnt = s;
    } else if (t < NA + NC) {
        int bin = t - NA; int s = 0;
        for (int sl = 0; sl < NSL; ++sl) {
            int v = bh2[sl * NC + bin]; bh2[sl * NC + bin] = s; s += v;
        }
        cnt = s;
    }
    tot[t] = cnt;
    __syncthreads();
    for (int ofs = 1; ofs < 512; ofs <<= 1) {
        int v = (t >= ofs) ? tot[t - ofs] : 0;
        __syncthreads();
        tot[t] += v;
        __syncthreads();
    }
    int ex = tot[t] - cnt;              // exclusive over combined [r0 | r2]
    if (t < NA) {
        exc[t] = ex;
        rp0[t] = ex;
        inv0[t] = 1.0f / (float)(cnt > 1 ? cnt : 1);
        if (t == 0) { rp0[NA] = E; rp2[NC] = E; }
    } else if (t < NA + NC) {
        exc[t] = ex - E;                // r2 csr buffer is its own array
        rp2[t - NA] = ex - E;
        inv2[t - NA] = 1.0f / (float)(cnt > 1 ? cnt : 1);
    } else exc[t] = 0;
    __syncthreads();
    for (int idx = t; idx < NSL * NA; idx += 512) {
        int sl = idx / NA; int bin = idx - sl * NA;
        bh0[idx] += exc[bin];
    }
    for (int idx = t; idx < NSL * NC; idx += 512) {
        int sl = idx / NC; int bin = idx - sl * NC;
        bh2[idx] += exc[NA + bin];
    }
}

// ---------------- r0/r2 CSR fill with LDS cursors --------------------------
__global__ __launch_bounds__(256) void fill02_kernel(
    const int* __restrict__ src0, const int* __restrict__ dst0,
    const int* __restrict__ src2, const int* __restrict__ dst2,
    const int* __restrict__ bh0, const int* __restrict__ bh2,
    int* __restrict__ csr0, int* __restrict__ csr2)
{
    __shared__ int cur[NA];
    int b = blockIdx.x;
    bool isR2 = (b >= NSL);
    int sl = isR2 ? b - NSL : b;
    const int* src = isR2 ? src2 : src0;
    const int* dst = isR2 ? dst2 : dst0;
    const int* bh  = isR2 ? (bh2 + sl * NC) : (bh0 + sl * NA);
    int* csr       = isR2 ? csr2 : csr0;
    int nb = isR2 ? NC : NA;
    for (int i = threadIdx.x; i < nb; i += 256) cur[i] = bh[i];
    __syncthreads();
    int lo = (int)((long long)E * sl / NSL);
    int hi = (int)((long long)E * (sl + 1) / NSL);
    for (int e = lo + threadIdx.x; e < hi; e += 256) {
        int pos = atomicAdd(&cur[dst[e]], 1);
        csr[pos] = src[e];
    }
}

// ---------------- r1/r3 scan chain -----------------------------------------
__global__ __launch_bounds__(1024) void scanA_kernel(
    const int* __restrict__ deg1, const int* __restrict__ deg3, int* __restrict__ bsum)
{
    __shared__ int s[1024];
    int b = blockIdx.x;                    // 0..195
    bool isR3 = (b >= 98);
    const int* deg = isR3 ? deg3 : deg1;
    int chunk = isR3 ? b - 98 : b;
    int i = chunk * 1024 + threadIdx.x;
    int v = (i < NF) ? deg[i] : 0;
    s[threadIdx.x] = v;
    __syncthreads();
    for (int ofs = 512; ofs > 0; ofs >>= 1) {
        if ((int)threadIdx.x < ofs) s[threadIdx.x] += s[threadIdx.x + ofs];
        __syncthreads();
    }
    if (threadIdx.x == 0) bsum[(isR3 ? 128 : 0) + chunk] = s[0];
}

// scanC with the scanB 196-entry exclusive scan inlined
__global__ __launch_bounds__(1024) void scanC_kernel(
    const int* __restrict__ deg1, const int* __restrict__ deg3,
    const int* __restrict__ bsum,
    int* __restrict__ rp1, int* __restrict__ rp3,
    int* __restrict__ cu1, int* __restrict__ cu3,
    float* __restrict__ inv1, float* __restrict__ inv3)
{
    __shared__ int s[1024];
    __shared__ int s2[256];
    int tid = threadIdx.x;
    int b = blockIdx.x;                    // 0..195
    int vb = 0;
    if (tid < 256) {
        vb = ((tid & 127) < 98) ? bsum[tid] : 0;
        s2[tid] = vb;
    }
    __syncthreads();
    for (int ofs = 1; ofs < 128; ofs <<= 1) {
        int a = 0;
        if (tid < 256 && (tid & 127) >= ofs) a = s2[tid - ofs];
        __syncthreads();
        if (tid < 256) s2[tid] += a;
        __syncthreads();
    }
    if (tid < 256) s2[tid] -= vb;          // exclusive
    __syncthreads();
    const int* deg; int* rp; int* cu; float* inv; int chunk; int prefix;
    if (b < 98) { deg = deg1; rp = rp1; cu = cu1; inv = inv1; chunk = b;      prefix = s2[chunk]; }
    else        { deg = deg3; rp = rp3; cu = cu3; inv = inv3; chunk = b - 98; prefix = s2[128 + chunk]; }
    int i = chunk * 1024 + tid;
    int v = (i < NF) ? deg[i] : 0;
    s[tid] = v;
    __syncthreads();
    for (int ofs = 1; ofs < 1024; ofs <<= 1) {
        int a = (tid >= ofs) ? s[tid - ofs] : 0;
        __syncthreads();
        s[tid] += a;
        __syncthreads();
    }
    int ex = prefix + s[tid] - v;
    if (i < NF) {
        rp[i] = ex;
        cu[i] = ex;
        inv[i] = 1.0f / (float)(v > 1 ? v : 1);
    }
    if (i == 0) rp[NF] = E;
}

__global__ __launch_bounds__(256) void csr_fill13_kernel(
    const int* __restrict__ src1, const int* __restrict__ dst1,
    const int* __restrict__ src3, const int* __restrict__ dst3,
    int* __restrict__ cu1, int* __restrict__ cu3,
    int* __restrict__ csr1, int* __restrict__ csr3)
{
    int idx = blockIdx.x * 256 + threadIdx.x;
    if (idx >= 2 * E) return;
    if (idx < E) {
        int pos = atomicAdd(&cu1[dst1[idx]], 1);
        csr1[pos] = src1[idx];
    } else {
        int e = idx - E;
        int pos = atomicAdd(&cu3[dst3[e]], 1);
        csr3[pos] = src3[e];
    }
}

// ------- y = h[src-type rows] @ Wr[rel]  (Wr precomputed) -------------------
__global__ __launch_bounds__(256) void y_kernel(
    const ushort* __restrict__ hH, const float* __restrict__ wr,
    float* __restrict__ y)
{
    int row = blockIdx.x;            // 0..429  (airports then carriers)
    int c = threadIdx.x;
    const ushort* sH = hH + (size_t)(NF + row) * D;
    const float* W = wr + (size_t)((row < NA) ? 1 : 3) * DD;
    float acc = 0.f;
    #pragma unroll 8
    for (int k = 0; k < D; ++k) acc += bf2f(sH[k]) * W[k * D + c];
    y[(size_t)row * D + c] = acc;
}

// ---- bf16 MFMA GEMM: G = A @ root^T + bias (A single-plane, W split) ------
// 8 waves, 64x32 sub-tiles, fragment-major global_load_lds staging, 3-buffer
// pipeline with COUNTED vmcnt (never drains in steady state).
__global__ __launch_bounds__(512) void gemm_mfma(
    const ushort* __restrict__ A,
    const ushort* __restrict__ WtH, const ushort* __restrict__ WtL,
    const float* __restrict__ bias,
    ushort* __restrict__ G, int nrows)
{
    constexpr int BM = 128, BK = 32;
    constexpr int PLANE = BM * BK;          // 4096 ushorts = 8 KB
    constexpr int BUF = 3 * PLANE;          // 12288 ushorts = 24 KB
    constexpr int LDW = 36;                 // fp32 epilogue scratch stride
    __shared__ __align__(16) ushort lds[3 * BUF];   // 73728 B (3 buffers)
    const int t = threadIdx.x;
    const int row0 = blockIdx.x * BM;
    const int col0 = blockIdx.y * BM;
    const int w = t >> 6, lane = t & 63;    // 8 waves
    const int wm = w >> 2, wn = w & 3;      // 2x4 wave grid, 64x32 per wave
    const int lr = lane & 15;
    const int lk = lane >> 4;
    f32x4 acc[4][2] = {};

    // staging: 24 (plane,group) units, wave w handles 3 consecutive
    const ushort* sp[3];
    int dofs[3];
    #pragma unroll
    for (int i = 0; i < 3; ++i) {
        int idx = w * 3 + i;
        int plane = idx >> 3, g = idx & 7;
        const ushort* base = (plane == 0) ? A : (plane == 1) ? WtH : WtL;
        int r = ((plane == 0) ? row0 : col0) + g * 16 + lr;
        if (plane == 0 && r >= nrows) r = nrows - 1;
        sp[i] = base + (size_t)r * D + lk * 8;
        dofs[i] = plane * PLANE + g * 512;
    }

    auto stage = [&](int kt, int buf) {
        ushort* bb = lds + buf * BUF;
        int k0 = kt * BK;
        #pragma unroll
        for (int i = 0; i < 3; ++i)
            gload_lds16(sp[i] + k0, bb + dofs[i]);
    };
    auto compute = [&](int buf) {
        const ushort* base = lds + buf * BUF;
        const ushort* As  = base;
        const ushort* WsH = base + PLANE;
        const ushort* WsL = base + 2 * PLANE;
        bf16x8 bh[2], bl[2];
        #pragma unroll
        for (int ni = 0; ni < 2; ++ni) {
            int off = (wn * 2 + ni) * 512 + lane * 8;
            bh[ni] = *(const bf16x8*)(&WsH[off]);
            bl[ni] = *(const bf16x8*)(&WsL[off]);
        }
        #pragma unroll
        for (int mi = 0; mi < 4; ++mi) {
            int off = (wm * 4 + mi) * 512 + lane * 8;
            bf16x8 ah = *(const bf16x8*)(&As[off]);
            #pragma unroll
            for (int ni = 0; ni < 2; ++ni) {
                acc[mi][ni] = __builtin_amdgcn_mfma_f32_16x16x32_bf16(ah, bh[ni], acc[mi][ni], 0, 0, 0);
                acc[mi][ni] = __builtin_amdgcn_mfma_f32_16x16x32_bf16(ah, bl[ni], acc[mi][ni], 0, 0, 0);
            }
        }
    };

    // prologue: 3 stages in flight (9 loads/wave)
    stage(0, 0);
    stage(1, 1);
    stage(2, 2);
#define PIPE_ITER(KT, PEND)                                        \
    asm volatile("s_waitcnt vmcnt(" #PEND ")" ::: "memory");       \
    __builtin_amdgcn_s_barrier();                                  \
    __builtin_amdgcn_sched_barrier(0);                             \
    compute((KT) % 3);                                             \
    __builtin_amdgcn_s_barrier();                                  \
    __builtin_amdgcn_sched_barrier(0);                             \
    if ((KT) + 3 < 8) stage((KT) + 3, (KT) % 3);
    PIPE_ITER(0, 6)
    PIPE_ITER(1, 6)
    PIPE_ITER(2, 6)
    PIPE_ITER(3, 6)
    PIPE_ITER(4, 6)
    PIPE_ITER(5, 6)
    PIPE_ITER(6, 3)
    PIPE_ITER(7, 0)
#undef PIPE_ITER

    // ---- epilogue: per-mi 16x32 pass through LDS, coalesced 16B stores -----
    __syncthreads();                         // everyone done with buffers
    float* S = (float*)lds + (size_t)w * 16 * LDW;   // per-wave 16x36 fp32
    const int rrow = lane >> 2;            // 0..15 read-back row
    const int grp  = lane & 3;             // col octet (8 bf16)
    #pragma unroll
    for (int mi = 0; mi < 4; ++mi) {
        __syncthreads();
        #pragma unroll
        for (int ni = 0; ni < 2; ++ni)
            #pragma unroll
            for (int reg = 0; reg < 4; ++reg)
                S[(lk * 4 + reg) * LDW + ni * 16 + lr] = acc[mi][ni][reg];
        __syncthreads();
        int gr = row0 + wm * 64 + mi * 16 + rrow;
        int gc = col0 + wn * 32 + grp * 8;
        if (gr >= nrows) continue;
        float4 f0 = *(const float4*)(&S[rrow * LDW + grp * 8]);
        float4 f1 = *(const float4*)(&S[rrow * LDW + grp * 8 + 4]);
        float4 b0 = *(const float4*)(bias + gc);
        float4 b1 = *(const float4*)(bias + gc + 4);
        float v[8] = {f0.x + b0.x, f0.y + b0.y, f0.z + b0.z, f0.w + b0.w,
                      f1.x + b1.x, f1.y + b1.y, f1.z + b1.z, f1.w + b1.w};
        u16x8 hh;
        #pragma unroll
        for (int j = 0; j < 8; ++j) hh[j] = f2bf(v[j]);
        *(u16x8*)(G + (size_t)gr * D + gc) = hh;
    }
}

// ---- layer-0 flight rows: G = relu(G + inv1*Σy1 + inv3*Σy3) in place ------
// 2 rows per wave: lanes 0-31 row 2w, lanes 32-63 row 2w+1; 8 ch/lane.
__global__ __launch_bounds__(256) void msg_relu_kernel(
    ushort* __restrict__ G,
    const float* __restrict__ y,
    const int* __restrict__ rp1, const int* __restrict__ csr1, const float* __restrict__ inv1,
    const int* __restrict__ rp3, const int* __restrict__ csr3, const float* __restrict__ inv3)
{
    int wid = (blockIdx.x * 256 + threadIdx.x) >> 6;
    int lane = threadIdx.x & 63;
    int row = wid * 2 + (lane >> 5);
    if (row >= NF) return;
    int c = (lane & 31) * 8;
    size_t o = (size_t)row * D + c;
    u16x8 gh = *(const u16x8*)(G + o);
    float v[8];
    #pragma unroll
    for (int j = 0; j < 8; ++j) v[j] = bf2f(gh[j]);
    float m[8] = {};
    int e0 = rp1[row], e1 = rp1[row + 1];
    for (int e = e0; e < e1; ++e) {
        const float* yr = y + (size_t)csr1[e] * D + c;
        float4 u0 = *(const float4*)yr;
        float4 u1 = *(const float4*)(yr + 4);
        m[0] += u0.x; m[1] += u0.y; m[2] += u0.z; m[3] += u0.w;
        m[4] += u1.x; m[5] += u1.y; m[6] += u1.z; m[7] += u1.w;
    }
    float s1 = inv1[row];
    #pragma unroll
    for (int j = 0; j < 8; ++j) { v[j] += s1 * m[j]; m[j] = 0.f; }
    e0 = rp3[row]; e1 = rp3[row + 1];
    for (int e = e0; e < e1; ++e) {
        const float* yr = y + (size_t)(NA + csr3[e]) * D + c;
        float4 u0 = *(const float4*)yr;
        float4 u1 = *(const float4*)(yr + 4);
        m[0] += u0.x; m[1] += u0.y; m[2] += u0.z; m[3] += u0.w;
        m[4] += u1.x; m[5] += u1.y; m[6] += u1.z; m[7] += u1.w;
    }
    float s3 = inv3[row];
    u16x8 oh;
    #pragma unroll
    for (int j = 0; j < 8; ++j) oh[j] = f2bf(fmaxf(v[j] + s3 * m[j], 0.f));
    *(u16x8*)(G + o) = oh;
}

// ---- layer-1: out[f] = relu(G2+msgs) . W_out + b_out (fused readout) -------
__global__ __launch_bounds__(256) void msg_readout_kernel(
    const ushort* __restrict__ G,
    const float* __restrict__ y,
    const int* __restrict__ rp1, const int* __restrict__ csr1, const float* __restrict__ inv1,
    const int* __restrict__ rp3, const int* __restrict__ csr3, const float* __restrict__ inv3,
    const float* __restrict__ wout, const float* __restrict__ bout,
    float* __restrict__ out)
{
    int wid = (blockIdx.x * 256 + threadIdx.x) >> 6;
    int lane = threadIdx.x & 63;
    int row = wid * 2 + (lane >> 5);
    if (row >= NF) return;
    int c = (lane & 31) * 8;
    size_t o = (size_t)row * D + c;
    u16x8 gh = *(const u16x8*)(G + o);
    float v[8];
    #pragma unroll
    for (int j = 0; j < 8; ++j) v[j] = bf2f(gh[j]);
    float m[8] = {};
    int e0 = rp1[row], e1 = rp1[row + 1];
    for (int e = e0; e < e1; ++e) {
        const float* yr = y + (size_t)csr1[e] * D + c;
        float4 u0 = *(const float4*)yr;
        float4 u1 = *(const float4*)(yr + 4);
        m[0] += u0.x; m[1] += u0.y; m[2] += u0.z; m[3] += u0.w;
        m[4] += u1.x; m[5] += u1.y; m[6] += u1.z; m[7] += u1.w;
    }
    float s1 = inv1[row];
    #pragma unroll
    for (int j = 0; j < 8; ++j) { v[j] += s1 * m[j]; m[j] = 0.f; }
    e0 = rp3[row]; e1 = rp3[row + 1];
    for (int e = e0; e < e1; ++e) {
        const float* yr = y + (size_t)(NA + csr3[e]) * D + c;
        float4 u0 = *(const float4*)yr;
        float4 u1 = *(const float4*)(yr + 4);
        m[0] += u0.x; m[1] += u0.y; m[2] += u0.z; m[3] += u0.w;
        m[4] += u1.x; m[5] += u1.y; m[6] += u1.z; m[7] += u1.w;
    }
    float s3 = inv3[row];
    float4 w0 = *(const float4*)(wout + c);
    float4 w1 = *(const float4*)(wout + c + 4);
    float wv[8] = {w0.x, w0.y, w0.z, w0.w, w1.x, w1.y, w1.z, w1.w};
    float pr = 0.f;
    #pragma unroll
    for (int j = 0; j < 8; ++j) pr += fmaxf(v[j] + s3 * m[j], 0.f) * wv[j];
    pr += __shfl_xor(pr, 1);
    pr += __shfl_xor(pr, 2);
    pr += __shfl_xor(pr, 4);
    pr += __shfl_xor(pr, 8);
    pr += __shfl_xor(pr, 16);
    if ((lane & 31) == 0) out[row] = pr + bout[0];
}

// ---- r0/r2: agg[dst] += hH[src] — 2 edges per wave, 16B/lane loads ---------
__global__ __launch_bounds__(256) void agg_small_kernel(
    const ushort* __restrict__ hH,
    const int* __restrict__ rp0, const int* __restrict__ csr0,
    const int* __restrict__ rp2, const int* __restrict__ csr2,
    float* __restrict__ agg)
{
    __shared__ float red[4][256];
    int b = blockIdx.x;
    const int* rp; const int* csr; int dstn, chunk, nch; float* arow;
    if (b < NA * 4) { dstn = b >> 2; chunk = b & 3; nch = 4;  rp = rp0; csr = csr0; arow = agg + (size_t)dstn * D; }
    else { int bb = b - NA * 4; dstn = bb >> 6; chunk = bb & 63; nch = 64; rp = rp2; csr = csr2; arow = agg + (size_t)(NA + dstn) * D; }
    int s = rp[dstn], e = rp[dstn + 1];
    int cnt = e - s;
    int lo = s + (int)((long long)cnt * chunk / nch);
    int hi = s + (int)((long long)cnt * (chunk + 1) / nch);
    int w = threadIdx.x >> 6, lane = threadIdx.x & 63;
    int span = hi - lo;
    int wlo = lo + (int)((long long)span * w / 4);
    int whi = lo + (int)((long long)span * (w + 1) / 4);
    int half = lane >> 5;                  // 0: edge p, 1: edge p+1
    int ch8 = (lane & 31) * 8;
    float acc[8] = {};
    int p = wlo;
    for (; p + 1 < whi; p += 2) {
        int r = csr[p + half];
        u16x8 v = *(const u16x8*)(hH + (size_t)r * D + ch8);
        #pragma unroll
        for (int j = 0; j < 8; ++j) acc[j] += bf2f(v[j]);
    }
    if (p < whi && half == 0) {
        int r = csr[p];
        u16x8 v = *(const u16x8*)(hH + (size_t)r * D + ch8);
        #pragma unroll
        for (int j = 0; j < 8; ++j) acc[j] += bf2f(v[j]);
    }
    #pragma unroll
    for (int j = 0; j < 8; ++j) acc[j] += __shfl_xor(acc[j], 32);
    if (lane < 32) {
        #pragma unroll
        for (int j = 0; j < 8; ++j) red[w][ch8 + j] = acc[j];
    }
    __syncthreads();
    int c = threadIdx.x;
    float total = red[0][c] + red[1][c] + red[2][c] + red[3][c];
    atomicAdd(arow + c, total);
}

// -- r0/r2 transform: G = relu(G + inv_deg*(agg @ Wr[rel])) in place ---------
__global__ __launch_bounds__(256) void smallT_kernel(
    const float* __restrict__ agg, const float* __restrict__ wr,
    const float* __restrict__ inv0, const float* __restrict__ inv2,
    ushort* __restrict__ G)
{
    int row = blockIdx.x;            // 0..429
    int c = threadIdx.x;
    const float* a = agg + (size_t)row * D;
    const float* W = wr + (size_t)((row < NA) ? 0 : 2) * DD;
    float scale = (row < NA) ? inv0[row] : inv2[row - NA];
    float acc = 0.f;
    #pragma unroll 8
    for (int k = 0; k < D; ++k) acc += a[k] * W[k * D + c];
    size_t o = (size_t)(NF + row) * D + c;
    G[o] = f2bf(fmaxf(bf2f(G[o]) + scale * acc, 0.f));
}

extern "C" void kernel_launch(void* const* d_in, const int* in_sizes, int n_in,
                              void* d_out, int out_size, void* d_ws, size_t ws_size,
                              hipStream_t stream)
{
    const float* xf = (const float*)d_in[0];
    const float* xa = (const float*)d_in[1];
    const float* xc = (const float*)d_in[2];
    const float* Wf = (const float*)d_in[3];
    const float* bf = (const float*)d_in[4];
    const float* Wa = (const float*)d_in[5];
    const float* ba = (const float*)d_in[6];
    const float* Wc = (const float*)d_in[7];
    const float* bc = (const float*)d_in[8];
    const float* basis0 = (const float*)d_in[9];
    const float* comp0  = (const float*)d_in[10];
    const float* root0  = (const float*)d_in[11];
    const float* bias0  = (const float*)d_in[12];
    const float* basis1 = (const float*)d_in[13];
    const float* comp1  = (const float*)d_in[14];
    const float* root1  = (const float*)d_in[15];
    const float* bias1  = (const float*)d_in[16];
    const float* Wout = (const float*)d_in[17];
    const float* bout = (const float*)d_in[18];
    const int* src0 = (const int*)d_in[19];
    const int* dst0 = (const int*)d_in[20];
    const int* src1 = (const int*)d_in[21];
    const int* dst1 = (const int*)d_in[22];
    const int* src2 = (const int*)d_in[23];
    const int* dst2 = (const int*)d_in[24];
    const int* src3 = (const int*)d_in[25];
    const int* dst3 = (const int*)d_in[26];
    float* out = (float*)d_out;

    char* ws = (char*)d_ws;
    size_t off = 0;
    auto alloc = [&](size_t bytes) -> char* {
        char* p = ws + off;
        off = (off + bytes + 255) & ~(size_t)255;
        return p;
    };
    ushort* hH  = (ushort*)alloc((size_t)NN * D * 2);
    ushort* gH  = (ushort*)alloc((size_t)NN * D * 2);
    // layer-1 GEMM output reuses hH (dead after layer-0 consumers)
    ushort* g2H = hH;
    ushort* WtH = (ushort*)alloc((size_t)DD * 2);
    ushort* WtL = (ushort*)alloc((size_t)DD * 2);
    ushort* WfTH = (ushort*)alloc((size_t)D * 32 * 2);
    ushort* WfTL = (ushort*)alloc((size_t)D * 32 * 2);
    float* wrbuf  = (float*)alloc((size_t)4 * DD * 4);
    float* ybuf   = (float*)alloc((size_t)(NA + NC) * D * 4);
    float* aggbuf = (float*)alloc((size_t)(NA + NC) * D * 4);
    int*   deg13  = (int*)  alloc((size_t)2 * NF * 4);
    int* deg1 = deg13; int* deg3 = deg13 + NF;
    float* inv1 = (float*)alloc((size_t)NF * 4);
    float* inv3 = (float*)alloc((size_t)NF * 4);
    float* inv0 = (float*)alloc((size_t)NA * 4);
    float* inv2 = (float*)alloc((size_t)NC * 4);
    int* rp0 = (int*)alloc((NA + 1) * 4);
    int* rp1 = (int*)alloc((size_t)(NF + 1) * 4);
    int* rp2 = (int*)alloc((NC + 1) * 4);
    int* rp3 = (int*)alloc((size_t)(NF + 1) * 4);
    int* cu1 = (int*)alloc((size_t)(NF + 1) * 4);
    int* cu3 = (int*)alloc((size_t)(NF + 1) * 4);
    int* csr0 = (int*)alloc((size_t)E * 4);
    int* csr1 = (int*)alloc((size_t)E * 4);
    int* csr2 = (int*)alloc((size_t)E * 4);
    int* csr3 = (int*)alloc((size_t)E * 4);
    int* bsum = (int*)alloc(256 * 4);
    int* bh0  = (int*)alloc((size_t)NSL * NA * 4);
    int* bh2  = (int*)alloc((size_t)NSL * NC * 4);
    (void)ws_size; (void)in_sizes; (void)n_in; (void)out_size;

    // ---- CSR build: r0/r2 counting sort; hist02 also zeroes deg13 + aggbuf
    //      and produces the flight-encoder weight transpose split
    hist02_kernel<<<2 * NSL, 256, 0, stream>>>(dst0, dst2, bh0, bh2, deg13, aggbuf,
                                               Wf, WfTH, WfTL);
    scan02_kernel<<<1, 512, 0, stream>>>(bh0, bh2, rp0, rp2, inv0, inv2);
    fill02_kernel<<<2 * NSL, 256, 0, stream>>>(src0, dst0, src2, dst2, bh0, bh2, csr0, csr2);

    // ---- CSR build: r1/r3 via atomics (100K dsts, avg degree 2.5 — cheap)
    deg_count_kernel<<<(2 * E + 255) / 256, 256, 0, stream>>>(dst1, dst3, deg1, deg3);
    scanA_kernel<<<196, 1024, 0, stream>>>(deg1, deg3, bsum);
    scanC_kernel<<<196, 1024, 0, stream>>>(deg1, deg3, bsum, rp1, rp3, cu1, cu3, inv1, inv3);
    csr_fill13_kernel<<<(2 * E + 255) / 256, 256, 0, stream>>>(
        src1, dst1, src3, dst3, cu1, cu3, csr1, csr3);

    // ---- MFMA flight encoder + scalar airports/carriers tail (one dispatch)
    encode_mfma_kernel<<<FBLK + (NA + NC + 7) / 8, 512, 0, stream>>>(
        xf, WfTH, WfTL, bf, xa, Wa, ba, xc, Wc, bc, hH);

    // ---- layer 0: pure MFMA gemm -> G; then per-row-type finishers in place
    wsplit_kernel<<<D, D, 0, stream>>>(root0, WtH, WtL);
    wr_kernel<<<4 * DD / 256, 256, 0, stream>>>(basis0, comp0, wrbuf);
    y_kernel<<<NA + NC, 256, 0, stream>>>(hH, wrbuf, ybuf);
    gemm_mfma<<<dim3((NN + 127) / 128, 2), 512, 0, stream>>>(
        hH, WtH, WtL, bias0, gH, NN);
    agg_small_kernel<<<NA * 4 + NC * 64, 256, 0, stream>>>(
        hH, rp0, csr0, rp2, csr2, aggbuf);
    smallT_kernel<<<NA + NC, 256, 0, stream>>>(aggbuf, wrbuf, inv0, inv2, gH);
    msg_relu_kernel<<<(NF / 2 * 64 + 255) / 256, 256, 0, stream>>>(
        gH, ybuf, rp1, csr1, inv1, rp3, csr3, inv3);

    // ---- layer 1 (flights only): pure gemm -> G2 (aliases h); readout -> out
    wsplit_kernel<<<D, D, 0, stream>>>(root1, WtH, WtL);
    wr_kernel<<<4 * DD / 256, 256, 0, stream>>>(basis1, comp1, wrbuf);
    y_kernel<<<NA + NC, 256, 0, stream>>>(gH, wrbuf, ybuf);
    gemm_mfma<<<dim3((NF + 127) / 128, 2), 512, 0, stream>>>(
        gH, WtH, WtL, bias1, g2H, NF);
    msg_readout_kernel<<<(NF / 2 * 64 + 255) / 256, 256, 0, stream>>>(
        g2H, ybuf, rp1, csr1, inv1, rp3, csr3, inv3, Wout, bout, out);
}

// Round 21
// 368.029 us; speedup vs baseline: 1.1397x; 1.0051x over previous
//
#include <hip/hip_runtime.h>
#include <hip/hip_bf16.h>
#include <cstdint>
#include <cstddef>

constexpr int NF = 100000;
constexpr int NA = 400;
constexpr int NC = 30;
constexpr int NN = NF + NA + NC;     // 100430
constexpr int D  = 256;
constexpr int DD = D * D;            // 65536
constexpr int E  = 250000;
constexpr int NSL = 128;             // slices for r0/r2 counting sort
constexpr int FBLK = (NF + 127) / 128;   // 782 flight-encoder blocks

typedef __attribute__((ext_vector_type(8))) short bf16x8;
typedef __attribute__((ext_vector_type(4))) float f32x4;
typedef __attribute__((ext_vector_type(8))) ushort u16x8;

__device__ inline ushort f2bf(float f) {
    __hip_bfloat16 h = __float2bfloat16(f);
    return __builtin_bit_cast(ushort, h);
}
__device__ inline float bf2f(ushort u) {
    __hip_bfloat16 h = __builtin_bit_cast(__hip_bfloat16, u);
    return __bfloat162float(h);
}

// async global->LDS, 16B per lane: LDS dest = base + lane*16 (wave-linear)
__device__ inline void gload_lds16(const ushort* g, ushort* l) {
    __builtin_amdgcn_global_load_lds(
        (const __attribute__((address_space(1))) void*)g,
        (__attribute__((address_space(3))) void*)l, 16, 0, 0);
}

// ---- MFMA flight encoder + scalar tail for airports/carriers --------------
__global__ __launch_bounds__(512) void encode_mfma_kernel(
    const float* __restrict__ xf,
    const ushort* __restrict__ WtH8, const ushort* __restrict__ WtL8,
    const float* __restrict__ bfl,
    const float* __restrict__ xa, const float* __restrict__ Wa, const float* __restrict__ ba,
    const float* __restrict__ xc, const float* __restrict__ Wc, const float* __restrict__ bc,
    ushort* __restrict__ hH)
{
    const int t = threadIdx.x;
    const int b = blockIdx.x;
    if (b >= FBLK) {
        int c = t & 255;
        int i0 = t >> 8;
        int base = (b - FBLK) * 8;
        for (int i = i0; i < 8; i += 2) {
            int row = base + i;
            if (row >= NA + NC) break;
            float acc;
            if (row < NA) {
                const float* xr = xa + (size_t)row * 16;
                acc = ba[c];
                #pragma unroll
                for (int k = 0; k < 16; ++k) acc += xr[k] * Wa[k * D + c];
            } else {
                const float* xr = xc + (size_t)(row - NA) * 8;
                acc = bc[c];
                #pragma unroll
                for (int k = 0; k < 8; ++k) acc += xr[k] * Wc[k * D + c];
            }
            hH[(size_t)(NF + row) * D + c] = f2bf(fmaxf(acc, 0.f));
        }
        return;
    }
    constexpr int AOFF = 0, WHOFF = 4096, WLOFF = 12288;   // ushort offsets
    __shared__ __align__(16) ushort lds[20480];            // 40960 B
    const int row0 = b * 128;
    const int w = t >> 6, lane = t & 63;     // 8 waves
    const int wm = w >> 2, wn = w & 3;       // 2x4 grid, 64 rows x 64 cols/wave
    const int lr = lane & 15;
    const int lk = lane >> 4;
    {
        int r = t >> 2;                      // 0..127
        int seg = (t & 3) * 8;               // 0,8,16,24
        int gr = row0 + r; if (gr >= NF) gr = NF - 1;
        const float* xr = xf + (size_t)gr * 32 + seg;
        float4 a0 = *(const float4*)xr;
        float4 a1 = *(const float4*)(xr + 4);
        u16x8 bb;
        bb[0] = f2bf(a0.x); bb[1] = f2bf(a0.y); bb[2] = f2bf(a0.z); bb[3] = f2bf(a0.w);
        bb[4] = f2bf(a1.x); bb[5] = f2bf(a1.y); bb[6] = f2bf(a1.z); bb[7] = f2bf(a1.w);
        int g = r >> 4, rr = r & 15, kg = seg >> 3;
        *(u16x8*)(lds + AOFF + g * 512 + (rr + 16 * kg) * 8) = bb;
    }
    #pragma unroll
    for (int i = 0; i < 4; ++i) {
        int u = w * 4 + i;                   // 0..31
        int plane = u >> 4, g = u & 15;
        const ushort* src = (plane ? WtL8 : WtH8) + ((size_t)(g * 16 + lr)) * 32 + lk * 8;
        ushort* dst = lds + (plane ? WLOFF : WHOFF) + g * 512;
        gload_lds16(src, dst);
    }
    __syncthreads();
    f32x4 acc[4][4] = {};
    bf16x8 bhv[4], blv[4];
    #pragma unroll
    for (int ni = 0; ni < 4; ++ni) {
        int off = (wn * 4 + ni) * 512 + lane * 8;
        bhv[ni] = *(const bf16x8*)(lds + WHOFF + off);
        blv[ni] = *(const bf16x8*)(lds + WLOFF + off);
    }
    #pragma unroll
    for (int mi = 0; mi < 4; ++mi) {
        bf16x8 ah = *(const bf16x8*)(lds + AOFF + (wm * 4 + mi) * 512 + lane * 8);
        #pragma unroll
        for (int ni = 0; ni < 4; ++ni) {
            acc[mi][ni] = __builtin_amdgcn_mfma_f32_16x16x32_bf16(ah, bhv[ni], acc[mi][ni], 0, 0, 0);
            acc[mi][ni] = __builtin_amdgcn_mfma_f32_16x16x32_bf16(ah, blv[ni], acc[mi][ni], 0, 0, 0);
        }
    }
    constexpr int ELDW = 68;
    float* S = (float*)lds + (size_t)w * 16 * ELDW;
    const int rrow = lane >> 3;
    const int grp  = lane & 7;
    #pragma unroll
    for (int mi = 0; mi < 4; ++mi) {
        __syncthreads();
        #pragma unroll
        for (int ni = 0; ni < 4; ++ni)
            #pragma unroll
            for (int reg = 0; reg < 4; ++reg)
                S[(lk * 4 + reg) * ELDW + ni * 16 + lr] = acc[mi][ni][reg];
        __syncthreads();
        #pragma unroll
        for (int it = 0; it < 2; ++it) {
            int row_i = rrow + it * 8;
            int gr = row0 + wm * 64 + mi * 16 + row_i;
            int gc = wn * 64 + grp * 8;
            if (gr >= NF) continue;
            float4 f0 = *(const float4*)(&S[row_i * ELDW + grp * 8]);
            float4 f1 = *(const float4*)(&S[row_i * ELDW + grp * 8 + 4]);
            float4 b0 = *(const float4*)(bfl + gc);
            float4 b1 = *(const float4*)(bfl + gc + 4);
            u16x8 hh;
            hh[0] = f2bf(fmaxf(f0.x + b0.x, 0.f));
            hh[1] = f2bf(fmaxf(f0.y + b0.y, 0.f));
            hh[2] = f2bf(fmaxf(f0.z + b0.z, 0.f));
            hh[3] = f2bf(fmaxf(f0.w + b0.w, 0.f));
            hh[4] = f2bf(fmaxf(f1.x + b1.x, 0.f));
            hh[5] = f2bf(fmaxf(f1.y + b1.y, 0.f));
            hh[6] = f2bf(fmaxf(f1.z + b1.z, 0.f));
            hh[7] = f2bf(fmaxf(f1.w + b1.w, 0.f));
            *(u16x8*)(hH + (size_t)gr * D + gc) = hh;
        }
    }
}

// ---------------- weight split+transpose: root[k][n] -> WtH/WtL[n][k] -------
__global__ __launch_bounds__(256) void wsplit_kernel(
    const float* __restrict__ root, ushort* __restrict__ WtH, ushort* __restrict__ WtL)
{
    int n = blockIdx.x, k = threadIdx.x;
    float w = root[(size_t)k * D + n];
    ushort hi = f2bf(w);
    WtH[(size_t)n * D + k] = hi;
    WtL[(size_t)n * D + k] = f2bf(w - bf2f(hi));
}

// ---------------- basis combine: Wr[r] = sum_b comp[r,b] * basis[b] ---------
__global__ __launch_bounds__(256) void wr_kernel(
    const float* __restrict__ basis, const float* __restrict__ comp,
    float* __restrict__ wr)
{
    int idx = blockIdx.x * 256 + threadIdx.x;   // < 4*DD
    int r = idx >> 16;
    int io = idx & (DD - 1);
    wr[idx] = comp[r * 3 + 0] * basis[io]
            + comp[r * 3 + 1] * basis[DD + io]
            + comp[r * 3 + 2] * basis[2 * DD + io];
}

// ---------------- r1/r3 degree count (low contention: 100K dsts) ----------
__global__ __launch_bounds__(256) void deg_count_kernel(
    const int* __restrict__ dst1, const int* __restrict__ dst3,
    int* __restrict__ deg1, int* __restrict__ deg3)
{
    int idx = blockIdx.x * 256 + threadIdx.x;
    if (idx >= 2 * E) return;
    if (idx < E) atomicAdd(&deg1[dst1[idx]], 1);
    else         atomicAdd(&deg3[dst3[idx - E]], 1);
}

// ---- r0/r2 per-slice LDS histograms; also zeroes deg13 & aggbuf and
// produces the flight-encoder weight transpose split (blocks 0..31) ---------
__global__ __launch_bounds__(256) void hist02_kernel(
    const int* __restrict__ dst0, const int* __restrict__ dst2,
    int* __restrict__ bh0, int* __restrict__ bh2,
    int* __restrict__ deg13z, float* __restrict__ aggz,
    const float* __restrict__ Wf, ushort* __restrict__ WfTH, ushort* __restrict__ WfTL)
{
    __shared__ int hist[NA];
    int b = blockIdx.x;                 // 0..2*NSL-1
    for (int i = b * 256 + threadIdx.x; i < 2 * NF; i += 2 * NSL * 256)
        deg13z[i] = 0;
    for (int i = b * 256 + threadIdx.x; i < (NA + NC) * D; i += 2 * NSL * 256)
        aggz[i] = 0.f;
    if (b < 32) {
        int n = threadIdx.x;
        float wv = Wf[(size_t)b * D + n];
        ushort hi = f2bf(wv);
        WfTH[(size_t)n * 32 + b] = hi;
        WfTL[(size_t)n * 32 + b] = f2bf(wv - bf2f(hi));
    }
    bool isR2 = (b >= NSL);
    int sl = isR2 ? b - NSL : b;
    const int* dst = isR2 ? dst2 : dst0;
    int nb = isR2 ? NC : NA;
    for (int i = threadIdx.x; i < nb; i += 256) hist[i] = 0;
    __syncthreads();
    int lo = (int)((long long)E * sl / NSL);
    int hi = (int)((long long)E * (sl + 1) / NSL);
    for (int e = lo + threadIdx.x; e < hi; e += 256)
        atomicAdd(&hist[dst[e]], 1);
    __syncthreads();
    int* bh = isR2 ? (bh2 + sl * NC) : (bh0 + sl * NA);
    for (int i = threadIdx.x; i < nb; i += 256) bh[i] = hist[i];
}

// -------- scan: per-bin over slices + cross-bin; emits rp/inv + abs offsets -
__global__ __launch_bounds__(512) void scan02_kernel(
    int* __restrict__ bh0, int* __restrict__ bh2,
    int* __restrict__ rp0, int* __restrict__ rp2,
    float* __restrict__ inv0, float* __restrict__ inv2)
{
    __shared__ int tot[512];
    __shared__ int exc[512];
    int t = threadIdx.x;
    int cnt = 0;
    if (t < NA) {
        int s = 0;
        for (int sl = 0; sl < NSL; ++sl) {
            int v = bh0[sl * NA + t]; bh0[sl * NA + t] = s; s += v;
        }
        cnt = s;
    } else if (t < NA + NC) {
        int bin = t - NA; int s = 0;
        for (int sl = 0; sl < NSL; ++sl) {
            int v = bh2[sl * NC + bin]; bh2[sl * NC + bin] = s; s += v;
        }
        cnt = s;
    }
    tot[t] = cnt;
    __syncthreads();
    for (int ofs = 1; ofs < 512; ofs <<= 1) {
        int v = (t >= ofs) ? tot[t - ofs] : 0;
        __syncthreads();
        tot[t] += v;
        __syncthreads();
    }
    int ex = tot[t] - cnt;              // exclusive over combined [r0 | r2]
    if (t < NA) {
        exc[t] = ex;
        rp0[t] = ex;
        inv0[t] = 1.0f / (float)(cnt > 1 ? cnt : 1);
        if (t == 0) { rp0[NA] = E; rp2[NC] = E; }
    } else if (t < NA + NC) {
        exc[t] = ex - E;                // r2 csr buffer is its own array
        rp2[t - NA] = ex - E;
        inv2[t - NA] = 1.0f / (float)(cnt > 1 ? cnt : 1);
    } else exc[t] = 0;
    __syncthreads();
    for (int idx = t; idx < NSL * NA; idx += 512) {
        int sl = idx / NA; int bin = idx - sl * NA;
        bh0[idx] += exc[bin];
    }
    for (int idx = t; idx < NSL * NC; idx += 512) {
        int sl = idx / NC; int bin = idx - sl * NC;
        bh2[idx] += exc[NA + bin];
    }
}

// ---------------- r0/r2 CSR fill with LDS cursors --------------------------
__global__ __launch_bounds__(256) void fill02_kernel(
    const int* __restrict__ src0, const int* __restrict__ dst0,
    const int* __restrict__ src2, const int* __restrict__ dst2,
    const int* __restrict__ bh0, const int* __restrict__ bh2,
    int* __restrict__ csr0, int* __restrict__ csr2)
{
    __shared__ int cur[NA];
    int b = blockIdx.x;
    bool isR2 = (b >= NSL);
    int sl = isR2 ? b - NSL : b;
    const int* src = isR2 ? src2 : src0;
    const int* dst = isR2 ? dst2 : dst0;
    const int* bh  = isR2 ? (bh2 + sl * NC) : (bh0 + sl * NA);
    int* csr       = isR2 ? csr2 : csr0;
    int nb = isR2 ? NC : NA;
    for (int i = threadIdx.x; i < nb; i += 256) cur[i] = bh[i];
    __syncthreads();
    int lo = (int)((long long)E * sl / NSL);
    int hi = (int)((long long)E * (sl + 1) / NSL);
    for (int e = lo + threadIdx.x; e < hi; e += 256) {
        int pos = atomicAdd(&cur[dst[e]], 1);
        csr[pos] = src[e];
    }
}

// ---------------- r1/r3 scan chain -----------------------------------------
__global__ __launch_bounds__(1024) void scanA_kernel(
    const int* __restrict__ deg1, const int* __restrict__ deg3, int* __restrict__ bsum)
{
    __shared__ int s[1024];
    int b = blockIdx.x;                    // 0..195
    bool isR3 = (b >= 98);
    const int* deg = isR3 ? deg3 : deg1;
    int chunk = isR3 ? b - 98 : b;
    int i = chunk * 1024 + threadIdx.x;
    int v = (i < NF) ? deg[i] : 0;
    s[threadIdx.x] = v;
    __syncthreads();
    for (int ofs = 512; ofs > 0; ofs >>= 1) {
        if ((int)threadIdx.x < ofs) s[threadIdx.x] += s[threadIdx.x + ofs];
        __syncthreads();
    }
    if (threadIdx.x == 0) bsum[(isR3 ? 128 : 0) + chunk] = s[0];
}

// scanC with the scanB 196-entry exclusive scan inlined
__global__ __launch_bounds__(1024) void scanC_kernel(
    const int* __restrict__ deg1, const int* __restrict__ deg3,
    const int* __restrict__ bsum,
    int* __restrict__ rp1, int* __restrict__ rp3,
    int* __restrict__ cu1, int* __restrict__ cu3,
    float* __restrict__ inv1, float* __restrict__ inv3)
{
    __shared__ int s[1024];
    __shared__ int s2[256];
    int tid = threadIdx.x;
    int b = blockIdx.x;                    // 0..195
    int vb = 0;
    if (tid < 256) {
        vb = ((tid & 127) < 98) ? bsum[tid] : 0;
        s2[tid] = vb;
    }
    __syncthreads();
    for (int ofs = 1; ofs < 128; ofs <<= 1) {
        int a = 0;
        if (tid < 256 && (tid & 127) >= ofs) a = s2[tid - ofs];
        __syncthreads();
        if (tid < 256) s2[tid] += a;
        __syncthreads();
    }
    if (tid < 256) s2[tid] -= vb;          // exclusive
    __syncthreads();
    const int* deg; int* rp; int* cu; float* inv; int chunk; int prefix;
    if (b < 98) { deg = deg1; rp = rp1; cu = cu1; inv = inv1; chunk = b;      prefix = s2[chunk]; }
    else        { deg = deg3; rp = rp3; cu = cu3; inv = inv3; chunk = b - 98; prefix = s2[128 + chunk]; }
    int i = chunk * 1024 + tid;
    int v = (i < NF) ? deg[i] : 0;
    s[tid] = v;
    __syncthreads();
    for (int ofs = 1; ofs < 1024; ofs <<= 1) {
        int a = (tid >= ofs) ? s[tid - ofs] : 0;
        __syncthreads();
        s[tid] += a;
        __syncthreads();
    }
    int ex = prefix + s[tid] - v;
    if (i < NF) {
        rp[i] = ex;
        cu[i] = ex;
        inv[i] = 1.0f / (float)(v > 1 ? v : 1);
    }
    if (i == 0) rp[NF] = E;
}

__global__ __launch_bounds__(256) void csr_fill13_kernel(
    const int* __restrict__ src1, const int* __restrict__ dst1,
    const int* __restrict__ src3, const int* __restrict__ dst3,
    int* __restrict__ cu1, int* __restrict__ cu3,
    int* __restrict__ csr1, int* __restrict__ csr3)
{
    int idx = blockIdx.x * 256 + threadIdx.x;
    if (idx >= 2 * E) return;
    if (idx < E) {
        int pos = atomicAdd(&cu1[dst1[idx]], 1);
        csr1[pos] = src1[idx];
    } else {
        int e = idx - E;
        int pos = atomicAdd(&cu3[dst3[e]], 1);
        csr3[pos] = src3[e];
    }
}

// ------- y = h[src-type rows] @ Wr[rel]  (Wr precomputed) -------------------
__global__ __launch_bounds__(256) void y_kernel(
    const ushort* __restrict__ hH, const float* __restrict__ wr,
    float* __restrict__ y)
{
    int row = blockIdx.x;            // 0..429  (airports then carriers)
    int c = threadIdx.x;
    const ushort* sH = hH + (size_t)(NF + row) * D;
    const float* W = wr + (size_t)((row < NA) ? 1 : 3) * DD;
    float acc = 0.f;
    #pragma unroll 8
    for (int k = 0; k < D; ++k) acc += bf2f(sH[k]) * W[k * D + c];
    y[(size_t)row * D + c] = acc;
}

// ---- bf16 MFMA GEMM: G = A @ root^T + bias (A single-plane, W split) ------
// 8 waves, 64x32 sub-tiles, fragment-major global_load_lds staging, 2-buffer
// pipeline with COUNTED vmcnt(3): one stage stays in flight across each
// barrier; LDS 48 KB -> 3 blocks/CU residency (24 waves).
__global__ __launch_bounds__(512) void gemm_mfma(
    const ushort* __restrict__ A,
    const ushort* __restrict__ WtH, const ushort* __restrict__ WtL,
    const float* __restrict__ bias,
    ushort* __restrict__ G, int nrows)
{
    constexpr int BM = 128, BK = 32;
    constexpr int PLANE = BM * BK;          // 4096 ushorts = 8 KB
    constexpr int BUF = 3 * PLANE;          // 12288 ushorts = 24 KB
    constexpr int LDW = 36;                 // fp32 epilogue scratch stride
    __shared__ __align__(16) ushort lds[2 * BUF];   // 49152 B (2 buffers)
    const int t = threadIdx.x;
    const int row0 = blockIdx.x * BM;
    const int col0 = blockIdx.y * BM;
    const int w = t >> 6, lane = t & 63;    // 8 waves
    const int wm = w >> 2, wn = w & 3;      // 2x4 wave grid, 64x32 per wave
    const int lr = lane & 15;
    const int lk = lane >> 4;
    f32x4 acc[4][2] = {};

    // staging: 24 (plane,group) units, wave w handles 3 consecutive
    const ushort* sp[3];
    int dofs[3];
    #pragma unroll
    for (int i = 0; i < 3; ++i) {
        int idx = w * 3 + i;
        int plane = idx >> 3, g = idx & 7;
        const ushort* base = (plane == 0) ? A : (plane == 1) ? WtH : WtL;
        int r = ((plane == 0) ? row0 : col0) + g * 16 + lr;
        if (plane == 0 && r >= nrows) r = nrows - 1;
        sp[i] = base + (size_t)r * D + lk * 8;
        dofs[i] = plane * PLANE + g * 512;
    }

    auto stage = [&](int kt, int buf) {
        ushort* bb = lds + buf * BUF;
        int k0 = kt * BK;
        #pragma unroll
        for (int i = 0; i < 3; ++i)
            gload_lds16(sp[i] + k0, bb + dofs[i]);
    };
    auto compute = [&](int buf) {
        const ushort* base = lds + buf * BUF;
        const ushort* As  = base;
        const ushort* WsH = base + PLANE;
        const ushort* WsL = base + 2 * PLANE;
        bf16x8 bh[2], bl[2];
        #pragma unroll
        for (int ni = 0; ni < 2; ++ni) {
            int off = (wn * 2 + ni) * 512 + lane * 8;
            bh[ni] = *(const bf16x8*)(&WsH[off]);
            bl[ni] = *(const bf16x8*)(&WsL[off]);
        }
        #pragma unroll
        for (int mi = 0; mi < 4; ++mi) {
            int off = (wm * 4 + mi) * 512 + lane * 8;
            bf16x8 ah = *(const bf16x8*)(&As[off]);
            #pragma unroll
            for (int ni = 0; ni < 2; ++ni) {
                acc[mi][ni] = __builtin_amdgcn_mfma_f32_16x16x32_bf16(ah, bh[ni], acc[mi][ni], 0, 0, 0);
                acc[mi][ni] = __builtin_amdgcn_mfma_f32_16x16x32_bf16(ah, bl[ni], acc[mi][ni], 0, 0, 0);
            }
        }
    };

    // prologue: 2 stages in flight (6 loads/wave)
    stage(0, 0);
    stage(1, 1);
#define PIPE_ITER(KT, PEND)                                        \
    asm volatile("s_waitcnt vmcnt(" #PEND ")" ::: "memory");       \
    __builtin_amdgcn_s_barrier();                                  \
    __builtin_amdgcn_sched_barrier(0);                             \
    compute((KT) & 1);                                             \
    __builtin_amdgcn_s_barrier();                                  \
    __builtin_amdgcn_sched_barrier(0);                             \
    if ((KT) + 2 < 8) stage((KT) + 2, (KT) & 1);
    PIPE_ITER(0, 3)
    PIPE_ITER(1, 3)
    PIPE_ITER(2, 3)
    PIPE_ITER(3, 3)
    PIPE_ITER(4, 3)
    PIPE_ITER(5, 3)
    PIPE_ITER(6, 3)
    PIPE_ITER(7, 0)
#undef PIPE_ITER

    // ---- epilogue: per-mi 16x32 pass through LDS, coalesced 16B stores -----
    __syncthreads();                         // everyone done with buffers
    float* S = (float*)lds + (size_t)w * 16 * LDW;   // per-wave 16x36 fp32
    const int rrow = lane >> 2;            // 0..15 read-back row
    const int grp  = lane & 3;             // col octet (8 bf16)
    #pragma unroll
    for (int mi = 0; mi < 4; ++mi) {
        __syncthreads();
        #pragma unroll
        for (int ni = 0; ni < 2; ++ni)
            #pragma unroll
            for (int reg = 0; reg < 4; ++reg)
                S[(lk * 4 + reg) * LDW + ni * 16 + lr] = acc[mi][ni][reg];
        __syncthreads();
        int gr = row0 + wm * 64 + mi * 16 + rrow;
        int gc = col0 + wn * 32 + grp * 8;
        if (gr >= nrows) continue;
        float4 f0 = *(const float4*)(&S[rrow * LDW + grp * 8]);
        float4 f1 = *(const float4*)(&S[rrow * LDW + grp * 8 + 4]);
        float4 b0 = *(const float4*)(bias + gc);
        float4 b1 = *(const float4*)(bias + gc + 4);
        float v[8] = {f0.x + b0.x, f0.y + b0.y, f0.z + b0.z, f0.w + b0.w,
                      f1.x + b1.x, f1.y + b1.y, f1.z + b1.z, f1.w + b1.w};
        u16x8 hh;
        #pragma unroll
        for (int j = 0; j < 8; ++j) hh[j] = f2bf(v[j]);
        *(u16x8*)(G + (size_t)gr * D + gc) = hh;
    }
}

// ---- layer-0 flight rows: G = relu(G + inv1*Σy1 + inv3*Σy3) in place ------
// 2 rows per wave: lanes 0-31 row 2w, lanes 32-63 row 2w+1; 8 ch/lane.
__global__ __launch_bounds__(256) void msg_relu_kernel(
    ushort* __restrict__ G,
    const float* __restrict__ y,
    const int* __restrict__ rp1, const int* __restrict__ csr1, const float* __restrict__ inv1,
    const int* __restrict__ rp3, const int* __restrict__ csr3, const float* __restrict__ inv3)
{
    int wid = (blockIdx.x * 256 + threadIdx.x) >> 6;
    int lane = threadIdx.x & 63;
    int row = wid * 2 + (lane >> 5);
    if (row >= NF) return;
    int c = (lane & 31) * 8;
    size_t o = (size_t)row * D + c;
    u16x8 gh = *(const u16x8*)(G + o);
    float v[8];
    #pragma unroll
    for (int j = 0; j < 8; ++j) v[j] = bf2f(gh[j]);
    float m[8] = {};
    int e0 = rp1[row], e1 = rp1[row + 1];
    for (int e = e0; e < e1; ++e) {
        const float* yr = y + (size_t)csr1[e] * D + c;
        float4 u0 = *(const float4*)yr;
        float4 u1 = *(const float4*)(yr + 4);
        m[0] += u0.x; m[1] += u0.y; m[2] += u0.z; m[3] += u0.w;
        m[4] += u1.x; m[5] += u1.y; m[6] += u1.z; m[7] += u1.w;
    }
    float s1 = inv1[row];
    #pragma unroll
    for (int j = 0; j < 8; ++j) { v[j] += s1 * m[j]; m[j] = 0.f; }
    e0 = rp3[row]; e1 = rp3[row + 1];
    for (int e = e0; e < e1; ++e) {
        const float* yr = y + (size_t)(NA + csr3[e]) * D + c;
        float4 u0 = *(const float4*)yr;
        float4 u1 = *(const float4*)(yr + 4);
        m[0] += u0.x; m[1] += u0.y; m[2] += u0.z; m[3] += u0.w;
        m[4] += u1.x; m[5] += u1.y; m[6] += u1.z; m[7] += u1.w;
    }
    float s3 = inv3[row];
    u16x8 oh;
    #pragma unroll
    for (int j = 0; j < 8; ++j) oh[j] = f2bf(fmaxf(v[j] + s3 * m[j], 0.f));
    *(u16x8*)(G + o) = oh;
}

// ---- layer-1: out[f] = relu(G2+msgs) . W_out + b_out (fused readout) -------
__global__ __launch_bounds__(256) void msg_readout_kernel(
    const ushort* __restrict__ G,
    const float* __restrict__ y,
    const int* __restrict__ rp1, const int* __restrict__ csr1, const float* __restrict__ inv1,
    const int* __restrict__ rp3, const int* __restrict__ csr3, const float* __restrict__ inv3,
    const float* __restrict__ wout, const float* __restrict__ bout,
    float* __restrict__ out)
{
    int wid = (blockIdx.x * 256 + threadIdx.x) >> 6;
    int lane = threadIdx.x & 63;
    int row = wid * 2 + (lane >> 5);
    if (row >= NF) return;
    int c = (lane & 31) * 8;
    size_t o = (size_t)row * D + c;
    u16x8 gh = *(const u16x8*)(G + o);
    float v[8];
    #pragma unroll
    for (int j = 0; j < 8; ++j) v[j] = bf2f(gh[j]);
    float m[8] = {};
    int e0 = rp1[row], e1 = rp1[row + 1];
    for (int e = e0; e < e1; ++e) {
        const float* yr = y + (size_t)csr1[e] * D + c;
        float4 u0 = *(const float4*)yr;
        float4 u1 = *(const float4*)(yr + 4);
        m[0] += u0.x; m[1] += u0.y; m[2] += u0.z; m[3] += u0.w;
        m[4] += u1.x; m[5] += u1.y; m[6] += u1.z; m[7] += u1.w;
    }
    float s1 = inv1[row];
    #pragma unroll
    for (int j = 0; j < 8; ++j) { v[j] += s1 * m[j]; m[j] = 0.f; }
    e0 = rp3[row]; e1 = rp3[row + 1];
    for (int e = e0; e < e1; ++e) {
        const float* yr = y + (size_t)(NA + csr3[e]) * D + c;
        float4 u0 = *(const float4*)yr;
        float4 u1 = *(const float4*)(yr + 4);
        m[0] += u0.x; m[1] += u0.y; m[2] += u0.z; m[3] += u0.w;
        m[4] += u1.x; m[5] += u1.y; m[6] += u1.z; m[7] += u1.w;
    }
    float s3 = inv3[row];
    float4 w0 = *(const float4*)(wout + c);
    float4 w1 = *(const float4*)(wout + c + 4);
    float wv[8] = {w0.x, w0.y, w0.z, w0.w, w1.x, w1.y, w1.z, w1.w};
    float pr = 0.f;
    #pragma unroll
    for (int j = 0; j < 8; ++j) pr += fmaxf(v[j] + s3 * m[j], 0.f) * wv[j];
    pr += __shfl_xor(pr, 1);
    pr += __shfl_xor(pr, 2);
    pr += __shfl_xor(pr, 4);
    pr += __shfl_xor(pr, 8);
    pr += __shfl_xor(pr, 16);
    if ((lane & 31) == 0) out[row] = pr + bout[0];
}

// ---- r0/r2: agg[dst] += hH[src] — 2 edges per wave, 16B/lane loads ---------
__global__ __launch_bounds__(256) void agg_small_kernel(
    const ushort* __restrict__ hH,
    const int* __restrict__ rp0, const int* __restrict__ csr0,
    const int* __restrict__ rp2, const int* __restrict__ csr2,
    float* __restrict__ agg)
{
    __shared__ float red[4][256];
    int b = blockIdx.x;
    const int* rp; const int* csr; int dstn, chunk, nch; float* arow;
    if (b < NA * 4) { dstn = b >> 2; chunk = b & 3; nch = 4;  rp = rp0; csr = csr0; arow = agg + (size_t)dstn * D; }
    else { int bb = b - NA * 4; dstn = bb >> 6; chunk = bb & 63; nch = 64; rp = rp2; csr = csr2; arow = agg + (size_t)(NA + dstn) * D; }
    int s = rp[dstn], e = rp[dstn + 1];
    int cnt = e - s;
    int lo = s + (int)((long long)cnt * chunk / nch);
    int hi = s + (int)((long long)cnt * (chunk + 1) / nch);
    int w = threadIdx.x >> 6, lane = threadIdx.x & 63;
    int span = hi - lo;
    int wlo = lo + (int)((long long)span * w / 4);
    int whi = lo + (int)((long long)span * (w + 1) / 4);
    int half = lane >> 5;                  // 0: edge p, 1: edge p+1
    int ch8 = (lane & 31) * 8;
    float acc[8] = {};
    int p = wlo;
    for (; p + 1 < whi; p += 2) {
        int r = csr[p + half];
        u16x8 v = *(const u16x8*)(hH + (size_t)r * D + ch8);
        #pragma unroll
        for (int j = 0; j < 8; ++j) acc[j] += bf2f(v[j]);
    }
    if (p < whi && half == 0) {
        int r = csr[p];
        u16x8 v = *(const u16x8*)(hH + (size_t)r * D + ch8);
        #pragma unroll
        for (int j = 0; j < 8; ++j) acc[j] += bf2f(v[j]);
    }
    #pragma unroll
    for (int j = 0; j < 8; ++j) acc[j] += __shfl_xor(acc[j], 32);
    if (lane < 32) {
        #pragma unroll
        for (int j = 0; j < 8; ++j) red[w][ch8 + j] = acc[j];
    }
    __syncthreads();
    int c = threadIdx.x;
    float total = red[0][c] + red[1][c] + red[2][c] + red[3][c];
    atomicAdd(arow + c, total);
}

// -- r0/r2 transform: G = relu(G + inv_deg*(agg @ Wr[rel])) in place ---------
__global__ __launch_bounds__(256) void smallT_kernel(
    const float* __restrict__ agg, const float* __restrict__ wr,
    const float* __restrict__ inv0, const float* __restrict__ inv2,
    ushort* __restrict__ G)
{
    int row = blockIdx.x;            // 0..429
    int c = threadIdx.x;
    const float* a = agg + (size_t)row * D;
    const float* W = wr + (size_t)((row < NA) ? 0 : 2) * DD;
    float scale = (row < NA) ? inv0[row] : inv2[row - NA];
    float acc = 0.f;
    #pragma unroll 8
    for (int k = 0; k < D; ++k) acc += a[k] * W[k * D + c];
    size_t o = (size_t)(NF + row) * D + c;
    G[o] = f2bf(fmaxf(bf2f(G[o]) + scale * acc, 0.f));
}

extern "C" void kernel_launch(void* const* d_in, const int* in_sizes, int n_in,
                              void* d_out, int out_size, void* d_ws, size_t ws_size,
                              hipStream_t stream)
{
    const float* xf = (const float*)d_in[0];
    const float* xa = (const float*)d_in[1];
    const float* xc = (const float*)d_in[2];
    const float* Wf = (const float*)d_in[3];
    const float* bf = (const float*)d_in[4];
    const float* Wa = (const float*)d_in[5];
    const float* ba = (const float*)d_in[6];
    const float* Wc = (const float*)d_in[7];
    const float* bc = (const float*)d_in[8];
    const float* basis0 = (const float*)d_in[9];
    const float* comp0  = (const float*)d_in[10];
    const float* root0  = (const float*)d_in[11];
    const float* bias0  = (const float*)d_in[12];
    const float* basis1 = (const float*)d_in[13];
    const float* comp1  = (const float*)d_in[14];
    const float* root1  = (const float*)d_in[15];
    const float* bias1  = (const float*)d_in[16];
    const float* Wout = (const float*)d_in[17];
    const float* bout = (const float*)d_in[18];
    const int* src0 = (const int*)d_in[19];
    const int* dst0 = (const int*)d_in[20];
    const int* src1 = (const int*)d_in[21];
    const int* dst1 = (const int*)d_in[22];
    const int* src2 = (const int*)d_in[23];
    const int* dst2 = (const int*)d_in[24];
    const int* src3 = (const int*)d_in[25];
    const int* dst3 = (const int*)d_in[26];
    float* out = (float*)d_out;

    char* ws = (char*)d_ws;
    size_t off = 0;
    auto alloc = [&](size_t bytes) -> char* {
        char* p = ws + off;
        off = (off + bytes + 255) & ~(size_t)255;
        return p;
    };
    ushort* hH  = (ushort*)alloc((size_t)NN * D * 2);
    ushort* gH  = (ushort*)alloc((size_t)NN * D * 2);
    // layer-1 GEMM output reuses hH (dead after layer-0 consumers)
    ushort* g2H = hH;
    ushort* WtH = (ushort*)alloc((size_t)DD * 2);
    ushort* WtL = (ushort*)alloc((size_t)DD * 2);
    ushort* WfTH = (ushort*)alloc((size_t)D * 32 * 2);
    ushort* WfTL = (ushort*)alloc((size_t)D * 32 * 2);
    float* wrbuf  = (float*)alloc((size_t)4 * DD * 4);
    float* ybuf   = (float*)alloc((size_t)(NA + NC) * D * 4);
    float* aggbuf = (float*)alloc((size_t)(NA + NC) * D * 4);
    int*   deg13  = (int*)  alloc((size_t)2 * NF * 4);
    int* deg1 = deg13; int* deg3 = deg13 + NF;
    float* inv1 = (float*)alloc((size_t)NF * 4);
    float* inv3 = (float*)alloc((size_t)NF * 4);
    float* inv0 = (float*)alloc((size_t)NA * 4);
    float* inv2 = (float*)alloc((size_t)NC * 4);
    int* rp0 = (int*)alloc((NA + 1) * 4);
    int* rp1 = (int*)alloc((size_t)(NF + 1) * 4);
    int* rp2 = (int*)alloc((NC + 1) * 4);
    int* rp3 = (int*)alloc((size_t)(NF + 1) * 4);
    int* cu1 = (int*)alloc((size_t)(NF + 1) * 4);
    int* cu3 = (int*)alloc((size_t)(NF + 1) * 4);
    int* csr0 = (int*)alloc((size_t)E * 4);
    int* csr1 = (int*)alloc((size_t)E * 4);
    int* csr2 = (int*)alloc((size_t)E * 4);
    int* csr3 = (int*)alloc((size_t)E * 4);
    int* bsum = (int*)alloc(256 * 4);
    int* bh0  = (int*)alloc((size_t)NSL * NA * 4);
    int* bh2  = (int*)alloc((size_t)NSL * NC * 4);
    (void)ws_size; (void)in_sizes; (void)n_in; (void)out_size;

    // ---- CSR build: r0/r2 counting sort; hist02 also zeroes deg13 + aggbuf
    //      and produces the flight-encoder weight transpose split
    hist02_kernel<<<2 * NSL, 256, 0, stream>>>(dst0, dst2, bh0, bh2, deg13, aggbuf,
                                               Wf, WfTH, WfTL);
    scan02_kernel<<<1, 512, 0, stream>>>(bh0, bh2, rp0, rp2, inv0, inv2);
    fill02_kernel<<<2 * NSL, 256, 0, stream>>>(src0, dst0, src2, dst2, bh0, bh2, csr0, csr2);

    // ---- CSR build: r1/r3 via atomics (100K dsts, avg degree 2.5 — cheap)
    deg_count_kernel<<<(2 * E + 255) / 256, 256, 0, stream>>>(dst1, dst3, deg1, deg3);
    scanA_kernel<<<196, 1024, 0, stream>>>(deg1, deg3, bsum);
    scanC_kernel<<<196, 1024, 0, stream>>>(deg1, deg3, bsum, rp1, rp3, cu1, cu3, inv1, inv3);
    csr_fill13_kernel<<<(2 * E + 255) / 256, 256, 0, stream>>>(
        src1, dst1, src3, dst3, cu1, cu3, csr1, csr3);

    // ---- MFMA flight encoder + scalar airports/carriers tail (one dispatch)
    encode_mfma_kernel<<<FBLK + (NA + NC + 7) / 8, 512, 0, stream>>>(
        xf, WfTH, WfTL, bf, xa, Wa, ba, xc, Wc, bc, hH);

    // ---- layer 0: pure MFMA gemm -> G; then per-row-type finishers in place
    wsplit_kernel<<<D, D, 0, stream>>>(root0, WtH, WtL);
    wr_kernel<<<4 * DD / 256, 256, 0, stream>>>(basis0, comp0, wrbuf);
    y_kernel<<<NA + NC, 256, 0, stream>>>(hH, wrbuf, ybuf);
    gemm_mfma<<<dim3((NN + 127) / 128, 2), 512, 0, stream>>>(
        hH, WtH, WtL, bias0, gH, NN);
    agg_small_kernel<<<NA * 4 + NC * 64, 256, 0, stream>>>(
        hH, rp0, csr0, rp2, csr2, aggbuf);
    smallT_kernel<<<NA + NC, 256, 0, stream>>>(aggbuf, wrbuf, inv0, inv2, gH);
    msg_relu_kernel<<<(NF / 2 * 64 + 255) / 256, 256, 0, stream>>>(
        gH, ybuf, rp1, csr1, inv1, rp3, csr3, inv3);

    // ---- layer 1 (flights only): pure gemm -> G2 (aliases h); readout -> out
    wsplit_kernel<<<D, D, 0, stream>>>(root1, WtH, WtL);
    wr_kernel<<<4 * DD / 256, 256, 0, stream>>>(basis1, comp1, wrbuf);
    y_kernel<<<NA + NC, 256, 0, stream>>>(gH, wrbuf, ybuf);
    gemm_mfma<<<dim3((NF + 127) / 128, 2), 512, 0, stream>>>(
        gH, WtH, WtL, bias1, g2H, NF);
    msg_readout_kernel<<<(NF / 2 * 64 + 255) / 256, 256, 0, stream>>>(
        g2H, ybuf, rp1, csr1, inv1, rp3, csr3, inv3, Wout, bout, out);
}

// Round 22
// 351.391 us; speedup vs baseline: 1.1937x; 1.0473x over previous
//
#include <hip/hip_runtime.h>
#include <hip/hip_bf16.h>
#include <cstdint>
#include <cstddef>

constexpr int NF = 100000;
constexpr int NA = 400;
constexpr int NC = 30;
constexpr int NN = NF + NA + NC;     // 100430
constexpr int D  = 256;
constexpr int DD = D * D;            // 65536
constexpr int E  = 250000;
constexpr int NSL = 128;             // slices for r0/r2 counting sort
constexpr int FBLK = (NF + 127) / 128;   // 782 flight-encoder blocks
constexpr int TAILB = (NA + NC + 7) / 8; // 54 scalar-tail blocks
constexpr int F13B = (2 * E + 511) / 512; // 977 csr_fill13 blocks (512 thr)

// K1 block ranges
constexpr int K1_HIST_END = 2 * NSL;                       // 256
constexpr int K1_DEG_END  = K1_HIST_END + (2 * E + 255) / 256;  // 2210
constexpr int K1_WS0_END  = K1_DEG_END + 256;              // 2466
constexpr int K1_WS1_END  = K1_WS0_END + 256;              // 2722
constexpr int K1_WR0_END  = K1_WS1_END + 1024;             // 3746
constexpr int K1_WR1_END  = K1_WR0_END + 1024;             // 4770

typedef __attribute__((ext_vector_type(8))) short bf16x8;
typedef __attribute__((ext_vector_type(4))) float f32x4;
typedef __attribute__((ext_vector_type(8))) ushort u16x8;

__device__ inline ushort f2bf(float f) {
    __hip_bfloat16 h = __float2bfloat16(f);
    return __builtin_bit_cast(ushort, h);
}
__device__ inline float bf2f(ushort u) {
    __hip_bfloat16 h = __builtin_bit_cast(__hip_bfloat16, u);
    return __bfloat162float(h);
}

// async global->LDS, 16B per lane: LDS dest = base + lane*16 (wave-linear)
__device__ inline void gload_lds16(const ushort* g, ushort* l) {
    __builtin_amdgcn_global_load_lds(
        (const __attribute__((address_space(1))) void*)g,
        (__attribute__((address_space(3))) void*)l, 16, 0, 0);
}

// ==== K1: hist02 + deg_count + wsplit(x2) + wr(x2), co-scheduled ============
__global__ __launch_bounds__(256) void prep_kernel(
    const int* __restrict__ dst0, const int* __restrict__ dst2,
    int* __restrict__ bh0, int* __restrict__ bh2,
    float* __restrict__ aggz,
    const float* __restrict__ Wf, ushort* __restrict__ WfTH, ushort* __restrict__ WfTL,
    const int* __restrict__ dst1, const int* __restrict__ dst3,
    int* __restrict__ deg1, int* __restrict__ deg3,
    const float* __restrict__ root0, ushort* __restrict__ WtH0, ushort* __restrict__ WtL0,
    const float* __restrict__ root1, ushort* __restrict__ WtH1, ushort* __restrict__ WtL1,
    const float* __restrict__ basis0, const float* __restrict__ comp0, float* __restrict__ wr0,
    const float* __restrict__ basis1, const float* __restrict__ comp1, float* __restrict__ wr1)
{
    __shared__ int hist[NA];
    const int b = blockIdx.x;
    const int t = threadIdx.x;
    if (b < K1_HIST_END) {
        // grid-strided aggbuf zero (over hist blocks only)
        for (int i = b * 256 + t; i < (NA + NC) * D; i += K1_HIST_END * 256)
            aggz[i] = 0.f;
        // flight-W transpose+split (blocks 0..31)
        if (b < 32) {
            float wv = Wf[(size_t)b * D + t];
            ushort hi = f2bf(wv);
            WfTH[(size_t)t * 32 + b] = hi;
            WfTL[(size_t)t * 32 + b] = f2bf(wv - bf2f(hi));
        }
        bool isR2 = (b >= NSL);
        int sl = isR2 ? b - NSL : b;
        const int* dst = isR2 ? dst2 : dst0;
        int nb = isR2 ? NC : NA;
        for (int i = t; i < nb; i += 256) hist[i] = 0;
        __syncthreads();
        int lo = (int)((long long)E * sl / NSL);
        int hi = (int)((long long)E * (sl + 1) / NSL);
        for (int e = lo + t; e < hi; e += 256)
            atomicAdd(&hist[dst[e]], 1);
        __syncthreads();
        int* bh = isR2 ? (bh2 + sl * NC) : (bh0 + sl * NA);
        for (int i = t; i < nb; i += 256) bh[i] = hist[i];
    } else if (b < K1_DEG_END) {
        int idx = (b - K1_HIST_END) * 256 + t;
        if (idx < 2 * E) {
            if (idx < E) atomicAdd(&deg1[dst1[idx]], 1);
            else         atomicAdd(&deg3[dst3[idx - E]], 1);
        }
    } else if (b < K1_WS0_END) {
        int n = b - K1_DEG_END;
        float w = root0[(size_t)t * D + n];
        ushort hi = f2bf(w);
        WtH0[(size_t)n * D + t] = hi;
        WtL0[(size_t)n * D + t] = f2bf(w - bf2f(hi));
    } else if (b < K1_WS1_END) {
        int n = b - K1_WS0_END;
        float w = root1[(size_t)t * D + n];
        ushort hi = f2bf(w);
        WtH1[(size_t)n * D + t] = hi;
        WtL1[(size_t)n * D + t] = f2bf(w - bf2f(hi));
    } else if (b < K1_WR0_END) {
        int idx = (b - K1_WS1_END) * 256 + t;
        int r = idx >> 16;
        int io = idx & (DD - 1);
        wr0[idx] = comp0[r * 3 + 0] * basis0[io]
                 + comp0[r * 3 + 1] * basis0[DD + io]
                 + comp0[r * 3 + 2] * basis0[2 * DD + io];
    } else {
        int idx = (b - K1_WR0_END) * 256 + t;
        int r = idx >> 16;
        int io = idx & (DD - 1);
        wr1[idx] = comp1[r * 3 + 0] * basis1[io]
                 + comp1[r * 3 + 1] * basis1[DD + io]
                 + comp1[r * 3 + 2] * basis1[2 * DD + io];
    }
}

// ==== K2: scanA (blocks 0..195) + scan02 (block 196), co-scheduled ==========
__global__ __launch_bounds__(1024) void scan_kernel(
    const int* __restrict__ deg1, const int* __restrict__ deg3,
    int* __restrict__ bsum,
    int* __restrict__ bh0, int* __restrict__ bh2,
    int* __restrict__ rp0, int* __restrict__ rp2,
    float* __restrict__ inv0, float* __restrict__ inv2)
{
    __shared__ int s[1024];
    __shared__ int tot[512];
    __shared__ int exc[512];
    const int b = blockIdx.x;
    const int t = threadIdx.x;
    if (b < 196) {
        bool isR3 = (b >= 98);
        const int* deg = isR3 ? deg3 : deg1;
        int chunk = isR3 ? b - 98 : b;
        int i = chunk * 1024 + t;
        int v = (i < NF) ? deg[i] : 0;
        s[t] = v;
        __syncthreads();
        for (int ofs = 512; ofs > 0; ofs >>= 1) {
            if (t < ofs) s[t] += s[t + ofs];
            __syncthreads();
        }
        if (t == 0) bsum[(isR3 ? 128 : 0) + chunk] = s[0];
        return;
    }
    // scan02 with 1024 threads (first 512 active in scan phases)
    int cnt = 0;
    if (t < NA) {
        int ss = 0;
        for (int sl = 0; sl < NSL; ++sl) {
            int v = bh0[sl * NA + t]; bh0[sl * NA + t] = ss; ss += v;
        }
        cnt = ss;
    } else if (t < NA + NC) {
        int bin = t - NA; int ss = 0;
        for (int sl = 0; sl < NSL; ++sl) {
            int v = bh2[sl * NC + bin]; bh2[sl * NC + bin] = ss; ss += v;
        }
        cnt = ss;
    }
    if (t < 512) tot[t] = cnt;
    __syncthreads();
    for (int ofs = 1; ofs < 512; ofs <<= 1) {
        int v = 0;
        if (t < 512 && t >= ofs) v = tot[t - ofs];
        __syncthreads();
        if (t < 512) tot[t] += v;
        __syncthreads();
    }
    if (t < 512) {
        int ex = tot[t] - cnt;
        if (t < NA) {
            exc[t] = ex;
            rp0[t] = ex;
            inv0[t] = 1.0f / (float)(cnt > 1 ? cnt : 1);
            if (t == 0) { rp0[NA] = E; rp2[NC] = E; }
        } else if (t < NA + NC) {
            exc[t] = ex - E;
            rp2[t - NA] = ex - E;
            inv2[t - NA] = 1.0f / (float)(cnt > 1 ? cnt : 1);
        } else exc[t] = 0;
    }
    __syncthreads();
    for (int idx = t; idx < NSL * NA; idx += 1024) {
        int sl = idx / NA; int bin = idx - sl * NA;
        bh0[idx] += exc[bin];
    }
    for (int idx = t; idx < NSL * NC; idx += 1024) {
        int sl = idx / NC; int bin = idx - sl * NC;
        bh2[idx] += exc[NA + bin];
    }
}

// ==== K3: fill02 (blocks 0..255) + scanC (blocks 256..451), co-scheduled ====
__global__ __launch_bounds__(1024) void fill_scan_kernel(
    const int* __restrict__ src0, const int* __restrict__ dst0,
    const int* __restrict__ src2, const int* __restrict__ dst2,
    const int* __restrict__ bh0, const int* __restrict__ bh2,
    int* __restrict__ csr0, int* __restrict__ csr2,
    const int* __restrict__ deg1, const int* __restrict__ deg3,
    const int* __restrict__ bsum,
    int* __restrict__ rp1, int* __restrict__ rp3,
    int* __restrict__ cu1, int* __restrict__ cu3,
    float* __restrict__ inv1, float* __restrict__ inv3)
{
    __shared__ int s[1024];
    __shared__ int s2[256];
    const int b = blockIdx.x;
    const int t = threadIdx.x;
    if (b < 2 * NSL) {
        // fill02 with 1024 threads; s[] reused as cursor array (NA <= 1024)
        bool isR2 = (b >= NSL);
        int sl = isR2 ? b - NSL : b;
        const int* src = isR2 ? src2 : src0;
        const int* dst = isR2 ? dst2 : dst0;
        const int* bh  = isR2 ? (bh2 + sl * NC) : (bh0 + sl * NA);
        int* csr       = isR2 ? csr2 : csr0;
        int nb = isR2 ? NC : NA;
        for (int i = t; i < nb; i += 1024) s[i] = bh[i];
        __syncthreads();
        int lo = (int)((long long)E * sl / NSL);
        int hi = (int)((long long)E * (sl + 1) / NSL);
        for (int e = lo + t; e < hi; e += 1024) {
            int pos = atomicAdd(&s[dst[e]], 1);
            csr[pos] = src[e];
        }
        return;
    }
    // scanC (with inlined scanB) for block bb = b - 256
    const int bb = b - 2 * NSL;
    int vb = 0;
    if (t < 256) {
        vb = ((t & 127) < 98) ? bsum[t] : 0;
        s2[t] = vb;
    }
    __syncthreads();
    for (int ofs = 1; ofs < 128; ofs <<= 1) {
        int a = 0;
        if (t < 256 && (t & 127) >= ofs) a = s2[t - ofs];
        __syncthreads();
        if (t < 256) s2[t] += a;
        __syncthreads();
    }
    if (t < 256) s2[t] -= vb;          // exclusive
    __syncthreads();
    const int* deg; int* rp; int* cu; float* inv; int chunk; int prefix;
    if (bb < 98) { deg = deg1; rp = rp1; cu = cu1; inv = inv1; chunk = bb;      prefix = s2[chunk]; }
    else         { deg = deg3; rp = rp3; cu = cu3; inv = inv3; chunk = bb - 98; prefix = s2[128 + chunk]; }
    int i = chunk * 1024 + t;
    int v = (i < NF) ? deg[i] : 0;
    s[t] = v;
    __syncthreads();
    for (int ofs = 1; ofs < 1024; ofs <<= 1) {
        int a = (t >= ofs) ? s[t - ofs] : 0;
        __syncthreads();
        s[t] += a;
        __syncthreads();
    }
    int ex = prefix + s[t] - v;
    if (i < NF) {
        rp[i] = ex;
        cu[i] = ex;
        inv[i] = 1.0f / (float)(v > 1 ? v : 1);
    }
    if (i == 0) rp[NF] = E;
}

// ==== K4: MFMA flight encoder + scalar tail + csr_fill13, co-scheduled ======
__global__ __launch_bounds__(512) void encode_fill_kernel(
    const float* __restrict__ xf,
    const ushort* __restrict__ WtH8, const ushort* __restrict__ WtL8,
    const float* __restrict__ bfl,
    const float* __restrict__ xa, const float* __restrict__ Wa, const float* __restrict__ ba,
    const float* __restrict__ xc, const float* __restrict__ Wc, const float* __restrict__ bc,
    ushort* __restrict__ hH,
    const int* __restrict__ src1, const int* __restrict__ dst1,
    const int* __restrict__ src3, const int* __restrict__ dst3,
    int* __restrict__ cu1, int* __restrict__ cu3,
    int* __restrict__ csr1, int* __restrict__ csr3)
{
    const int t = threadIdx.x;
    const int b = blockIdx.x;
    if (b >= FBLK + TAILB) {
        // ---- csr_fill13 range
        int idx = (b - FBLK - TAILB) * 512 + t;
        if (idx < 2 * E) {
            if (idx < E) {
                int pos = atomicAdd(&cu1[dst1[idx]], 1);
                csr1[pos] = src1[idx];
            } else {
                int e = idx - E;
                int pos = atomicAdd(&cu3[dst3[e]], 1);
                csr3[pos] = src3[e];
            }
        }
        return;
    }
    if (b >= FBLK) {
        // ---- airports + carriers scalar path
        int c = t & 255;
        int i0 = t >> 8;
        int base = (b - FBLK) * 8;
        for (int i = i0; i < 8; i += 2) {
            int row = base + i;
            if (row >= NA + NC) break;
            float acc;
            if (row < NA) {
                const float* xr = xa + (size_t)row * 16;
                acc = ba[c];
                #pragma unroll
                for (int k = 0; k < 16; ++k) acc += xr[k] * Wa[k * D + c];
            } else {
                const float* xr = xc + (size_t)(row - NA) * 8;
                acc = bc[c];
                #pragma unroll
                for (int k = 0; k < 8; ++k) acc += xr[k] * Wc[k * D + c];
            }
            hH[(size_t)(NF + row) * D + c] = f2bf(fmaxf(acc, 0.f));
        }
        return;
    }
    // ---- flight MFMA path
    constexpr int AOFF = 0, WHOFF = 4096, WLOFF = 12288;   // ushort offsets
    __shared__ __align__(16) ushort lds[20480];            // 40960 B
    const int row0 = b * 128;
    const int w = t >> 6, lane = t & 63;     // 8 waves
    const int wm = w >> 2, wn = w & 3;       // 2x4 grid, 64 rows x 64 cols/wave
    const int lr = lane & 15;
    const int lk = lane >> 4;
    {
        int r = t >> 2;                      // 0..127
        int seg = (t & 3) * 8;               // 0,8,16,24
        int gr = row0 + r; if (gr >= NF) gr = NF - 1;
        const float* xr = xf + (size_t)gr * 32 + seg;
        float4 a0 = *(const float4*)xr;
        float4 a1 = *(const float4*)(xr + 4);
        u16x8 bb;
        bb[0] = f2bf(a0.x); bb[1] = f2bf(a0.y); bb[2] = f2bf(a0.z); bb[3] = f2bf(a0.w);
        bb[4] = f2bf(a1.x); bb[5] = f2bf(a1.y); bb[6] = f2bf(a1.z); bb[7] = f2bf(a1.w);
        int g = r >> 4, rr = r & 15, kg = seg >> 3;
        *(u16x8*)(lds + AOFF + g * 512 + (rr + 16 * kg) * 8) = bb;
    }
    #pragma unroll
    for (int i = 0; i < 4; ++i) {
        int u = w * 4 + i;                   // 0..31
        int plane = u >> 4, g = u & 15;
        const ushort* src = (plane ? WtL8 : WtH8) + ((size_t)(g * 16 + lr)) * 32 + lk * 8;
        ushort* dst = lds + (plane ? WLOFF : WHOFF) + g * 512;
        gload_lds16(src, dst);
    }
    __syncthreads();
    f32x4 acc[4][4] = {};
    bf16x8 bhv[4], blv[4];
    #pragma unroll
    for (int ni = 0; ni < 4; ++ni) {
        int off = (wn * 4 + ni) * 512 + lane * 8;
        bhv[ni] = *(const bf16x8*)(lds + WHOFF + off);
        blv[ni] = *(const bf16x8*)(lds + WLOFF + off);
    }
    #pragma unroll
    for (int mi = 0; mi < 4; ++mi) {
        bf16x8 ah = *(const bf16x8*)(lds + AOFF + (wm * 4 + mi) * 512 + lane * 8);
        #pragma unroll
        for (int ni = 0; ni < 4; ++ni) {
            acc[mi][ni] = __builtin_amdgcn_mfma_f32_16x16x32_bf16(ah, bhv[ni], acc[mi][ni], 0, 0, 0);
            acc[mi][ni] = __builtin_amdgcn_mfma_f32_16x16x32_bf16(ah, blv[ni], acc[mi][ni], 0, 0, 0);
        }
    }
    constexpr int ELDW = 68;
    float* S = (float*)lds + (size_t)w * 16 * ELDW;
    const int rrow = lane >> 3;
    const int grp  = lane & 7;
    #pragma unroll
    for (int mi = 0; mi < 4; ++mi) {
        __syncthreads();
        #pragma unroll
        for (int ni = 0; ni < 4; ++ni)
            #pragma unroll
            for (int reg = 0; reg < 4; ++reg)
                S[(lk * 4 + reg) * ELDW + ni * 16 + lr] = acc[mi][ni][reg];
        __syncthreads();
        #pragma unroll
        for (int it = 0; it < 2; ++it) {
            int row_i = rrow + it * 8;
            int gr = row0 + wm * 64 + mi * 16 + row_i;
            int gc = wn * 64 + grp * 8;
            if (gr >= NF) continue;
            float4 f0 = *(const float4*)(&S[row_i * ELDW + grp * 8]);
            float4 f1 = *(const float4*)(&S[row_i * ELDW + grp * 8 + 4]);
            float4 b0 = *(const float4*)(bfl + gc);
            float4 b1 = *(const float4*)(bfl + gc + 4);
            u16x8 hh;
            hh[0] = f2bf(fmaxf(f0.x + b0.x, 0.f));
            hh[1] = f2bf(fmaxf(f0.y + b0.y, 0.f));
            hh[2] = f2bf(fmaxf(f0.z + b0.z, 0.f));
            hh[3] = f2bf(fmaxf(f0.w + b0.w, 0.f));
            hh[4] = f2bf(fmaxf(f1.x + b1.x, 0.f));
            hh[5] = f2bf(fmaxf(f1.y + b1.y, 0.f));
            hh[6] = f2bf(fmaxf(f1.z + b1.z, 0.f));
            hh[7] = f2bf(fmaxf(f1.w + b1.w, 0.f));
            *(u16x8*)(hH + (size_t)gr * D + gc) = hh;
        }
    }
}

// ------- y = h[src-type rows] @ Wr[rel]  (Wr precomputed) -------------------
__global__ __launch_bounds__(256) void y_kernel(
    const ushort* __restrict__ hH, const float* __restrict__ wr,
    float* __restrict__ y)
{
    int row = blockIdx.x;            // 0..429  (airports then carriers)
    int c = threadIdx.x;
    const ushort* sH = hH + (size_t)(NF + row) * D;
    const float* W = wr + (size_t)((row < NA) ? 1 : 3) * DD;
    float acc = 0.f;
    #pragma unroll 8
    for (int k = 0; k < D; ++k) acc += bf2f(sH[k]) * W[k * D + c];
    y[(size_t)row * D + c] = acc;
}

// ---- bf16 MFMA GEMM: G = A @ root^T + bias (A single-plane, W split) ------
// 8 waves, 64x32 sub-tiles, fragment-major global_load_lds staging, 2-buffer
// pipeline with COUNTED vmcnt(3).
__global__ __launch_bounds__(512) void gemm_mfma(
    const ushort* __restrict__ A,
    const ushort* __restrict__ WtH, const ushort* __restrict__ WtL,
    const float* __restrict__ bias,
    ushort* __restrict__ G, int nrows)
{
    constexpr int BM = 128, BK = 32;
    constexpr int PLANE = BM * BK;          // 4096 ushorts = 8 KB
    constexpr int BUF = 3 * PLANE;          // 12288 ushorts = 24 KB
    constexpr int LDW = 36;                 // fp32 epilogue scratch stride
    __shared__ __align__(16) ushort lds[2 * BUF];   // 49152 B (2 buffers)
    const int t = threadIdx.x;
    const int row0 = blockIdx.x * BM;
    const int col0 = blockIdx.y * BM;
    const int w = t >> 6, lane = t & 63;    // 8 waves
    const int wm = w >> 2, wn = w & 3;      // 2x4 wave grid, 64x32 per wave
    const int lr = lane & 15;
    const int lk = lane >> 4;
    f32x4 acc[4][2] = {};

    const ushort* sp[3];
    int dofs[3];
    #pragma unroll
    for (int i = 0; i < 3; ++i) {
        int idx = w * 3 + i;
        int plane = idx >> 3, g = idx & 7;
        const ushort* base = (plane == 0) ? A : (plane == 1) ? WtH : WtL;
        int r = ((plane == 0) ? row0 : col0) + g * 16 + lr;
        if (plane == 0 && r >= nrows) r = nrows - 1;
        sp[i] = base + (size_t)r * D + lk * 8;
        dofs[i] = plane * PLANE + g * 512;
    }

    auto stage = [&](int kt, int buf) {
        ushort* bb = lds + buf * BUF;
        int k0 = kt * BK;
        #pragma unroll
        for (int i = 0; i < 3; ++i)
            gload_lds16(sp[i] + k0, bb + dofs[i]);
    };
    auto compute = [&](int buf) {
        const ushort* base = lds + buf * BUF;
        const ushort* As  = base;
        const ushort* WsH = base + PLANE;
        const ushort* WsL = base + 2 * PLANE;
        bf16x8 bh[2], bl[2];
        #pragma unroll
        for (int ni = 0; ni < 2; ++ni) {
            int off = (wn * 2 + ni) * 512 + lane * 8;
            bh[ni] = *(const bf16x8*)(&WsH[off]);
            bl[ni] = *(const bf16x8*)(&WsL[off]);
        }
        #pragma unroll
        for (int mi = 0; mi < 4; ++mi) {
            int off = (wm * 4 + mi) * 512 + lane * 8;
            bf16x8 ah = *(const bf16x8*)(&As[off]);
            #pragma unroll
            for (int ni = 0; ni < 2; ++ni) {
                acc[mi][ni] = __builtin_amdgcn_mfma_f32_16x16x32_bf16(ah, bh[ni], acc[mi][ni], 0, 0, 0);
                acc[mi][ni] = __builtin_amdgcn_mfma_f32_16x16x32_bf16(ah, bl[ni], acc[mi][ni], 0, 0, 0);
            }
        }
    };

    stage(0, 0);
    stage(1, 1);
#define PIPE_ITER(KT, PEND)                                        \
    asm volatile("s_waitcnt vmcnt(" #PEND ")" ::: "memory");       \
    __builtin_amdgcn_s_barrier();                                  \
    __builtin_amdgcn_sched_barrier(0);                             \
    compute((KT) & 1);                                             \
    __builtin_amdgcn_s_barrier();                                  \
    __builtin_amdgcn_sched_barrier(0);                             \
    if ((KT) + 2 < 8) stage((KT) + 2, (KT) & 1);
    PIPE_ITER(0, 3)
    PIPE_ITER(1, 3)
    PIPE_ITER(2, 3)
    PIPE_ITER(3, 3)
    PIPE_ITER(4, 3)
    PIPE_ITER(5, 3)
    PIPE_ITER(6, 3)
    PIPE_ITER(7, 0)
#undef PIPE_ITER

    __syncthreads();
    float* S = (float*)lds + (size_t)w * 16 * LDW;   // per-wave 16x36 fp32
    const int rrow = lane >> 2;            // 0..15 read-back row
    const int grp  = lane & 3;             // col octet (8 bf16)
    #pragma unroll
    for (int mi = 0; mi < 4; ++mi) {
        __syncthreads();
        #pragma unroll
        for (int ni = 0; ni < 2; ++ni)
            #pragma unroll
            for (int reg = 0; reg < 4; ++reg)
                S[(lk * 4 + reg) * LDW + ni * 16 + lr] = acc[mi][ni][reg];
        __syncthreads();
        int gr = row0 + wm * 64 + mi * 16 + rrow;
        int gc = col0 + wn * 32 + grp * 8;
        if (gr >= nrows) continue;
        float4 f0 = *(const float4*)(&S[rrow * LDW + grp * 8]);
        float4 f1 = *(const float4*)(&S[rrow * LDW + grp * 8 + 4]);
        float4 b0 = *(const float4*)(bias + gc);
        float4 b1 = *(const float4*)(bias + gc + 4);
        float v[8] = {f0.x + b0.x, f0.y + b0.y, f0.z + b0.z, f0.w + b0.w,
                      f1.x + b1.x, f1.y + b1.y, f1.z + b1.z, f1.w + b1.w};
        u16x8 hh;
        #pragma unroll
        for (int j = 0; j < 8; ++j) hh[j] = f2bf(v[j]);
        *(u16x8*)(G + (size_t)gr * D + gc) = hh;
    }
}

// ---- layer-0 flight rows: G = relu(G + inv1*Σy1 + inv3*Σy3) in place ------
__global__ __launch_bounds__(256) void msg_relu_kernel(
    ushort* __restrict__ G,
    const float* __restrict__ y,
    const int* __restrict__ rp1, const int* __restrict__ csr1, const float* __restrict__ inv1,
    const int* __restrict__ rp3, const int* __restrict__ csr3, const float* __restrict__ inv3)
{
    int wid = (blockIdx.x * 256 + threadIdx.x) >> 6;
    int lane = threadIdx.x & 63;
    int row = wid * 2 + (lane >> 5);
    if (row >= NF) return;
    int c = (lane & 31) * 8;
    size_t o = (size_t)row * D + c;
    u16x8 gh = *(const u16x8*)(G + o);
    float v[8];
    #pragma unroll
    for (int j = 0; j < 8; ++j) v[j] = bf2f(gh[j]);
    float m[8] = {};
    int e0 = rp1[row], e1 = rp1[row + 1];
    for (int e = e0; e < e1; ++e) {
        const float* yr = y + (size_t)csr1[e] * D + c;
        float4 u0 = *(const float4*)yr;
        float4 u1 = *(const float4*)(yr + 4);
        m[0] += u0.x; m[1] += u0.y; m[2] += u0.z; m[3] += u0.w;
        m[4] += u1.x; m[5] += u1.y; m[6] += u1.z; m[7] += u1.w;
    }
    float s1 = inv1[row];
    #pragma unroll
    for (int j = 0; j < 8; ++j) { v[j] += s1 * m[j]; m[j] = 0.f; }
    e0 = rp3[row]; e1 = rp3[row + 1];
    for (int e = e0; e < e1; ++e) {
        const float* yr = y + (size_t)(NA + csr3[e]) * D + c;
        float4 u0 = *(const float4*)yr;
        float4 u1 = *(const float4*)(yr + 4);
        m[0] += u0.x; m[1] += u0.y; m[2] += u0.z; m[3] += u0.w;
        m[4] += u1.x; m[5] += u1.y; m[6] += u1.z; m[7] += u1.w;
    }
    float s3 = inv3[row];
    u16x8 oh;
    #pragma unroll
    for (int j = 0; j < 8; ++j) oh[j] = f2bf(fmaxf(v[j] + s3 * m[j], 0.f));
    *(u16x8*)(G + o) = oh;
}

// ---- layer-1: out[f] = relu(G2+msgs) . W_out + b_out (fused readout) -------
__global__ __launch_bounds__(256) void msg_readout_kernel(
    const ushort* __restrict__ G,
    const float* __restrict__ y,
    const int* __restrict__ rp1, const int* __restrict__ csr1, const float* __restrict__ inv1,
    const int* __restrict__ rp3, const int* __restrict__ csr3, const float* __restrict__ inv3,
    const float* __restrict__ wout, const float* __restrict__ bout,
    float* __restrict__ out)
{
    int wid = (blockIdx.x * 256 + threadIdx.x) >> 6;
    int lane = threadIdx.x & 63;
    int row = wid * 2 + (lane >> 5);
    if (row >= NF) return;
    int c = (lane & 31) * 8;
    size_t o = (size_t)row * D + c;
    u16x8 gh = *(const u16x8*)(G + o);
    float v[8];
    #pragma unroll
    for (int j = 0; j < 8; ++j) v[j] = bf2f(gh[j]);
    float m[8] = {};
    int e0 = rp1[row], e1 = rp1[row + 1];
    for (int e = e0; e < e1; ++e) {
        const float* yr = y + (size_t)csr1[e] * D + c;
        float4 u0 = *(const float4*)yr;
        float4 u1 = *(const float4*)(yr + 4);
        m[0] += u0.x; m[1] += u0.y; m[2] += u0.z; m[3] += u0.w;
        m[4] += u1.x; m[5] += u1.y; m[6] += u1.z; m[7] += u1.w;
    }
    float s1 = inv1[row];
    #pragma unroll
    for (int j = 0; j < 8; ++j) { v[j] += s1 * m[j]; m[j] = 0.f; }
    e0 = rp3[row]; e1 = rp3[row + 1];
    for (int e = e0; e < e1; ++e) {
        const float* yr = y + (size_t)(NA + csr3[e]) * D + c;
        float4 u0 = *(const float4*)yr;
        float4 u1 = *(const float4*)(yr + 4);
        m[0] += u0.x; m[1] += u0.y; m[2] += u0.z; m[3] += u0.w;
        m[4] += u1.x; m[5] += u1.y; m[6] += u1.z; m[7] += u1.w;
    }
    float s3 = inv3[row];
    float4 w0 = *(const float4*)(wout + c);
    float4 w1 = *(const float4*)(wout + c + 4);
    float wv[8] = {w0.x, w0.y, w0.z, w0.w, w1.x, w1.y, w1.z, w1.w};
    float pr = 0.f;
    #pragma unroll
    for (int j = 0; j < 8; ++j) pr += fmaxf(v[j] + s3 * m[j], 0.f) * wv[j];
    pr += __shfl_xor(pr, 1);
    pr += __shfl_xor(pr, 2);
    pr += __shfl_xor(pr, 4);
    pr += __shfl_xor(pr, 8);
    pr += __shfl_xor(pr, 16);
    if ((lane & 31) == 0) out[row] = pr + bout[0];
}

// ---- r0/r2: agg[dst] += hH[src] — 2 edges per wave, 16B/lane loads ---------
__global__ __launch_bounds__(256) void agg_small_kernel(
    const ushort* __restrict__ hH,
    const int* __restrict__ rp0, const int* __restrict__ csr0,
    const int* __restrict__ rp2, const int* __restrict__ csr2,
    float* __restrict__ agg)
{
    __shared__ float red[4][256];
    int b = blockIdx.x;
    const int* rp; const int* csr; int dstn, chunk, nch; float* arow;
    if (b < NA * 4) { dstn = b >> 2; chunk = b & 3; nch = 4;  rp = rp0; csr = csr0; arow = agg + (size_t)dstn * D; }
    else { int bb = b - NA * 4; dstn = bb >> 6; chunk = bb & 63; nch = 64; rp = rp2; csr = csr2; arow = agg + (size_t)(NA + dstn) * D; }
    int s = rp[dstn], e = rp[dstn + 1];
    int cnt = e - s;
    int lo = s + (int)((long long)cnt * chunk / nch);
    int hi = s + (int)((long long)cnt * (chunk + 1) / nch);
    int w = threadIdx.x >> 6, lane = threadIdx.x & 63;
    int span = hi - lo;
    int wlo = lo + (int)((long long)span * w / 4);
    int whi = lo + (int)((long long)span * (w + 1) / 4);
    int half = lane >> 5;                  // 0: edge p, 1: edge p+1
    int ch8 = (lane & 31) * 8;
    float acc[8] = {};
    int p = wlo;
    for (; p + 1 < whi; p += 2) {
        int r = csr[p + half];
        u16x8 v = *(const u16x8*)(hH + (size_t)r * D + ch8);
        #pragma unroll
        for (int j = 0; j < 8; ++j) acc[j] += bf2f(v[j]);
    }
    if (p < whi && half == 0) {
        int r = csr[p];
        u16x8 v = *(const u16x8*)(hH + (size_t)r * D + ch8);
        #pragma unroll
        for (int j = 0; j < 8; ++j) acc[j] += bf2f(v[j]);
    }
    #pragma unroll
    for (int j = 0; j < 8; ++j) acc[j] += __shfl_xor(acc[j], 32);
    if (lane < 32) {
        #pragma unroll
        for (int j = 0; j < 8; ++j) red[w][ch8 + j] = acc[j];
    }
    __syncthreads();
    int c = threadIdx.x;
    float total = red[0][c] + red[1][c] + red[2][c] + red[3][c];
    atomicAdd(arow + c, total);
}

// -- r0/r2 transform: G = relu(G + inv_deg*(agg @ Wr[rel])) in place ---------
__global__ __launch_bounds__(256) void smallT_kernel(
    const float* __restrict__ agg, const float* __restrict__ wr,
    const float* __restrict__ inv0, const float* __restrict__ inv2,
    ushort* __restrict__ G)
{
    int row = blockIdx.x;            // 0..429
    int c = threadIdx.x;
    const float* a = agg + (size_t)row * D;
    const float* W = wr + (size_t)((row < NA) ? 0 : 2) * DD;
    float scale = (row < NA) ? inv0[row] : inv2[row - NA];
    float acc = 0.f;
    #pragma unroll 8
    for (int k = 0; k < D; ++k) acc += a[k] * W[k * D + c];
    size_t o = (size_t)(NF + row) * D + c;
    G[o] = f2bf(fmaxf(bf2f(G[o]) + scale * acc, 0.f));
}

extern "C" void kernel_launch(void* const* d_in, const int* in_sizes, int n_in,
                              void* d_out, int out_size, void* d_ws, size_t ws_size,
                              hipStream_t stream)
{
    const float* xf = (const float*)d_in[0];
    const float* xa = (const float*)d_in[1];
    const float* xc = (const float*)d_in[2];
    const float* Wf = (const float*)d_in[3];
    const float* bf = (const float*)d_in[4];
    const float* Wa = (const float*)d_in[5];
    const float* ba = (const float*)d_in[6];
    const float* Wc = (const float*)d_in[7];
    const float* bc = (const float*)d_in[8];
    const float* basis0 = (const float*)d_in[9];
    const float* comp0  = (const float*)d_in[10];
    const float* root0  = (const float*)d_in[11];
    const float* bias0  = (const float*)d_in[12];
    const float* basis1 = (const float*)d_in[13];
    const float* comp1  = (const float*)d_in[14];
    const float* root1  = (const float*)d_in[15];
    const float* bias1  = (const float*)d_in[16];
    const float* Wout = (const float*)d_in[17];
    const float* bout = (const float*)d_in[18];
    const int* src0 = (const int*)d_in[19];
    const int* dst0 = (const int*)d_in[20];
    const int* src1 = (const int*)d_in[21];
    const int* dst1 = (const int*)d_in[22];
    const int* src2 = (const int*)d_in[23];
    const int* dst2 = (const int*)d_in[24];
    const int* src3 = (const int*)d_in[25];
    const int* dst3 = (const int*)d_in[26];
    float* out = (float*)d_out;

    char* ws = (char*)d_ws;
    size_t off = 0;
    auto alloc = [&](size_t bytes) -> char* {
        char* p = ws + off;
        off = (off + bytes + 255) & ~(size_t)255;
        return p;
    };
    ushort* hH  = (ushort*)alloc((size_t)NN * D * 2);
    ushort* gH  = (ushort*)alloc((size_t)NN * D * 2);
    // layer-1 GEMM output reuses hH (dead after layer-0 consumers)
    ushort* g2H = hH;
    ushort* WtH0 = (ushort*)alloc((size_t)DD * 2);
    ushort* WtL0 = (ushort*)alloc((size_t)DD * 2);
    ushort* WtH1 = (ushort*)alloc((size_t)DD * 2);
    ushort* WtL1 = (ushort*)alloc((size_t)DD * 2);
    ushort* WfTH = (ushort*)alloc((size_t)D * 32 * 2);
    ushort* WfTL = (ushort*)alloc((size_t)D * 32 * 2);
    float* wr0    = (float*)alloc((size_t)4 * DD * 4);
    float* wr1    = (float*)alloc((size_t)4 * DD * 4);
    float* ybuf   = (float*)alloc((size_t)(NA + NC) * D * 4);
    float* aggbuf = (float*)alloc((size_t)(NA + NC) * D * 4);
    int*   deg13  = (int*)  alloc((size_t)2 * NF * 4);
    int* deg1 = deg13; int* deg3 = deg13 + NF;
    float* inv1 = (float*)alloc((size_t)NF * 4);
    float* inv3 = (float*)alloc((size_t)NF * 4);
    float* inv0 = (float*)alloc((size_t)NA * 4);
    float* inv2 = (float*)alloc((size_t)NC * 4);
    int* rp0 = (int*)alloc((NA + 1) * 4);
    int* rp1 = (int*)alloc((size_t)(NF + 1) * 4);
    int* rp2 = (int*)alloc((NC + 1) * 4);
    int* rp3 = (int*)alloc((size_t)(NF + 1) * 4);
    int* cu1 = (int*)alloc((size_t)(NF + 1) * 4);
    int* cu3 = (int*)alloc((size_t)(NF + 1) * 4);
    int* csr0 = (int*)alloc((size_t)E * 4);
    int* csr1 = (int*)alloc((size_t)E * 4);
    int* csr2 = (int*)alloc((size_t)E * 4);
    int* csr3 = (int*)alloc((size_t)E * 4);
    int* bsum = (int*)alloc(256 * 4);
    int* bh0  = (int*)alloc((size_t)NSL * NA * 4);
    int* bh2  = (int*)alloc((size_t)NSL * NC * 4);
    (void)ws_size; (void)in_sizes; (void)n_in; (void)out_size;

    // deg13 must be zero before prep_kernel's deg_count blocks (stream order)
    hipMemsetAsync(deg13, 0, (size_t)2 * NF * 4, stream);

    // K1: hist02 + deg_count + wsplit(x2) + wr(x2)
    prep_kernel<<<K1_WR1_END, 256, 0, stream>>>(
        dst0, dst2, bh0, bh2, aggbuf, Wf, WfTH, WfTL,
        dst1, dst3, deg1, deg3,
        root0, WtH0, WtL0, root1, WtH1, WtL1,
        basis0, comp0, wr0, basis1, comp1, wr1);

    // K2: scanA + scan02
    scan_kernel<<<197, 1024, 0, stream>>>(
        deg1, deg3, bsum, bh0, bh2, rp0, rp2, inv0, inv2);

    // K3: fill02 + scanC
    fill_scan_kernel<<<2 * NSL + 196, 1024, 0, stream>>>(
        src0, dst0, src2, dst2, bh0, bh2, csr0, csr2,
        deg1, deg3, bsum, rp1, rp3, cu1, cu3, inv1, inv3);

    // K4: encoders + csr_fill13
    encode_fill_kernel<<<FBLK + TAILB + F13B, 512, 0, stream>>>(
        xf, WfTH, WfTL, bf, xa, Wa, ba, xc, Wc, bc, hH,
        src1, dst1, src3, dst3, cu1, cu3, csr1, csr3);

    // ---- layer 0
    y_kernel<<<NA + NC, 256, 0, stream>>>(hH, wr0, ybuf);
    gemm_mfma<<<dim3((NN + 127) / 128, 2), 512, 0, stream>>>(
        hH, WtH0, WtL0, bias0, gH, NN);
    agg_small_kernel<<<NA * 4 + NC * 64, 256, 0, stream>>>(
        hH, rp0, csr0, rp2, csr2, aggbuf);
    smallT_kernel<<<NA + NC, 256, 0, stream>>>(aggbuf, wr0, inv0, inv2, gH);
    msg_relu_kernel<<<(NF / 2 * 64 + 255) / 256, 256, 0, stream>>>(
        gH, ybuf, rp1, csr1, inv1, rp3, csr3, inv3);

    // ---- layer 1
    y_kernel<<<NA + NC, 256, 0, stream>>>(gH, wr1, ybuf);
    gemm_mfma<<<dim3((NF + 127) / 128, 2), 512, 0, stream>>>(
        gH, WtH1, WtL1, bias1, g2H, NF);
    msg_readout_kernel<<<(NF / 2 * 64 + 255) / 256, 256, 0, stream>>>(
        g2H, ybuf, rp1, csr1, inv1, rp3, csr3, inv3, Wout, bout, out);
}

// Round 23
// 332.584 us; speedup vs baseline: 1.2612x; 1.0565x over previous
//
#include <hip/hip_runtime.h>
#include <hip/hip_bf16.h>
#include <cstdint>
#include <cstddef>

constexpr int NF = 100000;
constexpr int NA = 400;
constexpr int NC = 30;
constexpr int NN = NF + NA + NC;     // 100430
constexpr int D  = 256;
constexpr int DD = D * D;            // 65536
constexpr int E  = 250000;
constexpr int NSL = 128;             // slices for r0/r2 counting sort
constexpr int FBLK = (NF + 127) / 128;   // 782 flight-encoder blocks
constexpr int TAILB = (NA + NC + 7) / 8; // 54 scalar-tail blocks
constexpr int F13B = (2 * E + 511) / 512; // 977 csr_fill13 blocks (512 thr)
constexpr int AGGB = NA * 4 + NC * 64;    // 3520 agg chunks
constexpr int YB   = (NA + NC) / 2;       // 215 y blocks (2 rows each)

// K1 block ranges
constexpr int K1_HIST_END = 2 * NSL;                       // 256
constexpr int K1_DEG_END  = K1_HIST_END + (2 * E + 255) / 256;  // 2210
constexpr int K1_WS0_END  = K1_DEG_END + 256;              // 2466
constexpr int K1_WS1_END  = K1_WS0_END + 256;              // 2722
constexpr int K1_WR0_END  = K1_WS1_END + 1024;             // 3746
constexpr int K1_WR1_END  = K1_WR0_END + 1024;             // 4770

typedef __attribute__((ext_vector_type(8))) short bf16x8;
typedef __attribute__((ext_vector_type(4))) float f32x4;
typedef __attribute__((ext_vector_type(8))) ushort u16x8;

__device__ inline ushort f2bf(float f) {
    __hip_bfloat16 h = __float2bfloat16(f);
    return __builtin_bit_cast(ushort, h);
}
__device__ inline float bf2f(ushort u) {
    __hip_bfloat16 h = __builtin_bit_cast(__hip_bfloat16, u);
    return __bfloat162float(h);
}

// async global->LDS, 16B per lane: LDS dest = base + lane*16 (wave-linear)
__device__ inline void gload_lds16(const ushort* g, ushort* l) {
    __builtin_amdgcn_global_load_lds(
        (const __attribute__((address_space(1))) void*)g,
        (__attribute__((address_space(3))) void*)l, 16, 0, 0);
}

// ==== K1: hist02 + deg_count + wsplit(x2) + wr(x2), co-scheduled ============
__global__ __launch_bounds__(256) void prep_kernel(
    const int* __restrict__ dst0, const int* __restrict__ dst2,
    int* __restrict__ bh0, int* __restrict__ bh2,
    float* __restrict__ aggz,
    const float* __restrict__ Wf, ushort* __restrict__ WfTH, ushort* __restrict__ WfTL,
    const int* __restrict__ dst1, const int* __restrict__ dst3,
    int* __restrict__ deg1, int* __restrict__ deg3,
    const float* __restrict__ root0, ushort* __restrict__ WtH0, ushort* __restrict__ WtL0,
    const float* __restrict__ root1, ushort* __restrict__ WtH1, ushort* __restrict__ WtL1,
    const float* __restrict__ basis0, const float* __restrict__ comp0, float* __restrict__ wr0,
    const float* __restrict__ basis1, const float* __restrict__ comp1, float* __restrict__ wr1)
{
    __shared__ int hist[NA];
    const int b = blockIdx.x;
    const int t = threadIdx.x;
    if (b < K1_HIST_END) {
        for (int i = b * 256 + t; i < (NA + NC) * D; i += K1_HIST_END * 256)
            aggz[i] = 0.f;
        if (b < 32) {
            float wv = Wf[(size_t)b * D + t];
            ushort hi = f2bf(wv);
            WfTH[(size_t)t * 32 + b] = hi;
            WfTL[(size_t)t * 32 + b] = f2bf(wv - bf2f(hi));
        }
        bool isR2 = (b >= NSL);
        int sl = isR2 ? b - NSL : b;
        const int* dst = isR2 ? dst2 : dst0;
        int nb = isR2 ? NC : NA;
        for (int i = t; i < nb; i += 256) hist[i] = 0;
        __syncthreads();
        int lo = (int)((long long)E * sl / NSL);
        int hi = (int)((long long)E * (sl + 1) / NSL);
        for (int e = lo + t; e < hi; e += 256)
            atomicAdd(&hist[dst[e]], 1);
        __syncthreads();
        int* bh = isR2 ? (bh2 + sl * NC) : (bh0 + sl * NA);
        for (int i = t; i < nb; i += 256) bh[i] = hist[i];
    } else if (b < K1_DEG_END) {
        int idx = (b - K1_HIST_END) * 256 + t;
        if (idx < 2 * E) {
            if (idx < E) atomicAdd(&deg1[dst1[idx]], 1);
            else         atomicAdd(&deg3[dst3[idx - E]], 1);
        }
    } else if (b < K1_WS0_END) {
        int n = b - K1_DEG_END;
        float w = root0[(size_t)t * D + n];
        ushort hi = f2bf(w);
        WtH0[(size_t)n * D + t] = hi;
        WtL0[(size_t)n * D + t] = f2bf(w - bf2f(hi));
    } else if (b < K1_WS1_END) {
        int n = b - K1_WS0_END;
        float w = root1[(size_t)t * D + n];
        ushort hi = f2bf(w);
        WtH1[(size_t)n * D + t] = hi;
        WtL1[(size_t)n * D + t] = f2bf(w - bf2f(hi));
    } else if (b < K1_WR0_END) {
        int idx = (b - K1_WS1_END) * 256 + t;
        int r = idx >> 16;
        int io = idx & (DD - 1);
        wr0[idx] = comp0[r * 3 + 0] * basis0[io]
                 + comp0[r * 3 + 1] * basis0[DD + io]
                 + comp0[r * 3 + 2] * basis0[2 * DD + io];
    } else {
        int idx = (b - K1_WR0_END) * 256 + t;
        int r = idx >> 16;
        int io = idx & (DD - 1);
        wr1[idx] = comp1[r * 3 + 0] * basis1[io]
                 + comp1[r * 3 + 1] * basis1[DD + io]
                 + comp1[r * 3 + 2] * basis1[2 * DD + io];
    }
}

// ==== K2: scanA (blocks 0..195) + scan02 (block 196), co-scheduled ==========
__global__ __launch_bounds__(1024) void scan_kernel(
    const int* __restrict__ deg1, const int* __restrict__ deg3,
    int* __restrict__ bsum,
    int* __restrict__ bh0, int* __restrict__ bh2,
    int* __restrict__ rp0, int* __restrict__ rp2,
    float* __restrict__ inv0, float* __restrict__ inv2)
{
    __shared__ int s[1024];
    __shared__ int tot[512];
    __shared__ int exc[512];
    const int b = blockIdx.x;
    const int t = threadIdx.x;
    if (b < 196) {
        bool isR3 = (b >= 98);
        const int* deg = isR3 ? deg3 : deg1;
        int chunk = isR3 ? b - 98 : b;
        int i = chunk * 1024 + t;
        int v = (i < NF) ? deg[i] : 0;
        s[t] = v;
        __syncthreads();
        for (int ofs = 512; ofs > 0; ofs >>= 1) {
            if (t < ofs) s[t] += s[t + ofs];
            __syncthreads();
        }
        if (t == 0) bsum[(isR3 ? 128 : 0) + chunk] = s[0];
        return;
    }
    int cnt = 0;
    if (t < NA) {
        int ss = 0;
        for (int sl = 0; sl < NSL; ++sl) {
            int v = bh0[sl * NA + t]; bh0[sl * NA + t] = ss; ss += v;
        }
        cnt = ss;
    } else if (t < NA + NC) {
        int bin = t - NA; int ss = 0;
        for (int sl = 0; sl < NSL; ++sl) {
            int v = bh2[sl * NC + bin]; bh2[sl * NC + bin] = ss; ss += v;
        }
        cnt = ss;
    }
    if (t < 512) tot[t] = cnt;
    __syncthreads();
    for (int ofs = 1; ofs < 512; ofs <<= 1) {
        int v = 0;
        if (t < 512 && t >= ofs) v = tot[t - ofs];
        __syncthreads();
        if (t < 512) tot[t] += v;
        __syncthreads();
    }
    if (t < 512) {
        int ex = tot[t] - cnt;
        if (t < NA) {
            exc[t] = ex;
            rp0[t] = ex;
            inv0[t] = 1.0f / (float)(cnt > 1 ? cnt : 1);
            if (t == 0) { rp0[NA] = E; rp2[NC] = E; }
        } else if (t < NA + NC) {
            exc[t] = ex - E;
            rp2[t - NA] = ex - E;
            inv2[t - NA] = 1.0f / (float)(cnt > 1 ? cnt : 1);
        } else exc[t] = 0;
    }
    __syncthreads();
    for (int idx = t; idx < NSL * NA; idx += 1024) {
        int sl = idx / NA; int bin = idx - sl * NA;
        bh0[idx] += exc[bin];
    }
    for (int idx = t; idx < NSL * NC; idx += 1024) {
        int sl = idx / NC; int bin = idx - sl * NC;
        bh2[idx] += exc[NA + bin];
    }
}

// ==== K3: fill02 (blocks 0..255) + scanC (blocks 256..451), co-scheduled ====
__global__ __launch_bounds__(1024) void fill_scan_kernel(
    const int* __restrict__ src0, const int* __restrict__ dst0,
    const int* __restrict__ src2, const int* __restrict__ dst2,
    const int* __restrict__ bh0, const int* __restrict__ bh2,
    int* __restrict__ csr0, int* __restrict__ csr2,
    const int* __restrict__ deg1, const int* __restrict__ deg3,
    const int* __restrict__ bsum,
    int* __restrict__ rp1, int* __restrict__ rp3,
    int* __restrict__ cu1, int* __restrict__ cu3,
    float* __restrict__ inv1, float* __restrict__ inv3)
{
    __shared__ int s[1024];
    __shared__ int s2[256];
    const int b = blockIdx.x;
    const int t = threadIdx.x;
    if (b < 2 * NSL) {
        bool isR2 = (b >= NSL);
        int sl = isR2 ? b - NSL : b;
        const int* src = isR2 ? src2 : src0;
        const int* dst = isR2 ? dst2 : dst0;
        const int* bh  = isR2 ? (bh2 + sl * NC) : (bh0 + sl * NA);
        int* csr       = isR2 ? csr2 : csr0;
        int nb = isR2 ? NC : NA;
        for (int i = t; i < nb; i += 1024) s[i] = bh[i];
        __syncthreads();
        int lo = (int)((long long)E * sl / NSL);
        int hi = (int)((long long)E * (sl + 1) / NSL);
        for (int e = lo + t; e < hi; e += 1024) {
            int pos = atomicAdd(&s[dst[e]], 1);
            csr[pos] = src[e];
        }
        return;
    }
    const int bb = b - 2 * NSL;
    int vb = 0;
    if (t < 256) {
        vb = ((t & 127) < 98) ? bsum[t] : 0;
        s2[t] = vb;
    }
    __syncthreads();
    for (int ofs = 1; ofs < 128; ofs <<= 1) {
        int a = 0;
        if (t < 256 && (t & 127) >= ofs) a = s2[t - ofs];
        __syncthreads();
        if (t < 256) s2[t] += a;
        __syncthreads();
    }
    if (t < 256) s2[t] -= vb;          // exclusive
    __syncthreads();
    const int* deg; int* rp; int* cu; float* inv; int chunk; int prefix;
    if (bb < 98) { deg = deg1; rp = rp1; cu = cu1; inv = inv1; chunk = bb;      prefix = s2[chunk]; }
    else         { deg = deg3; rp = rp3; cu = cu3; inv = inv3; chunk = bb - 98; prefix = s2[128 + chunk]; }
    int i = chunk * 1024 + t;
    int v = (i < NF) ? deg[i] : 0;
    s[t] = v;
    __syncthreads();
    for (int ofs = 1; ofs < 1024; ofs <<= 1) {
        int a = (t >= ofs) ? s[t - ofs] : 0;
        __syncthreads();
        s[t] += a;
        __syncthreads();
    }
    int ex = prefix + s[t] - v;
    if (i < NF) {
        rp[i] = ex;
        cu[i] = ex;
        inv[i] = 1.0f / (float)(v > 1 ? v : 1);
    }
    if (i == 0) rp[NF] = E;
}

// ==== K4: MFMA flight encoder + scalar tail + csr_fill13, co-scheduled ======
__global__ __launch_bounds__(512) void encode_fill_kernel(
    const float* __restrict__ xf,
    const ushort* __restrict__ WtH8, const ushort* __restrict__ WtL8,
    const float* __restrict__ bfl,
    const float* __restrict__ xa, const float* __restrict__ Wa, const float* __restrict__ ba,
    const float* __restrict__ xc, const float* __restrict__ Wc, const float* __restrict__ bc,
    ushort* __restrict__ hH,
    const int* __restrict__ src1, const int* __restrict__ dst1,
    const int* __restrict__ src3, const int* __restrict__ dst3,
    int* __restrict__ cu1, int* __restrict__ cu3,
    int* __restrict__ csr1, int* __restrict__ csr3)
{
    const int t = threadIdx.x;
    const int b = blockIdx.x;
    if (b >= FBLK + TAILB) {
        int idx = (b - FBLK - TAILB) * 512 + t;
        if (idx < 2 * E) {
            if (idx < E) {
                int pos = atomicAdd(&cu1[dst1[idx]], 1);
                csr1[pos] = src1[idx];
            } else {
                int e = idx - E;
                int pos = atomicAdd(&cu3[dst3[e]], 1);
                csr3[pos] = src3[e];
            }
        }
        return;
    }
    if (b >= FBLK) {
        int c = t & 255;
        int i0 = t >> 8;
        int base = (b - FBLK) * 8;
        for (int i = i0; i < 8; i += 2) {
            int row = base + i;
            if (row >= NA + NC) break;
            float acc;
            if (row < NA) {
                const float* xr = xa + (size_t)row * 16;
                acc = ba[c];
                #pragma unroll
                for (int k = 0; k < 16; ++k) acc += xr[k] * Wa[k * D + c];
            } else {
                const float* xr = xc + (size_t)(row - NA) * 8;
                acc = bc[c];
                #pragma unroll
                for (int k = 0; k < 8; ++k) acc += xr[k] * Wc[k * D + c];
            }
            hH[(size_t)(NF + row) * D + c] = f2bf(fmaxf(acc, 0.f));
        }
        return;
    }
    constexpr int AOFF = 0, WHOFF = 4096, WLOFF = 12288;   // ushort offsets
    __shared__ __align__(16) ushort lds[20480];            // 40960 B
    const int row0 = b * 128;
    const int w = t >> 6, lane = t & 63;     // 8 waves
    const int wm = w >> 2, wn = w & 3;       // 2x4 grid, 64 rows x 64 cols/wave
    const int lr = lane & 15;
    const int lk = lane >> 4;
    {
        int r = t >> 2;                      // 0..127
        int seg = (t & 3) * 8;               // 0,8,16,24
        int gr = row0 + r; if (gr >= NF) gr = NF - 1;
        const float* xr = xf + (size_t)gr * 32 + seg;
        float4 a0 = *(const float4*)xr;
        float4 a1 = *(const float4*)(xr + 4);
        u16x8 bb;
        bb[0] = f2bf(a0.x); bb[1] = f2bf(a0.y); bb[2] = f2bf(a0.z); bb[3] = f2bf(a0.w);
        bb[4] = f2bf(a1.x); bb[5] = f2bf(a1.y); bb[6] = f2bf(a1.z); bb[7] = f2bf(a1.w);
        int g = r >> 4, rr = r & 15, kg = seg >> 3;
        *(u16x8*)(lds + AOFF + g * 512 + (rr + 16 * kg) * 8) = bb;
    }
    #pragma unroll
    for (int i = 0; i < 4; ++i) {
        int u = w * 4 + i;                   // 0..31
        int plane = u >> 4, g = u & 15;
        const ushort* src = (plane ? WtL8 : WtH8) + ((size_t)(g * 16 + lr)) * 32 + lk * 8;
        ushort* dst = lds + (plane ? WLOFF : WHOFF) + g * 512;
        gload_lds16(src, dst);
    }
    __syncthreads();
    f32x4 acc[4][4] = {};
    bf16x8 bhv[4], blv[4];
    #pragma unroll
    for (int ni = 0; ni < 4; ++ni) {
        int off = (wn * 4 + ni) * 512 + lane * 8;
        bhv[ni] = *(const bf16x8*)(lds + WHOFF + off);
        blv[ni] = *(const bf16x8*)(lds + WLOFF + off);
    }
    #pragma unroll
    for (int mi = 0; mi < 4; ++mi) {
        bf16x8 ah = *(const bf16x8*)(lds + AOFF + (wm * 4 + mi) * 512 + lane * 8);
        #pragma unroll
        for (int ni = 0; ni < 4; ++ni) {
            acc[mi][ni] = __builtin_amdgcn_mfma_f32_16x16x32_bf16(ah, bhv[ni], acc[mi][ni], 0, 0, 0);
            acc[mi][ni] = __builtin_amdgcn_mfma_f32_16x16x32_bf16(ah, blv[ni], acc[mi][ni], 0, 0, 0);
        }
    }
    constexpr int ELDW = 68;
    float* S = (float*)lds + (size_t)w * 16 * ELDW;
    const int rrow = lane >> 3;
    const int grp  = lane & 7;
    #pragma unroll
    for (int mi = 0; mi < 4; ++mi) {
        __syncthreads();
        #pragma unroll
        for (int ni = 0; ni < 4; ++ni)
            #pragma unroll
            for (int reg = 0; reg < 4; ++reg)
                S[(lk * 4 + reg) * ELDW + ni * 16 + lr] = acc[mi][ni][reg];
        __syncthreads();
        #pragma unroll
        for (int it = 0; it < 2; ++it) {
            int row_i = rrow + it * 8;
            int gr = row0 + wm * 64 + mi * 16 + row_i;
            int gc = wn * 64 + grp * 8;
            if (gr >= NF) continue;
            float4 f0 = *(const float4*)(&S[row_i * ELDW + grp * 8]);
            float4 f1 = *(const float4*)(&S[row_i * ELDW + grp * 8 + 4]);
            float4 b0 = *(const float4*)(bfl + gc);
            float4 b1 = *(const float4*)(bfl + gc + 4);
            u16x8 hh;
            hh[0] = f2bf(fmaxf(f0.x + b0.x, 0.f));
            hh[1] = f2bf(fmaxf(f0.y + b0.y, 0.f));
            hh[2] = f2bf(fmaxf(f0.z + b0.z, 0.f));
            hh[3] = f2bf(fmaxf(f0.w + b0.w, 0.f));
            hh[4] = f2bf(fmaxf(f1.x + b1.x, 0.f));
            hh[5] = f2bf(fmaxf(f1.y + b1.y, 0.f));
            hh[6] = f2bf(fmaxf(f1.z + b1.z, 0.f));
            hh[7] = f2bf(fmaxf(f1.w + b1.w, 0.f));
            *(u16x8*)(hH + (size_t)gr * D + gc) = hh;
        }
    }
}

// ==== layer kernel: gemm tiles + (MODE 0: agg chunks) + y rows, co-sched ====
// MODE 0: A=hH, gemm over NN rows -> gH; agg over r0/r2 CSR; y from hH.
// MODE 1: A=gH, gemm over NF rows -> g2H; y from gH.
template<int MODE>
__global__ __launch_bounds__(512) void layer_kernel(
    const ushort* __restrict__ A,
    const ushort* __restrict__ WtH, const ushort* __restrict__ WtL,
    const float* __restrict__ bias, ushort* __restrict__ G,
    const float* __restrict__ wr, float* __restrict__ y,
    const int* __restrict__ rp0, const int* __restrict__ csr0,
    const int* __restrict__ rp2, const int* __restrict__ csr2,
    float* __restrict__ agg)
{
    constexpr int BM = 128, BK = 32;
    constexpr int PLANE = BM * BK;          // 4096 ushorts = 8 KB
    constexpr int BUF = 3 * PLANE;          // 12288 ushorts = 24 KB
    constexpr int LDW = 36;                 // fp32 epilogue scratch stride
    constexpr int nrows = (MODE == 0) ? NN : NF;
    constexpr int NG = ((nrows + 127) / 128) * 2;
    constexpr int NAGG = (MODE == 0) ? AGGB : 0;
    __shared__ __align__(16) ushort lds[2 * BUF];   // 49152 B
    const int t = threadIdx.x;
    const int b = blockIdx.x;
    if (b >= NG) {
        int bb = b - NG;
        if (MODE == 0 && bb < NAGG) {
            // ---- agg: 8-wave span split, 8-way LDS reduce ----
            float* red = (float*)lds;        // 8 x 256 floats
            const int* rp; const int* csr; int dstn, chunk, nch; float* arow;
            if (bb < NA * 4) { dstn = bb >> 2; chunk = bb & 3; nch = 4;  rp = rp0; csr = csr0; arow = agg + (size_t)dstn * D; }
            else { int b2 = bb - NA * 4; dstn = b2 >> 6; chunk = b2 & 63; nch = 64; rp = rp2; csr = csr2; arow = agg + (size_t)(NA + dstn) * D; }
            int s = rp[dstn], e = rp[dstn + 1];
            int cnt = e - s;
            int lo = s + (int)((long long)cnt * chunk / nch);
            int hi = s + (int)((long long)cnt * (chunk + 1) / nch);
            int w8 = t >> 6, lane = t & 63;
            int span = hi - lo;
            int wlo = lo + (int)((long long)span * w8 / 8);
            int whi = lo + (int)((long long)span * (w8 + 1) / 8);
            int half = lane >> 5;
            int ch8 = (lane & 31) * 8;
            float acc[8] = {};
            int p = wlo;
            for (; p + 1 < whi; p += 2) {
                int r = csr[p + half];
                u16x8 v = *(const u16x8*)(A + (size_t)r * D + ch8);
                #pragma unroll
                for (int j = 0; j < 8; ++j) acc[j] += bf2f(v[j]);
            }
            if (p < whi && half == 0) {
                int r = csr[p];
                u16x8 v = *(const u16x8*)(A + (size_t)r * D + ch8);
                #pragma unroll
                for (int j = 0; j < 8; ++j) acc[j] += bf2f(v[j]);
            }
            #pragma unroll
            for (int j = 0; j < 8; ++j) acc[j] += __shfl_xor(acc[j], 32);
            if (lane < 32) {
                #pragma unroll
                for (int j = 0; j < 8; ++j) red[w8 * 256 + ch8 + j] = acc[j];
            }
            __syncthreads();
            if (t < 256) {
                float total = 0.f;
                #pragma unroll
                for (int j = 0; j < 8; ++j) total += red[j * 256 + t];
                atomicAdd(arow + t, total);
            }
            return;
        }
        // ---- y rows (2 per block) ----
        int yb = bb - NAGG;
        int row = yb * 2 + (t >> 8);
        if (row < NA + NC) {
            int c = t & 255;
            const ushort* sH = A + (size_t)(NF + row) * D;
            const float* W = wr + (size_t)((row < NA) ? 1 : 3) * DD;
            float acc = 0.f;
            #pragma unroll 8
            for (int k = 0; k < D; ++k) acc += bf2f(sH[k]) * W[k * D + c];
            y[(size_t)row * D + c] = acc;
        }
        return;
    }
    // ---- gemm tile: row0 = (b>>1)*128, col0 = (b&1)*128 ----
    const int row0 = (b >> 1) * BM;
    const int col0 = (b & 1) * BM;
    const int w = t >> 6, lane = t & 63;    // 8 waves
    const int wm = w >> 2, wn = w & 3;      // 2x4 wave grid, 64x32 per wave
    const int lr = lane & 15;
    const int lk = lane >> 4;
    f32x4 acc[4][2] = {};

    const ushort* sp[3];
    int dofs[3];
    #pragma unroll
    for (int i = 0; i < 3; ++i) {
        int idx = w * 3 + i;
        int plane = idx >> 3, g = idx & 7;
        const ushort* base = (plane == 0) ? A : (plane == 1) ? WtH : WtL;
        int r = ((plane == 0) ? row0 : col0) + g * 16 + lr;
        if (plane == 0 && r >= nrows) r = nrows - 1;
        sp[i] = base + (size_t)r * D + lk * 8;
        dofs[i] = plane * PLANE + g * 512;
    }

    auto stage = [&](int kt, int buf) {
        ushort* bb2 = lds + buf * BUF;
        int k0 = kt * BK;
        #pragma unroll
        for (int i = 0; i < 3; ++i)
            gload_lds16(sp[i] + k0, bb2 + dofs[i]);
    };
    auto compute = [&](int buf) {
        const ushort* base = lds + buf * BUF;
        const ushort* As  = base;
        const ushort* WsH = base + PLANE;
        const ushort* WsL = base + 2 * PLANE;
        bf16x8 bh[2], bl[2];
        #pragma unroll
        for (int ni = 0; ni < 2; ++ni) {
            int off = (wn * 2 + ni) * 512 + lane * 8;
            bh[ni] = *(const bf16x8*)(&WsH[off]);
            bl[ni] = *(const bf16x8*)(&WsL[off]);
        }
        #pragma unroll
        for (int mi = 0; mi < 4; ++mi) {
            int off = (wm * 4 + mi) * 512 + lane * 8;
            bf16x8 ah = *(const bf16x8*)(&As[off]);
            #pragma unroll
            for (int ni = 0; ni < 2; ++ni) {
                acc[mi][ni] = __builtin_amdgcn_mfma_f32_16x16x32_bf16(ah, bh[ni], acc[mi][ni], 0, 0, 0);
                acc[mi][ni] = __builtin_amdgcn_mfma_f32_16x16x32_bf16(ah, bl[ni], acc[mi][ni], 0, 0, 0);
            }
        }
    };

    stage(0, 0);
    stage(1, 1);
#define PIPE_ITER(KT, PEND)                                        \
    asm volatile("s_waitcnt vmcnt(" #PEND ")" ::: "memory");       \
    __builtin_amdgcn_s_barrier();                                  \
    __builtin_amdgcn_sched_barrier(0);                             \
    compute((KT) & 1);                                             \
    __builtin_amdgcn_s_barrier();                                  \
    __builtin_amdgcn_sched_barrier(0);                             \
    if ((KT) + 2 < 8) stage((KT) + 2, (KT) & 1);
    PIPE_ITER(0, 3)
    PIPE_ITER(1, 3)
    PIPE_ITER(2, 3)
    PIPE_ITER(3, 3)
    PIPE_ITER(4, 3)
    PIPE_ITER(5, 3)
    PIPE_ITER(6, 3)
    PIPE_ITER(7, 0)
#undef PIPE_ITER

    __syncthreads();
    float* S = (float*)lds + (size_t)w * 16 * LDW;   // per-wave 16x36 fp32
    const int rrow = lane >> 2;            // 0..15 read-back row
    const int grp  = lane & 3;             // col octet (8 bf16)
    #pragma unroll
    for (int mi = 0; mi < 4; ++mi) {
        __syncthreads();
        #pragma unroll
        for (int ni = 0; ni < 2; ++ni)
            #pragma unroll
            for (int reg = 0; reg < 4; ++reg)
                S[(lk * 4 + reg) * LDW + ni * 16 + lr] = acc[mi][ni][reg];
        __syncthreads();
        int gr = row0 + wm * 64 + mi * 16 + rrow;
        int gc = col0 + wn * 32 + grp * 8;
        if (gr >= nrows) continue;
        float4 f0 = *(const float4*)(&S[rrow * LDW + grp * 8]);
        float4 f1 = *(const float4*)(&S[rrow * LDW + grp * 8 + 4]);
        float4 b0 = *(const float4*)(bias + gc);
        float4 b1 = *(const float4*)(bias + gc + 4);
        float v[8] = {f0.x + b0.x, f0.y + b0.y, f0.z + b0.z, f0.w + b0.w,
                      f1.x + b1.x, f1.y + b1.y, f1.z + b1.z, f1.w + b1.w};
        u16x8 hh;
        #pragma unroll
        for (int j = 0; j < 8; ++j) hh[j] = f2bf(v[j]);
        *(u16x8*)(G + (size_t)gr * D + gc) = hh;
    }
}

// ---- layer-0 flight rows: G = relu(G + inv1*Σy1 + inv3*Σy3) in place ------
__global__ __launch_bounds__(256) void msg_relu_kernel(
    ushort* __restrict__ G,
    const float* __restrict__ y,
    const int* __restrict__ rp1, const int* __restrict__ csr1, const float* __restrict__ inv1,
    const int* __restrict__ rp3, const int* __restrict__ csr3, const float* __restrict__ inv3)
{
    int wid = (blockIdx.x * 256 + threadIdx.x) >> 6;
    int lane = threadIdx.x & 63;
    int row = wid * 2 + (lane >> 5);
    if (row >= NF) return;
    int c = (lane & 31) * 8;
    size_t o = (size_t)row * D + c;
    u16x8 gh = *(const u16x8*)(G + o);
    float v[8];
    #pragma unroll
    for (int j = 0; j < 8; ++j) v[j] = bf2f(gh[j]);
    float m[8] = {};
    int e0 = rp1[row], e1 = rp1[row + 1];
    for (int e = e0; e < e1; ++e) {
        const float* yr = y + (size_t)csr1[e] * D + c;
        float4 u0 = *(const float4*)yr;
        float4 u1 = *(const float4*)(yr + 4);
        m[0] += u0.x; m[1] += u0.y; m[2] += u0.z; m[3] += u0.w;
        m[4] += u1.x; m[5] += u1.y; m[6] += u1.z; m[7] += u1.w;
    }
    float s1 = inv1[row];
    #pragma unroll
    for (int j = 0; j < 8; ++j) { v[j] += s1 * m[j]; m[j] = 0.f; }
    e0 = rp3[row]; e1 = rp3[row + 1];
    for (int e = e0; e < e1; ++e) {
        const float* yr = y + (size_t)(NA + csr3[e]) * D + c;
        float4 u0 = *(const float4*)yr;
        float4 u1 = *(const float4*)(yr + 4);
        m[0] += u0.x; m[1] += u0.y; m[2] += u0.z; m[3] += u0.w;
        m[4] += u1.x; m[5] += u1.y; m[6] += u1.z; m[7] += u1.w;
    }
    float s3 = inv3[row];
    u16x8 oh;
    #pragma unroll
    for (int j = 0; j < 8; ++j) oh[j] = f2bf(fmaxf(v[j] + s3 * m[j], 0.f));
    *(u16x8*)(G + o) = oh;
}

// ---- layer-1: out[f] = relu(G2+msgs) . W_out + b_out (fused readout) -------
__global__ __launch_bounds__(256) void msg_readout_kernel(
    const ushort* __restrict__ G,
    const float* __restrict__ y,
    const int* __restrict__ rp1, const int* __restrict__ csr1, const float* __restrict__ inv1,
    const int* __restrict__ rp3, const int* __restrict__ csr3, const float* __restrict__ inv3,
    const float* __restrict__ wout, const float* __restrict__ bout,
    float* __restrict__ out)
{
    int wid = (blockIdx.x * 256 + threadIdx.x) >> 6;
    int lane = threadIdx.x & 63;
    int row = wid * 2 + (lane >> 5);
    if (row >= NF) return;
    int c = (lane & 31) * 8;
    size_t o = (size_t)row * D + c;
    u16x8 gh = *(const u16x8*)(G + o);
    float v[8];
    #pragma unroll
    for (int j = 0; j < 8; ++j) v[j] = bf2f(gh[j]);
    float m[8] = {};
    int e0 = rp1[row], e1 = rp1[row + 1];
    for (int e = e0; e < e1; ++e) {
        const float* yr = y + (size_t)csr1[e] * D + c;
        float4 u0 = *(const float4*)yr;
        float4 u1 = *(const float4*)(yr + 4);
        m[0] += u0.x; m[1] += u0.y; m[2] += u0.z; m[3] += u0.w;
        m[4] += u1.x; m[5] += u1.y; m[6] += u1.z; m[7] += u1.w;
    }
    float s1 = inv1[row];
    #pragma unroll
    for (int j = 0; j < 8; ++j) { v[j] += s1 * m[j]; m[j] = 0.f; }
    e0 = rp3[row]; e1 = rp3[row + 1];
    for (int e = e0; e < e1; ++e) {
        const float* yr = y + (size_t)(NA + csr3[e]) * D + c;
        float4 u0 = *(const float4*)yr;
        float4 u1 = *(const float4*)(yr + 4);
        m[0] += u0.x; m[1] += u0.y; m[2] += u0.z; m[3] += u0.w;
        m[4] += u1.x; m[5] += u1.y; m[6] += u1.z; m[7] += u1.w;
    }
    float s3 = inv3[row];
    float4 w0 = *(const float4*)(wout + c);
    float4 w1 = *(const float4*)(wout + c + 4);
    float wv[8] = {w0.x, w0.y, w0.z, w0.w, w1.x, w1.y, w1.z, w1.w};
    float pr = 0.f;
    #pragma unroll
    for (int j = 0; j < 8; ++j) pr += fmaxf(v[j] + s3 * m[j], 0.f) * wv[j];
    pr += __shfl_xor(pr, 1);
    pr += __shfl_xor(pr, 2);
    pr += __shfl_xor(pr, 4);
    pr += __shfl_xor(pr, 8);
    pr += __shfl_xor(pr, 16);
    if ((lane & 31) == 0) out[row] = pr + bout[0];
}

// -- r0/r2 transform: G = relu(G + inv_deg*(agg @ Wr[rel])) in place ---------
__global__ __launch_bounds__(256) void smallT_kernel(
    const float* __restrict__ agg, const float* __restrict__ wr,
    const float* __restrict__ inv0, const float* __restrict__ inv2,
    ushort* __restrict__ G)
{
    int row = blockIdx.x;            // 0..429
    int c = threadIdx.x;
    const float* a = agg + (size_t)row * D;
    const float* W = wr + (size_t)((row < NA) ? 0 : 2) * DD;
    float scale = (row < NA) ? inv0[row] : inv2[row - NA];
    float acc = 0.f;
    #pragma unroll 8
    for (int k = 0; k < D; ++k) acc += a[k] * W[k * D + c];
    size_t o = (size_t)(NF + row) * D + c;
    G[o] = f2bf(fmaxf(bf2f(G[o]) + scale * acc, 0.f));
}

extern "C" void kernel_launch(void* const* d_in, const int* in_sizes, int n_in,
                              void* d_out, int out_size, void* d_ws, size_t ws_size,
                              hipStream_t stream)
{
    const float* xf = (const float*)d_in[0];
    const float* xa = (const float*)d_in[1];
    const float* xc = (const float*)d_in[2];
    const float* Wf = (const float*)d_in[3];
    const float* bf = (const float*)d_in[4];
    const float* Wa = (const float*)d_in[5];
    const float* ba = (const float*)d_in[6];
    const float* Wc = (const float*)d_in[7];
    const float* bc = (const float*)d_in[8];
    const float* basis0 = (const float*)d_in[9];
    const float* comp0  = (const float*)d_in[10];
    const float* root0  = (const float*)d_in[11];
    const float* bias0  = (const float*)d_in[12];
    const float* basis1 = (const float*)d_in[13];
    const float* comp1  = (const float*)d_in[14];
    const float* root1  = (const float*)d_in[15];
    const float* bias1  = (const float*)d_in[16];
    const float* Wout = (const float*)d_in[17];
    const float* bout = (const float*)d_in[18];
    const int* src0 = (const int*)d_in[19];
    const int* dst0 = (const int*)d_in[20];
    const int* src1 = (const int*)d_in[21];
    const int* dst1 = (const int*)d_in[22];
    const int* src2 = (const int*)d_in[23];
    const int* dst2 = (const int*)d_in[24];
    const int* src3 = (const int*)d_in[25];
    const int* dst3 = (const int*)d_in[26];
    float* out = (float*)d_out;

    char* ws = (char*)d_ws;
    size_t off = 0;
    auto alloc = [&](size_t bytes) -> char* {
        char* p = ws + off;
        off = (off + bytes + 255) & ~(size_t)255;
        return p;
    };
    ushort* hH  = (ushort*)alloc((size_t)NN * D * 2);
    ushort* gH  = (ushort*)alloc((size_t)NN * D * 2);
    // layer-1 GEMM output reuses hH (dead after layer-0 consumers)
    ushort* g2H = hH;
    ushort* WtH0 = (ushort*)alloc((size_t)DD * 2);
    ushort* WtL0 = (ushort*)alloc((size_t)DD * 2);
    ushort* WtH1 = (ushort*)alloc((size_t)DD * 2);
    ushort* WtL1 = (ushort*)alloc((size_t)DD * 2);
    ushort* WfTH = (ushort*)alloc((size_t)D * 32 * 2);
    ushort* WfTL = (ushort*)alloc((size_t)D * 32 * 2);
    float* wr0    = (float*)alloc((size_t)4 * DD * 4);
    float* wr1    = (float*)alloc((size_t)4 * DD * 4);
    float* ybuf   = (float*)alloc((size_t)(NA + NC) * D * 4);
    float* aggbuf = (float*)alloc((size_t)(NA + NC) * D * 4);
    int*   deg13  = (int*)  alloc((size_t)2 * NF * 4);
    int* deg1 = deg13; int* deg3 = deg13 + NF;
    float* inv1 = (float*)alloc((size_t)NF * 4);
    float* inv3 = (float*)alloc((size_t)NF * 4);
    float* inv0 = (float*)alloc((size_t)NA * 4);
    float* inv2 = (float*)alloc((size_t)NC * 4);
    int* rp0 = (int*)alloc((NA + 1) * 4);
    int* rp1 = (int*)alloc((size_t)(NF + 1) * 4);
    int* rp2 = (int*)alloc((NC + 1) * 4);
    int* rp3 = (int*)alloc((size_t)(NF + 1) * 4);
    int* cu1 = (int*)alloc((size_t)(NF + 1) * 4);
    int* cu3 = (int*)alloc((size_t)(NF + 1) * 4);
    int* csr0 = (int*)alloc((size_t)E * 4);
    int* csr1 = (int*)alloc((size_t)E * 4);
    int* csr2 = (int*)alloc((size_t)E * 4);
    int* csr3 = (int*)alloc((size_t)E * 4);
    int* bsum = (int*)alloc(256 * 4);
    int* bh0  = (int*)alloc((size_t)NSL * NA * 4);
    int* bh2  = (int*)alloc((size_t)NSL * NC * 4);
    (void)ws_size; (void)in_sizes; (void)n_in; (void)out_size;

    // deg13 must be zero before prep_kernel's deg_count blocks (stream order)
    hipMemsetAsync(deg13, 0, (size_t)2 * NF * 4, stream);

    // K1: hist02 + deg_count + wsplit(x2) + wr(x2)
    prep_kernel<<<K1_WR1_END, 256, 0, stream>>>(
        dst0, dst2, bh0, bh2, aggbuf, Wf, WfTH, WfTL,
        dst1, dst3, deg1, deg3,
        root0, WtH0, WtL0, root1, WtH1, WtL1,
        basis0, comp0, wr0, basis1, comp1, wr1);

    // K2: scanA + scan02
    scan_kernel<<<197, 1024, 0, stream>>>(
        deg1, deg3, bsum, bh0, bh2, rp0, rp2, inv0, inv2);

    // K3: fill02 + scanC
    fill_scan_kernel<<<2 * NSL + 196, 1024, 0, stream>>>(
        src0, dst0, src2, dst2, bh0, bh2, csr0, csr2,
        deg1, deg3, bsum, rp1, rp3, cu1, cu3, inv1, inv3);

    // K4: encoders + csr_fill13
    encode_fill_kernel<<<FBLK + TAILB + F13B, 512, 0, stream>>>(
        xf, WfTH, WfTL, bf, xa, Wa, ba, xc, Wc, bc, hH,
        src1, dst1, src3, dst3, cu1, cu3, csr1, csr3);

    // ---- layer 0: {gemm + agg + y} co-scheduled, then finishers
    constexpr int NG0 = ((NN + 127) / 128) * 2;
    layer_kernel<0><<<NG0 + AGGB + YB, 512, 0, stream>>>(
        hH, WtH0, WtL0, bias0, gH, wr0, ybuf,
        rp0, csr0, rp2, csr2, aggbuf);
    smallT_kernel<<<NA + NC, 256, 0, stream>>>(aggbuf, wr0, inv0, inv2, gH);
    msg_relu_kernel<<<(NF / 2 * 64 + 255) / 256, 256, 0, stream>>>(
        gH, ybuf, rp1, csr1, inv1, rp3, csr3, inv3);

    // ---- layer 1: {gemm + y} co-scheduled, then fused readout
    constexpr int NG1 = ((NF + 127) / 128) * 2;
    layer_kernel<1><<<NG1 + YB, 512, 0, stream>>>(
        gH, WtH1, WtL1, bias1, g2H, wr1, ybuf,
        nullptr, nullptr, nullptr, nullptr, nullptr);
    msg_readout_kernel<<<(NF / 2 * 64 + 255) / 256, 256, 0, stream>>>(
        g2H, ybuf, rp1, csr1, inv1, rp3, csr3, inv3, Wout, bout, out);
}

// Round 24
// 325.521 us; speedup vs baseline: 1.2885x; 1.0217x over previous
//
#include <hip/hip_runtime.h>
#include <hip/hip_bf16.h>
#include <cstdint>
#include <cstddef>

constexpr int NF = 100000;
constexpr int NA = 400;
constexpr int NC = 30;
constexpr int NN = NF + NA + NC;     // 100430
constexpr int D  = 256;
constexpr int DD = D * D;            // 65536
constexpr int E  = 250000;
constexpr int NSL = 128;             // slices for r0/r2 counting sort
constexpr int FBLK = (NF + 127) / 128;   // 782 flight-encoder blocks
constexpr int TAILB = (NA + NC + 7) / 8; // 54 scalar-tail blocks
constexpr int F13B = (2 * E + 511) / 512; // 977 csr_fill13 blocks (512 thr)
constexpr int AGGB = NA * 4 + NC * 64;    // 3520 agg chunks
constexpr int YB   = (NA + NC) / 2;       // 215 y blocks (2 rows each)

// K1 block ranges
constexpr int K1_HIST_END = 2 * NSL;                       // 256
constexpr int K1_DEG_END  = K1_HIST_END + (2 * E + 255) / 256;  // 2210
constexpr int K1_WS0_END  = K1_DEG_END + 256;              // 2466
constexpr int K1_WS1_END  = K1_WS0_END + 256;              // 2722
constexpr int K1_WR0_END  = K1_WS1_END + 1024;             // 3746
constexpr int K1_WR1_END  = K1_WR0_END + 1024;             // 4770

// work_kernel block ranges: encoder | tail | fill13 | fill02
constexpr int W_ENC_END  = FBLK;                 // 782
constexpr int W_TAIL_END = W_ENC_END + TAILB;    // 836
constexpr int W_F13_END  = W_TAIL_END + F13B;    // 1813
constexpr int W_TOTAL    = W_F13_END + 2 * NSL;  // 2069

typedef __attribute__((ext_vector_type(8))) short bf16x8;
typedef __attribute__((ext_vector_type(4))) float f32x4;
typedef __attribute__((ext_vector_type(8))) ushort u16x8;

__device__ inline ushort f2bf(float f) {
    __hip_bfloat16 h = __float2bfloat16(f);
    return __builtin_bit_cast(ushort, h);
}
__device__ inline float bf2f(ushort u) {
    __hip_bfloat16 h = __builtin_bit_cast(__hip_bfloat16, u);
    return __bfloat162float(h);
}

// async global->LDS, 16B per lane: LDS dest = base + lane*16 (wave-linear)
__device__ inline void gload_lds16(const ushort* g, ushort* l) {
    __builtin_amdgcn_global_load_lds(
        (const __attribute__((address_space(1))) void*)g,
        (__attribute__((address_space(3))) void*)l, 16, 0, 0);
}

// ==== K1: hist02 + deg_count + wsplit(x2) + wr(x2), co-scheduled ============
__global__ __launch_bounds__(256) void prep_kernel(
    const int* __restrict__ dst0, const int* __restrict__ dst2,
    int* __restrict__ bh0, int* __restrict__ bh2,
    float* __restrict__ aggz,
    const float* __restrict__ Wf, ushort* __restrict__ WfTH, ushort* __restrict__ WfTL,
    const int* __restrict__ dst1, const int* __restrict__ dst3,
    int* __restrict__ deg1, int* __restrict__ deg3,
    const float* __restrict__ root0, ushort* __restrict__ WtH0, ushort* __restrict__ WtL0,
    const float* __restrict__ root1, ushort* __restrict__ WtH1, ushort* __restrict__ WtL1,
    const float* __restrict__ basis0, const float* __restrict__ comp0, float* __restrict__ wr0,
    const float* __restrict__ basis1, const float* __restrict__ comp1, float* __restrict__ wr1)
{
    __shared__ int hist[NA];
    const int b = blockIdx.x;
    const int t = threadIdx.x;
    if (b < K1_HIST_END) {
        for (int i = b * 256 + t; i < (NA + NC) * D; i += K1_HIST_END * 256)
            aggz[i] = 0.f;
        if (b < 32) {
            float wv = Wf[(size_t)b * D + t];
            ushort hi = f2bf(wv);
            WfTH[(size_t)t * 32 + b] = hi;
            WfTL[(size_t)t * 32 + b] = f2bf(wv - bf2f(hi));
        }
        bool isR2 = (b >= NSL);
        int sl = isR2 ? b - NSL : b;
        const int* dst = isR2 ? dst2 : dst0;
        int nb = isR2 ? NC : NA;
        for (int i = t; i < nb; i += 256) hist[i] = 0;
        __syncthreads();
        int lo = (int)((long long)E * sl / NSL);
        int hi = (int)((long long)E * (sl + 1) / NSL);
        for (int e = lo + t; e < hi; e += 256)
            atomicAdd(&hist[dst[e]], 1);
        __syncthreads();
        int* bh = isR2 ? (bh2 + sl * NC) : (bh0 + sl * NA);
        for (int i = t; i < nb; i += 256) bh[i] = hist[i];
    } else if (b < K1_DEG_END) {
        int idx = (b - K1_HIST_END) * 256 + t;
        if (idx < 2 * E) {
            if (idx < E) atomicAdd(&deg1[dst1[idx]], 1);
            else         atomicAdd(&deg3[dst3[idx - E]], 1);
        }
    } else if (b < K1_WS0_END) {
        int n = b - K1_DEG_END;
        float w = root0[(size_t)t * D + n];
        ushort hi = f2bf(w);
        WtH0[(size_t)n * D + t] = hi;
        WtL0[(size_t)n * D + t] = f2bf(w - bf2f(hi));
    } else if (b < K1_WS1_END) {
        int n = b - K1_WS0_END;
        float w = root1[(size_t)t * D + n];
        ushort hi = f2bf(w);
        WtH1[(size_t)n * D + t] = hi;
        WtL1[(size_t)n * D + t] = f2bf(w - bf2f(hi));
    } else if (b < K1_WR0_END) {
        int idx = (b - K1_WS1_END) * 256 + t;
        int r = idx >> 16;
        int io = idx & (DD - 1);
        wr0[idx] = comp0[r * 3 + 0] * basis0[io]
                 + comp0[r * 3 + 1] * basis0[DD + io]
                 + comp0[r * 3 + 2] * basis0[2 * DD + io];
    } else {
        int idx = (b - K1_WR0_END) * 256 + t;
        int r = idx >> 16;
        int io = idx & (DD - 1);
        wr1[idx] = comp1[r * 3 + 0] * basis1[io]
                 + comp1[r * 3 + 1] * basis1[DD + io]
                 + comp1[r * 3 + 2] * basis1[2 * DD + io];
    }
}

// ==== K2: scanA (blocks 0..195) + scan02 (block 196), co-scheduled ==========
__global__ __launch_bounds__(1024) void scan_kernel(
    const int* __restrict__ deg1, const int* __restrict__ deg3,
    int* __restrict__ bsum,
    int* __restrict__ bh0, int* __restrict__ bh2,
    int* __restrict__ rp0, int* __restrict__ rp2,
    float* __restrict__ inv0, float* __restrict__ inv2)
{
    __shared__ int s[1024];
    __shared__ int tot[512];
    __shared__ int exc[512];
    const int b = blockIdx.x;
    const int t = threadIdx.x;
    if (b < 196) {
        bool isR3 = (b >= 98);
        const int* deg = isR3 ? deg3 : deg1;
        int chunk = isR3 ? b - 98 : b;
        int i = chunk * 1024 + t;
        int v = (i < NF) ? deg[i] : 0;
        s[t] = v;
        __syncthreads();
        for (int ofs = 512; ofs > 0; ofs >>= 1) {
            if (t < ofs) s[t] += s[t + ofs];
            __syncthreads();
        }
        if (t == 0) bsum[(isR3 ? 128 : 0) + chunk] = s[0];
        return;
    }
    int cnt = 0;
    if (t < NA) {
        int ss = 0;
        for (int sl = 0; sl < NSL; ++sl) {
            int v = bh0[sl * NA + t]; bh0[sl * NA + t] = ss; ss += v;
        }
        cnt = ss;
    } else if (t < NA + NC) {
        int bin = t - NA; int ss = 0;
        for (int sl = 0; sl < NSL; ++sl) {
            int v = bh2[sl * NC + bin]; bh2[sl * NC + bin] = ss; ss += v;
        }
        cnt = ss;
    }
    if (t < 512) tot[t] = cnt;
    __syncthreads();
    for (int ofs = 1; ofs < 512; ofs <<= 1) {
        int v = 0;
        if (t < 512 && t >= ofs) v = tot[t - ofs];
        __syncthreads();
        if (t < 512) tot[t] += v;
        __syncthreads();
    }
    if (t < 512) {
        int ex = tot[t] - cnt;
        if (t < NA) {
            exc[t] = ex;
            rp0[t] = ex;
            inv0[t] = 1.0f / (float)(cnt > 1 ? cnt : 1);
            if (t == 0) { rp0[NA] = E; rp2[NC] = E; }
        } else if (t < NA + NC) {
            exc[t] = ex - E;
            rp2[t - NA] = ex - E;
            inv2[t - NA] = 1.0f / (float)(cnt > 1 ? cnt : 1);
        } else exc[t] = 0;
    }
    __syncthreads();
    for (int idx = t; idx < NSL * NA; idx += 1024) {
        int sl = idx / NA; int bin = idx - sl * NA;
        bh0[idx] += exc[bin];
    }
    for (int idx = t; idx < NSL * NC; idx += 1024) {
        int sl = idx / NC; int bin = idx - sl * NC;
        bh2[idx] += exc[NA + bin];
    }
}

// ==== scanC (with inlined scanB), standalone -------------------------------
__global__ __launch_bounds__(1024) void scanC_kernel(
    const int* __restrict__ deg1, const int* __restrict__ deg3,
    const int* __restrict__ bsum,
    int* __restrict__ rp1, int* __restrict__ rp3,
    int* __restrict__ cu1, int* __restrict__ cu3,
    float* __restrict__ inv1, float* __restrict__ inv3)
{
    __shared__ int s[1024];
    __shared__ int s2[256];
    int t = threadIdx.x;
    int b = blockIdx.x;                    // 0..195
    int vb = 0;
    if (t < 256) {
        vb = ((t & 127) < 98) ? bsum[t] : 0;
        s2[t] = vb;
    }
    __syncthreads();
    for (int ofs = 1; ofs < 128; ofs <<= 1) {
        int a = 0;
        if (t < 256 && (t & 127) >= ofs) a = s2[t - ofs];
        __syncthreads();
        if (t < 256) s2[t] += a;
        __syncthreads();
    }
    if (t < 256) s2[t] -= vb;          // exclusive
    __syncthreads();
    const int* deg; int* rp; int* cu; float* inv; int chunk; int prefix;
    if (b < 98) { deg = deg1; rp = rp1; cu = cu1; inv = inv1; chunk = b;      prefix = s2[chunk]; }
    else        { deg = deg3; rp = rp3; cu = cu3; inv = inv3; chunk = b - 98; prefix = s2[128 + chunk]; }
    int i = chunk * 1024 + t;
    int v = (i < NF) ? deg[i] : 0;
    s[t] = v;
    __syncthreads();
    for (int ofs = 1; ofs < 1024; ofs <<= 1) {
        int a = (t >= ofs) ? s[t - ofs] : 0;
        __syncthreads();
        s[t] += a;
        __syncthreads();
    }
    int ex = prefix + s[t] - v;
    if (i < NF) {
        rp[i] = ex;
        cu[i] = ex;
        inv[i] = 1.0f / (float)(v > 1 ? v : 1);
    }
    if (i == 0) rp[NF] = E;
}

// ==== work_kernel: encoder + tail + csr_fill13 + fill02, co-scheduled =======
__global__ __launch_bounds__(512) void work_kernel(
    const float* __restrict__ xf,
    const ushort* __restrict__ WtH8, const ushort* __restrict__ WtL8,
    const float* __restrict__ bfl,
    const float* __restrict__ xa, const float* __restrict__ Wa, const float* __restrict__ ba,
    const float* __restrict__ xc, const float* __restrict__ Wc, const float* __restrict__ bc,
    ushort* __restrict__ hH,
    const int* __restrict__ src1, const int* __restrict__ dst1,
    const int* __restrict__ src3, const int* __restrict__ dst3,
    int* __restrict__ cu1, int* __restrict__ cu3,
    int* __restrict__ csr1, int* __restrict__ csr3,
    const int* __restrict__ src0, const int* __restrict__ dst0,
    const int* __restrict__ src2, const int* __restrict__ dst2,
    const int* __restrict__ bh0, const int* __restrict__ bh2,
    int* __restrict__ csr0, int* __restrict__ csr2)
{
    __shared__ __align__(16) ushort lds[20480];            // 40960 B
    const int t = threadIdx.x;
    const int b = blockIdx.x;
    if (b >= W_F13_END) {
        // ---- fill02 (512 threads, LDS cursor)
        int bb = b - W_F13_END;
        int* cur = (int*)lds;
        bool isR2 = (bb >= NSL);
        int sl = isR2 ? bb - NSL : bb;
        const int* src = isR2 ? src2 : src0;
        const int* dst = isR2 ? dst2 : dst0;
        const int* bh  = isR2 ? (bh2 + sl * NC) : (bh0 + sl * NA);
        int* csr       = isR2 ? csr2 : csr0;
        int nb = isR2 ? NC : NA;
        for (int i = t; i < nb; i += 512) cur[i] = bh[i];
        __syncthreads();
        int lo = (int)((long long)E * sl / NSL);
        int hi = (int)((long long)E * (sl + 1) / NSL);
        for (int e = lo + t; e < hi; e += 512) {
            int pos = atomicAdd(&cur[dst[e]], 1);
            csr[pos] = src[e];
        }
        return;
    }
    if (b >= W_TAIL_END) {
        // ---- csr_fill13
        int idx = (b - W_TAIL_END) * 512 + t;
        if (idx < 2 * E) {
            if (idx < E) {
                int pos = atomicAdd(&cu1[dst1[idx]], 1);
                csr1[pos] = src1[idx];
            } else {
                int e = idx - E;
                int pos = atomicAdd(&cu3[dst3[e]], 1);
                csr3[pos] = src3[e];
            }
        }
        return;
    }
    if (b >= W_ENC_END) {
        // ---- airports + carriers scalar path
        int c = t & 255;
        int i0 = t >> 8;
        int base = (b - W_ENC_END) * 8;
        for (int i = i0; i < 8; i += 2) {
            int row = base + i;
            if (row >= NA + NC) break;
            float acc;
            if (row < NA) {
                const float* xr = xa + (size_t)row * 16;
                acc = ba[c];
                #pragma unroll
                for (int k = 0; k < 16; ++k) acc += xr[k] * Wa[k * D + c];
            } else {
                const float* xr = xc + (size_t)(row - NA) * 8;
                acc = bc[c];
                #pragma unroll
                for (int k = 0; k < 8; ++k) acc += xr[k] * Wc[k * D + c];
            }
            hH[(size_t)(NF + row) * D + c] = f2bf(fmaxf(acc, 0.f));
        }
        return;
    }
    // ---- flight MFMA encoder
    constexpr int AOFF = 0, WHOFF = 4096, WLOFF = 12288;   // ushort offsets
    const int row0 = b * 128;
    const int w = t >> 6, lane = t & 63;     // 8 waves
    const int wm = w >> 2, wn = w & 3;       // 2x4 grid, 64 rows x 64 cols/wave
    const int lr = lane & 15;
    const int lk = lane >> 4;
    {
        int r = t >> 2;                      // 0..127
        int seg = (t & 3) * 8;               // 0,8,16,24
        int gr = row0 + r; if (gr >= NF) gr = NF - 1;
        const float* xr = xf + (size_t)gr * 32 + seg;
        float4 a0 = *(const float4*)xr;
        float4 a1 = *(const float4*)(xr + 4);
        u16x8 bb;
        bb[0] = f2bf(a0.x); bb[1] = f2bf(a0.y); bb[2] = f2bf(a0.z); bb[3] = f2bf(a0.w);
        bb[4] = f2bf(a1.x); bb[5] = f2bf(a1.y); bb[6] = f2bf(a1.z); bb[7] = f2bf(a1.w);
        int g = r >> 4, rr = r & 15, kg = seg >> 3;
        *(u16x8*)(lds + AOFF + g * 512 + (rr + 16 * kg) * 8) = bb;
    }
    #pragma unroll
    for (int i = 0; i < 4; ++i) {
        int u = w * 4 + i;                   // 0..31
        int plane = u >> 4, g = u & 15;
        const ushort* src = (plane ? WtL8 : WtH8) + ((size_t)(g * 16 + lr)) * 32 + lk * 8;
        ushort* dst = lds + (plane ? WLOFF : WHOFF) + g * 512;
        gload_lds16(src, dst);
    }
    __syncthreads();
    f32x4 acc[4][4] = {};
    bf16x8 bhv[4], blv[4];
    #pragma unroll
    for (int ni = 0; ni < 4; ++ni) {
        int off = (wn * 4 + ni) * 512 + lane * 8;
        bhv[ni] = *(const bf16x8*)(lds + WHOFF + off);
        blv[ni] = *(const bf16x8*)(lds + WLOFF + off);
    }
    #pragma unroll
    for (int mi = 0; mi < 4; ++mi) {
        bf16x8 ah = *(const bf16x8*)(lds + AOFF + (wm * 4 + mi) * 512 + lane * 8);
        #pragma unroll
        for (int ni = 0; ni < 4; ++ni) {
            acc[mi][ni] = __builtin_amdgcn_mfma_f32_16x16x32_bf16(ah, bhv[ni], acc[mi][ni], 0, 0, 0);
            acc[mi][ni] = __builtin_amdgcn_mfma_f32_16x16x32_bf16(ah, blv[ni], acc[mi][ni], 0, 0, 0);
        }
    }
    constexpr int ELDW = 68;
    float* S = (float*)lds + (size_t)w * 16 * ELDW;
    const int rrow = lane >> 3;
    const int grp  = lane & 7;
    #pragma unroll
    for (int mi = 0; mi < 4; ++mi) {
        __syncthreads();
        #pragma unroll
        for (int ni = 0; ni < 4; ++ni)
            #pragma unroll
            for (int reg = 0; reg < 4; ++reg)
                S[(lk * 4 + reg) * ELDW + ni * 16 + lr] = acc[mi][ni][reg];
        __syncthreads();
        #pragma unroll
        for (int it = 0; it < 2; ++it) {
            int row_i = rrow + it * 8;
            int gr = row0 + wm * 64 + mi * 16 + row_i;
            int gc = wn * 64 + grp * 8;
            if (gr >= NF) continue;
            float4 f0 = *(const float4*)(&S[row_i * ELDW + grp * 8]);
            float4 f1 = *(const float4*)(&S[row_i * ELDW + grp * 8 + 4]);
            float4 b0 = *(const float4*)(bfl + gc);
            float4 b1 = *(const float4*)(bfl + gc + 4);
            u16x8 hh;
            hh[0] = f2bf(fmaxf(f0.x + b0.x, 0.f));
            hh[1] = f2bf(fmaxf(f0.y + b0.y, 0.f));
            hh[2] = f2bf(fmaxf(f0.z + b0.z, 0.f));
            hh[3] = f2bf(fmaxf(f0.w + b0.w, 0.f));
            hh[4] = f2bf(fmaxf(f1.x + b1.x, 0.f));
            hh[5] = f2bf(fmaxf(f1.y + b1.y, 0.f));
            hh[6] = f2bf(fmaxf(f1.z + b1.z, 0.f));
            hh[7] = f2bf(fmaxf(f1.w + b1.w, 0.f));
            *(u16x8*)(hH + (size_t)gr * D + gc) = hh;
        }
    }
}

// ==== layer kernel: gemm tiles + (MODE 0: agg chunks) + y rows, co-sched ====
template<int MODE>
__global__ __launch_bounds__(512) void layer_kernel(
    const ushort* __restrict__ A,
    const ushort* __restrict__ WtH, const ushort* __restrict__ WtL,
    const float* __restrict__ bias, ushort* __restrict__ G,
    const float* __restrict__ wr, float* __restrict__ y,
    const int* __restrict__ rp0, const int* __restrict__ csr0,
    const int* __restrict__ rp2, const int* __restrict__ csr2,
    float* __restrict__ agg)
{
    constexpr int BM = 128, BK = 32;
    constexpr int PLANE = BM * BK;          // 4096 ushorts = 8 KB
    constexpr int BUF = 3 * PLANE;          // 12288 ushorts = 24 KB
    constexpr int LDW = 36;                 // fp32 epilogue scratch stride
    constexpr int nrows = (MODE == 0) ? NN : NF;
    constexpr int NG = ((nrows + 127) / 128) * 2;
    constexpr int NAGG = (MODE == 0) ? AGGB : 0;
    __shared__ __align__(16) ushort lds[2 * BUF];   // 49152 B
    const int t = threadIdx.x;
    const int b = blockIdx.x;
    if (b >= NG) {
        int bb = b - NG;
        if (MODE == 0 && bb < NAGG) {
            float* red = (float*)lds;        // 8 x 256 floats
            const int* rp; const int* csr; int dstn, chunk, nch; float* arow;
            if (bb < NA * 4) { dstn = bb >> 2; chunk = bb & 3; nch = 4;  rp = rp0; csr = csr0; arow = agg + (size_t)dstn * D; }
            else { int b2 = bb - NA * 4; dstn = b2 >> 6; chunk = b2 & 63; nch = 64; rp = rp2; csr = csr2; arow = agg + (size_t)(NA + dstn) * D; }
            int s = rp[dstn], e = rp[dstn + 1];
            int cnt = e - s;
            int lo = s + (int)((long long)cnt * chunk / nch);
            int hi = s + (int)((long long)cnt * (chunk + 1) / nch);
            int w8 = t >> 6, lane = t & 63;
            int span = hi - lo;
            int wlo = lo + (int)((long long)span * w8 / 8);
            int whi = lo + (int)((long long)span * (w8 + 1) / 8);
            int half = lane >> 5;
            int ch8 = (lane & 31) * 8;
            float acc[8] = {};
            int p = wlo;
            for (; p + 1 < whi; p += 2) {
                int r = csr[p + half];
                u16x8 v = *(const u16x8*)(A + (size_t)r * D + ch8);
                #pragma unroll
                for (int j = 0; j < 8; ++j) acc[j] += bf2f(v[j]);
            }
            if (p < whi && half == 0) {
                int r = csr[p];
                u16x8 v = *(const u16x8*)(A + (size_t)r * D + ch8);
                #pragma unroll
                for (int j = 0; j < 8; ++j) acc[j] += bf2f(v[j]);
            }
            #pragma unroll
            for (int j = 0; j < 8; ++j) acc[j] += __shfl_xor(acc[j], 32);
            if (lane < 32) {
                #pragma unroll
                for (int j = 0; j < 8; ++j) red[w8 * 256 + ch8 + j] = acc[j];
            }
            __syncthreads();
            if (t < 256) {
                float total = 0.f;
                #pragma unroll
                for (int j = 0; j < 8; ++j) total += red[j * 256 + t];
                atomicAdd(arow + t, total);
            }
            return;
        }
        int yb = bb - NAGG;
        int row = yb * 2 + (t >> 8);
        if (row < NA + NC) {
            int c = t & 255;
            const ushort* sH = A + (size_t)(NF + row) * D;
            const float* W = wr + (size_t)((row < NA) ? 1 : 3) * DD;
            float acc = 0.f;
            #pragma unroll 8
            for (int k = 0; k < D; ++k) acc += bf2f(sH[k]) * W[k * D + c];
            y[(size_t)row * D + c] = acc;
        }
        return;
    }
    const int row0 = (b >> 1) * BM;
    const int col0 = (b & 1) * BM;
    const int w = t >> 6, lane = t & 63;    // 8 waves
    const int wm = w >> 2, wn = w & 3;      // 2x4 wave grid, 64x32 per wave
    const int lr = lane & 15;
    const int lk = lane >> 4;
    f32x4 acc[4][2] = {};

    const ushort* sp[3];
    int dofs[3];
    #pragma unroll
    for (int i = 0; i < 3; ++i) {
        int idx = w * 3 + i;
        int plane = idx >> 3, g = idx & 7;
        const ushort* base = (plane == 0) ? A : (plane == 1) ? WtH : WtL;
        int r = ((plane == 0) ? row0 : col0) + g * 16 + lr;
        if (plane == 0 && r >= nrows) r = nrows - 1;
        sp[i] = base + (size_t)r * D + lk * 8;
        dofs[i] = plane * PLANE + g * 512;
    }

    auto stage = [&](int kt, int buf) {
        ushort* bb2 = lds + buf * BUF;
        int k0 = kt * BK;
        #pragma unroll
        for (int i = 0; i < 3; ++i)
            gload_lds16(sp[i] + k0, bb2 + dofs[i]);
    };
    auto compute = [&](int buf) {
        const ushort* base = lds + buf * BUF;
        const ushort* As  = base;
        const ushort* WsH = base + PLANE;
        const ushort* WsL = base + 2 * PLANE;
        bf16x8 bh[2], bl[2];
        #pragma unroll
        for (int ni = 0; ni < 2; ++ni) {
            int off = (wn * 2 + ni) * 512 + lane * 8;
            bh[ni] = *(const bf16x8*)(&WsH[off]);
            bl[ni] = *(const bf16x8*)(&WsL[off]);
        }
        #pragma unroll
        for (int mi = 0; mi < 4; ++mi) {
            int off = (wm * 4 + mi) * 512 + lane * 8;
            bf16x8 ah = *(const bf16x8*)(&As[off]);
            #pragma unroll
            for (int ni = 0; ni < 2; ++ni) {
                acc[mi][ni] = __builtin_amdgcn_mfma_f32_16x16x32_bf16(ah, bh[ni], acc[mi][ni], 0, 0, 0);
                acc[mi][ni] = __builtin_amdgcn_mfma_f32_16x16x32_bf16(ah, bl[ni], acc[mi][ni], 0, 0, 0);
            }
        }
    };

    stage(0, 0);
    stage(1, 1);
#define PIPE_ITER(KT, PEND)                                        \
    asm volatile("s_waitcnt vmcnt(" #PEND ")" ::: "memory");       \
    __builtin_amdgcn_s_barrier();                                  \
    __builtin_amdgcn_sched_barrier(0);                             \
    compute((KT) & 1);                                             \
    __builtin_amdgcn_s_barrier();                                  \
    __builtin_amdgcn_sched_barrier(0);                             \
    if ((KT) + 2 < 8) stage((KT) + 2, (KT) & 1);
    PIPE_ITER(0, 3)
    PIPE_ITER(1, 3)
    PIPE_ITER(2, 3)
    PIPE_ITER(3, 3)
    PIPE_ITER(4, 3)
    PIPE_ITER(5, 3)
    PIPE_ITER(6, 3)
    PIPE_ITER(7, 0)
#undef PIPE_ITER

    __syncthreads();
    float* S = (float*)lds + (size_t)w * 16 * LDW;   // per-wave 16x36 fp32
    const int rrow = lane >> 2;            // 0..15 read-back row
    const int grp  = lane & 3;             // col octet (8 bf16)
    #pragma unroll
    for (int mi = 0; mi < 4; ++mi) {
        __syncthreads();
        #pragma unroll
        for (int ni = 0; ni < 2; ++ni)
            #pragma unroll
            for (int reg = 0; reg < 4; ++reg)
                S[(lk * 4 + reg) * LDW + ni * 16 + lr] = acc[mi][ni][reg];
        __syncthreads();
        int gr = row0 + wm * 64 + mi * 16 + rrow;
        int gc = col0 + wn * 32 + grp * 8;
        if (gr >= nrows) continue;
        float4 f0 = *(const float4*)(&S[rrow * LDW + grp * 8]);
        float4 f1 = *(const float4*)(&S[rrow * LDW + grp * 8 + 4]);
        float4 b0 = *(const float4*)(bias + gc);
        float4 b1 = *(const float4*)(bias + gc + 4);
        float v[8] = {f0.x + b0.x, f0.y + b0.y, f0.z + b0.z, f0.w + b0.w,
                      f1.x + b1.x, f1.y + b1.y, f1.z + b1.z, f1.w + b1.w};
        u16x8 hh;
        #pragma unroll
        for (int j = 0; j < 8; ++j) hh[j] = f2bf(v[j]);
        *(u16x8*)(G + (size_t)gr * D + gc) = hh;
    }
}

// ==== finish0: smallT (blocks 0..429) + msg_relu, co-scheduled ==============
__global__ __launch_bounds__(256) void finish0_kernel(
    const float* __restrict__ agg, const float* __restrict__ wr,
    const float* __restrict__ inv0, const float* __restrict__ inv2,
    ushort* __restrict__ G,
    const float* __restrict__ y,
    const int* __restrict__ rp1, const int* __restrict__ csr1, const float* __restrict__ inv1,
    const int* __restrict__ rp3, const int* __restrict__ csr3, const float* __restrict__ inv3)
{
    const int b = blockIdx.x;
    const int t = threadIdx.x;
    if (b < NA + NC) {
        // ---- smallT: G = relu(G + inv_deg*(agg @ Wr[rel])) in place
        int row = b;
        int c = t;
        const float* a = agg + (size_t)row * D;
        const float* W = wr + (size_t)((row < NA) ? 0 : 2) * DD;
        float scale = (row < NA) ? inv0[row] : inv2[row - NA];
        float acc = 0.f;
        #pragma unroll 8
        for (int k = 0; k < D; ++k) acc += a[k] * W[k * D + c];
        size_t o = (size_t)(NF + row) * D + c;
        G[o] = f2bf(fmaxf(bf2f(G[o]) + scale * acc, 0.f));
        return;
    }
    // ---- msg_relu: 2 rows per wave
    int wid = ((b - (NA + NC)) * 256 + t) >> 6;
    int lane = t & 63;
    int row = wid * 2 + (lane >> 5);
    if (row >= NF) return;
    int c = (lane & 31) * 8;
    size_t o = (size_t)row * D + c;
    u16x8 gh = *(const u16x8*)(G + o);
    float v[8];
    #pragma unroll
    for (int j = 0; j < 8; ++j) v[j] = bf2f(gh[j]);
    float m[8] = {};
    int e0 = rp1[row], e1 = rp1[row + 1];
    for (int e = e0; e < e1; ++e) {
        const float* yr = y + (size_t)csr1[e] * D + c;
        float4 u0 = *(const float4*)yr;
        float4 u1 = *(const float4*)(yr + 4);
        m[0] += u0.x; m[1] += u0.y; m[2] += u0.z; m[3] += u0.w;
        m[4] += u1.x; m[5] += u1.y; m[6] += u1.z; m[7] += u1.w;
    }
    float s1 = inv1[row];
    #pragma unroll
    for (int j = 0; j < 8; ++j) { v[j] += s1 * m[j]; m[j] = 0.f; }
    e0 = rp3[row]; e1 = rp3[row + 1];
    for (int e = e0; e < e1; ++e) {
        const float* yr = y + (size_t)(NA + csr3[e]) * D + c;
        float4 u0 = *(const float4*)yr;
        float4 u1 = *(const float4*)(yr + 4);
        m[0] += u0.x; m[1] += u0.y; m[2] += u0.z; m[3] += u0.w;
        m[4] += u1.x; m[5] += u1.y; m[6] += u1.z; m[7] += u1.w;
    }
    float s3 = inv3[row];
    u16x8 oh;
    #pragma unroll
    for (int j = 0; j < 8; ++j) oh[j] = f2bf(fmaxf(v[j] + s3 * m[j], 0.f));
    *(u16x8*)(G + o) = oh;
}

// ---- layer-1: out[f] = relu(G2+msgs) . W_out + b_out (fused readout) -------
__global__ __launch_bounds__(256) void msg_readout_kernel(
    const ushort* __restrict__ G,
    const float* __restrict__ y,
    const int* __restrict__ rp1, const int* __restrict__ csr1, const float* __restrict__ inv1,
    const int* __restrict__ rp3, const int* __restrict__ csr3, const float* __restrict__ inv3,
    const float* __restrict__ wout, const float* __restrict__ bout,
    float* __restrict__ out)
{
    int wid = (blockIdx.x * 256 + threadIdx.x) >> 6;
    int lane = threadIdx.x & 63;
    int row = wid * 2 + (lane >> 5);
    if (row >= NF) return;
    int c = (lane & 31) * 8;
    size_t o = (size_t)row * D + c;
    u16x8 gh = *(const u16x8*)(G + o);
    float v[8];
    #pragma unroll
    for (int j = 0; j < 8; ++j) v[j] = bf2f(gh[j]);
    float m[8] = {};
    int e0 = rp1[row], e1 = rp1[row + 1];
    for (int e = e0; e < e1; ++e) {
        const float* yr = y + (size_t)csr1[e] * D + c;
        float4 u0 = *(const float4*)yr;
        float4 u1 = *(const float4*)(yr + 4);
        m[0] += u0.x; m[1] += u0.y; m[2] += u0.z; m[3] += u0.w;
        m[4] += u1.x; m[5] += u1.y; m[6] += u1.z; m[7] += u1.w;
    }
    float s1 = inv1[row];
    #pragma unroll
    for (int j = 0; j < 8; ++j) { v[j] += s1 * m[j]; m[j] = 0.f; }
    e0 = rp3[row]; e1 = rp3[row + 1];
    for (int e = e0; e < e1; ++e) {
        const float* yr = y + (size_t)(NA + csr3[e]) * D + c;
        float4 u0 = *(const float4*)yr;
        float4 u1 = *(const float4*)(yr + 4);
        m[0] += u0.x; m[1] += u0.y; m[2] += u0.z; m[3] += u0.w;
        m[4] += u1.x; m[5] += u1.y; m[6] += u1.z; m[7] += u1.w;
    }
    float s3 = inv3[row];
    float4 w0 = *(const float4*)(wout + c);
    float4 w1 = *(const float4*)(wout + c + 4);
    float wv[8] = {w0.x, w0.y, w0.z, w0.w, w1.x, w1.y, w1.z, w1.w};
    float pr = 0.f;
    #pragma unroll
    for (int j = 0; j < 8; ++j) pr += fmaxf(v[j] + s3 * m[j], 0.f) * wv[j];
    pr += __shfl_xor(pr, 1);
    pr += __shfl_xor(pr, 2);
    pr += __shfl_xor(pr, 4);
    pr += __shfl_xor(pr, 8);
    pr += __shfl_xor(pr, 16);
    if ((lane & 31) == 0) out[row] = pr + bout[0];
}

extern "C" void kernel_launch(void* const* d_in, const int* in_sizes, int n_in,
                              void* d_out, int out_size, void* d_ws, size_t ws_size,
                              hipStream_t stream)
{
    const float* xf = (const float*)d_in[0];
    const float* xa = (const float*)d_in[1];
    const float* xc = (const float*)d_in[2];
    const float* Wf = (const float*)d_in[3];
    const float* bf = (const float*)d_in[4];
    const float* Wa = (const float*)d_in[5];
    const float* ba = (const float*)d_in[6];
    const float* Wc = (const float*)d_in[7];
    const float* bc = (const float*)d_in[8];
    const float* basis0 = (const float*)d_in[9];
    const float* comp0  = (const float*)d_in[10];
    const float* root0  = (const float*)d_in[11];
    const float* bias0  = (const float*)d_in[12];
    const float* basis1 = (const float*)d_in[13];
    const float* comp1  = (const float*)d_in[14];
    const float* root1  = (const float*)d_in[15];
    const float* bias1  = (const float*)d_in[16];
    const float* Wout = (const float*)d_in[17];
    const float* bout = (const float*)d_in[18];
    const int* src0 = (const int*)d_in[19];
    const int* dst0 = (const int*)d_in[20];
    const int* src1 = (const int*)d_in[21];
    const int* dst1 = (const int*)d_in[22];
    const int* src2 = (const int*)d_in[23];
    const int* dst2 = (const int*)d_in[24];
    const int* src3 = (const int*)d_in[25];
    const int* dst3 = (const int*)d_in[26];
    float* out = (float*)d_out;

    char* ws = (char*)d_ws;
    size_t off = 0;
    auto alloc = [&](size_t bytes) -> char* {
        char* p = ws + off;
        off = (off + bytes + 255) & ~(size_t)255;
        return p;
    };
    ushort* hH  = (ushort*)alloc((size_t)NN * D * 2);
    ushort* gH  = (ushort*)alloc((size_t)NN * D * 2);
    // layer-1 GEMM output reuses hH (dead after layer-0 consumers)
    ushort* g2H = hH;
    ushort* WtH0 = (ushort*)alloc((size_t)DD * 2);
    ushort* WtL0 = (ushort*)alloc((size_t)DD * 2);
    ushort* WtH1 = (ushort*)alloc((size_t)DD * 2);
    ushort* WtL1 = (ushort*)alloc((size_t)DD * 2);
    ushort* WfTH = (ushort*)alloc((size_t)D * 32 * 2);
    ushort* WfTL = (ushort*)alloc((size_t)D * 32 * 2);
    float* wr0    = (float*)alloc((size_t)4 * DD * 4);
    float* wr1    = (float*)alloc((size_t)4 * DD * 4);
    float* ybuf   = (float*)alloc((size_t)(NA + NC) * D * 4);
    float* aggbuf = (float*)alloc((size_t)(NA + NC) * D * 4);
    int*   deg13  = (int*)  alloc((size_t)2 * NF * 4);
    int* deg1 = deg13; int* deg3 = deg13 + NF;
    float* inv1 = (float*)alloc((size_t)NF * 4);
    float* inv3 = (float*)alloc((size_t)NF * 4);
    float* inv0 = (float*)alloc((size_t)NA * 4);
    float* inv2 = (float*)alloc((size_t)NC * 4);
    int* rp0 = (int*)alloc((NA + 1) * 4);
    int* rp1 = (int*)alloc((size_t)(NF + 1) * 4);
    int* rp2 = (int*)alloc((NC + 1) * 4);
    int* rp3 = (int*)alloc((size_t)(NF + 1) * 4);
    int* cu1 = (int*)alloc((size_t)(NF + 1) * 4);
    int* cu3 = (int*)alloc((size_t)(NF + 1) * 4);
    int* csr0 = (int*)alloc((size_t)E * 4);
    int* csr1 = (int*)alloc((size_t)E * 4);
    int* csr2 = (int*)alloc((size_t)E * 4);
    int* csr3 = (int*)alloc((size_t)E * 4);
    int* bsum = (int*)alloc(256 * 4);
    int* bh0  = (int*)alloc((size_t)NSL * NA * 4);
    int* bh2  = (int*)alloc((size_t)NSL * NC * 4);
    (void)ws_size; (void)in_sizes; (void)n_in; (void)out_size;

    // deg13 must be zero before prep_kernel's deg_count blocks (stream order)
    hipMemsetAsync(deg13, 0, (size_t)2 * NF * 4, stream);

    // K1: hist02 + deg_count + wsplit(x2) + wr(x2)
    prep_kernel<<<K1_WR1_END, 256, 0, stream>>>(
        dst0, dst2, bh0, bh2, aggbuf, Wf, WfTH, WfTL,
        dst1, dst3, deg1, deg3,
        root0, WtH0, WtL0, root1, WtH1, WtL1,
        basis0, comp0, wr0, basis1, comp1, wr1);

    // K2: scanA + scan02
    scan_kernel<<<197, 1024, 0, stream>>>(
        deg1, deg3, bsum, bh0, bh2, rp0, rp2, inv0, inv2);

    // scanC (standalone: produces cu1/cu3 for fill13)
    scanC_kernel<<<196, 1024, 0, stream>>>(
        deg1, deg3, bsum, rp1, rp3, cu1, cu3, inv1, inv3);

    // work: encoder + tail + csr_fill13 + fill02, all co-scheduled
    work_kernel<<<W_TOTAL, 512, 0, stream>>>(
        xf, WfTH, WfTL, bf, xa, Wa, ba, xc, Wc, bc, hH,
        src1, dst1, src3, dst3, cu1, cu3, csr1, csr3,
        src0, dst0, src2, dst2, bh0, bh2, csr0, csr2);

    // ---- layer 0: {gemm + agg + y} co-scheduled, then finishers
    constexpr int NG0 = ((NN + 127) / 128) * 2;
    layer_kernel<0><<<NG0 + AGGB + YB, 512, 0, stream>>>(
        hH, WtH0, WtL0, bias0, gH, wr0, ybuf,
        rp0, csr0, rp2, csr2, aggbuf);
    finish0_kernel<<<(NA + NC) + (NF / 2 * 64 + 255) / 256, 256, 0, stream>>>(
        aggbuf, wr0, inv0, inv2, gH,
        ybuf, rp1, csr1, inv1, rp3, csr3, inv3);

    // ---- layer 1: {gemm + y} co-scheduled, then fused readout
    constexpr int NG1 = ((NF + 127) / 128) * 2;
    layer_kernel<1><<<NG1 + YB, 512, 0, stream>>>(
        gH, WtH1, WtL1, bias1, g2H, wr1, ybuf,
        nullptr, nullptr, nullptr, nullptr, nullptr);
    msg_readout_kernel<<<(NF / 2 * 64 + 255) / 256, 256, 0, stream>>>(
        g2H, ybuf, rp1, csr1, inv1, rp3, csr3, inv3, Wout, bout, out);
}

// Round 25
// 325.132 us; speedup vs baseline: 1.2901x; 1.0012x over previous
//
#include <hip/hip_runtime.h>
#include <hip/hip_bf16.h>
#include <cstdint>
#include <cstddef>

constexpr int NF = 100000;
constexpr int NA = 400;
constexpr int NC = 30;
constexpr int NN = NF + NA + NC;     // 100430
constexpr int D  = 256;
constexpr int DD = D * D;            // 65536
constexpr int E  = 250000;
constexpr int NSL = 128;             // slices for r0/r2 counting sort
constexpr int FBLK = (NF + 127) / 128;   // 782 flight-encoder blocks
constexpr int TAILB = (NA + NC + 7) / 8; // 54 scalar-tail blocks
constexpr int F13B = (2 * E + 511) / 512; // 977 csr_fill13 blocks (512 thr)
constexpr int AGGB = NA * 4 + NC * 64;    // 3520 agg chunks
constexpr int YB   = (NA + NC) / 2;       // 215 y blocks (2 rows each)

// K1 block ranges
constexpr int K1_HIST_END = 2 * NSL;                       // 256
constexpr int K1_DEG_END  = K1_HIST_END + (2 * E + 255) / 256;  // 2210
constexpr int K1_WS0_END  = K1_DEG_END + 256;              // 2466
constexpr int K1_WS1_END  = K1_WS0_END + 256;              // 2722
constexpr int K1_WR0_END  = K1_WS1_END + 1024;             // 3746
constexpr int K1_WR1_END  = K1_WR0_END + 1024;             // 4770

// work_kernel block ranges: encoder | tail | fill13 | fill02
constexpr int W_ENC_END  = FBLK;                 // 782
constexpr int W_TAIL_END = W_ENC_END + TAILB;    // 836
constexpr int W_F13_END  = W_TAIL_END + F13B;    // 1813
constexpr int W_TOTAL    = W_F13_END + 2 * NSL;  // 2069

typedef __attribute__((ext_vector_type(8))) short bf16x8;
typedef __attribute__((ext_vector_type(4))) float f32x4;
typedef __attribute__((ext_vector_type(8))) ushort u16x8;

__device__ inline ushort f2bf(float f) {
    __hip_bfloat16 h = __float2bfloat16(f);
    return __builtin_bit_cast(ushort, h);
}
__device__ inline float bf2f(ushort u) {
    __hip_bfloat16 h = __builtin_bit_cast(__hip_bfloat16, u);
    return __bfloat162float(h);
}

// async global->LDS, 16B per lane: LDS dest = base + lane*16 (wave-linear)
__device__ inline void gload_lds16(const ushort* g, ushort* l) {
    __builtin_amdgcn_global_load_lds(
        (const __attribute__((address_space(1))) void*)g,
        (__attribute__((address_space(3))) void*)l, 16, 0, 0);
}

// ==== K1: hist02 + deg_count + wsplit(x2) + wr(x2), co-scheduled ============
__global__ __launch_bounds__(256) void prep_kernel(
    const int* __restrict__ dst0, const int* __restrict__ dst2,
    int* __restrict__ bh0, int* __restrict__ bh2,
    float* __restrict__ aggz,
    const float* __restrict__ Wf, ushort* __restrict__ WfTH, ushort* __restrict__ WfTL,
    const int* __restrict__ dst1, const int* __restrict__ dst3,
    int* __restrict__ deg1, int* __restrict__ deg3,
    const float* __restrict__ root0, ushort* __restrict__ WtH0, ushort* __restrict__ WtL0,
    const float* __restrict__ root1, ushort* __restrict__ WtH1, ushort* __restrict__ WtL1,
    const float* __restrict__ basis0, const float* __restrict__ comp0, float* __restrict__ wr0,
    const float* __restrict__ basis1, const float* __restrict__ comp1, float* __restrict__ wr1)
{
    __shared__ int hist[NA];
    const int b = blockIdx.x;
    const int t = threadIdx.x;
    if (b < K1_HIST_END) {
        for (int i = b * 256 + t; i < (NA + NC) * D; i += K1_HIST_END * 256)
            aggz[i] = 0.f;
        if (b < 32) {
            float wv = Wf[(size_t)b * D + t];
            ushort hi = f2bf(wv);
            WfTH[(size_t)t * 32 + b] = hi;
            WfTL[(size_t)t * 32 + b] = f2bf(wv - bf2f(hi));
        }
        bool isR2 = (b >= NSL);
        int sl = isR2 ? b - NSL : b;
        const int* dst = isR2 ? dst2 : dst0;
        int nb = isR2 ? NC : NA;
        for (int i = t; i < nb; i += 256) hist[i] = 0;
        __syncthreads();
        int lo = (int)((long long)E * sl / NSL);
        int hi = (int)((long long)E * (sl + 1) / NSL);
        for (int e = lo + t; e < hi; e += 256)
            atomicAdd(&hist[dst[e]], 1);
        __syncthreads();
        int* bh = isR2 ? (bh2 + sl * NC) : (bh0 + sl * NA);
        for (int i = t; i < nb; i += 256) bh[i] = hist[i];
    } else if (b < K1_DEG_END) {
        int idx = (b - K1_HIST_END) * 256 + t;
        if (idx < 2 * E) {
            if (idx < E) atomicAdd(&deg1[dst1[idx]], 1);
            else         atomicAdd(&deg3[dst3[idx - E]], 1);
        }
    } else if (b < K1_WS0_END) {
        int n = b - K1_DEG_END;
        float w = root0[(size_t)t * D + n];
        ushort hi = f2bf(w);
        WtH0[(size_t)n * D + t] = hi;
        WtL0[(size_t)n * D + t] = f2bf(w - bf2f(hi));
    } else if (b < K1_WS1_END) {
        int n = b - K1_WS0_END;
        float w = root1[(size_t)t * D + n];
        ushort hi = f2bf(w);
        WtH1[(size_t)n * D + t] = hi;
        WtL1[(size_t)n * D + t] = f2bf(w - bf2f(hi));
    } else if (b < K1_WR0_END) {
        int idx = (b - K1_WS1_END) * 256 + t;
        int r = idx >> 16;
        int io = idx & (DD - 1);
        wr0[idx] = comp0[r * 3 + 0] * basis0[io]
                 + comp0[r * 3 + 1] * basis0[DD + io]
                 + comp0[r * 3 + 2] * basis0[2 * DD + io];
    } else {
        int idx = (b - K1_WR0_END) * 256 + t;
        int r = idx >> 16;
        int io = idx & (DD - 1);
        wr1[idx] = comp1[r * 3 + 0] * basis1[io]
                 + comp1[r * 3 + 1] * basis1[DD + io]
                 + comp1[r * 3 + 2] * basis1[2 * DD + io];
    }
}

// ==== K2: scanA (blocks 0..195) + scan02 (block 196), co-scheduled ==========
__global__ __launch_bounds__(1024) void scan_kernel(
    const int* __restrict__ deg1, const int* __restrict__ deg3,
    int* __restrict__ bsum,
    int* __restrict__ bh0, int* __restrict__ bh2,
    int* __restrict__ rp0, int* __restrict__ rp2,
    float* __restrict__ inv0, float* __restrict__ inv2)
{
    __shared__ int s[1024];
    __shared__ int tot[512];
    __shared__ int exc[512];
    const int b = blockIdx.x;
    const int t = threadIdx.x;
    if (b < 196) {
        bool isR3 = (b >= 98);
        const int* deg = isR3 ? deg3 : deg1;
        int chunk = isR3 ? b - 98 : b;
        int i = chunk * 1024 + t;
        int v = (i < NF) ? deg[i] : 0;
        s[t] = v;
        __syncthreads();
        for (int ofs = 512; ofs > 0; ofs >>= 1) {
            if (t < ofs) s[t] += s[t + ofs];
            __syncthreads();
        }
        if (t == 0) bsum[(isR3 ? 128 : 0) + chunk] = s[0];
        return;
    }
    int cnt = 0;
    if (t < NA) {
        int ss = 0;
        for (int sl = 0; sl < NSL; ++sl) {
            int v = bh0[sl * NA + t]; bh0[sl * NA + t] = ss; ss += v;
        }
        cnt = ss;
    } else if (t < NA + NC) {
        int bin = t - NA; int ss = 0;
        for (int sl = 0; sl < NSL; ++sl) {
            int v = bh2[sl * NC + bin]; bh2[sl * NC + bin] = ss; ss += v;
        }
        cnt = ss;
    }
    if (t < 512) tot[t] = cnt;
    __syncthreads();
    for (int ofs = 1; ofs < 512; ofs <<= 1) {
        int v = 0;
        if (t < 512 && t >= ofs) v = tot[t - ofs];
        __syncthreads();
        if (t < 512) tot[t] += v;
        __syncthreads();
    }
    if (t < 512) {
        int ex = tot[t] - cnt;
        if (t < NA) {
            exc[t] = ex;
            rp0[t] = ex;
            inv0[t] = 1.0f / (float)(cnt > 1 ? cnt : 1);
            if (t == 0) { rp0[NA] = E; rp2[NC] = E; }
        } else if (t < NA + NC) {
            exc[t] = ex - E;
            rp2[t - NA] = ex - E;
            inv2[t - NA] = 1.0f / (float)(cnt > 1 ? cnt : 1);
        } else exc[t] = 0;
    }
    __syncthreads();
    for (int idx = t; idx < NSL * NA; idx += 1024) {
        int sl = idx / NA; int bin = idx - sl * NA;
        bh0[idx] += exc[bin];
    }
    for (int idx = t; idx < NSL * NC; idx += 1024) {
        int sl = idx / NC; int bin = idx - sl * NC;
        bh2[idx] += exc[NA + bin];
    }
}

// ==== scanC (with inlined scanB), standalone -------------------------------
__global__ __launch_bounds__(1024) void scanC_kernel(
    const int* __restrict__ deg1, const int* __restrict__ deg3,
    const int* __restrict__ bsum,
    int* __restrict__ rp1, int* __restrict__ rp3,
    int* __restrict__ cu1, int* __restrict__ cu3,
    float* __restrict__ inv1, float* __restrict__ inv3)
{
    __shared__ int s[1024];
    __shared__ int s2[256];
    int t = threadIdx.x;
    int b = blockIdx.x;                    // 0..195
    int vb = 0;
    if (t < 256) {
        vb = ((t & 127) < 98) ? bsum[t] : 0;
        s2[t] = vb;
    }
    __syncthreads();
    for (int ofs = 1; ofs < 128; ofs <<= 1) {
        int a = 0;
        if (t < 256 && (t & 127) >= ofs) a = s2[t - ofs];
        __syncthreads();
        if (t < 256) s2[t] += a;
        __syncthreads();
    }
    if (t < 256) s2[t] -= vb;          // exclusive
    __syncthreads();
    const int* deg; int* rp; int* cu; float* inv; int chunk; int prefix;
    if (b < 98) { deg = deg1; rp = rp1; cu = cu1; inv = inv1; chunk = b;      prefix = s2[chunk]; }
    else        { deg = deg3; rp = rp3; cu = cu3; inv = inv3; chunk = b - 98; prefix = s2[128 + chunk]; }
    int i = chunk * 1024 + t;
    int v = (i < NF) ? deg[i] : 0;
    s[t] = v;
    __syncthreads();
    for (int ofs = 1; ofs < 1024; ofs <<= 1) {
        int a = (t >= ofs) ? s[t - ofs] : 0;
        __syncthreads();
        s[t] += a;
        __syncthreads();
    }
    int ex = prefix + s[t] - v;
    if (i < NF) {
        rp[i] = ex;
        cu[i] = ex;
        inv[i] = 1.0f / (float)(v > 1 ? v : 1);
    }
    if (i == 0) rp[NF] = E;
}

// ==== work_kernel: encoder + tail + csr_fill13 + fill02, co-scheduled =======
__global__ __launch_bounds__(512) void work_kernel(
    const float* __restrict__ xf,
    const ushort* __restrict__ WtH8, const ushort* __restrict__ WtL8,
    const float* __restrict__ bfl,
    const float* __restrict__ xa, const float* __restrict__ Wa, const float* __restrict__ ba,
    const float* __restrict__ xc, const float* __restrict__ Wc, const float* __restrict__ bc,
    ushort* __restrict__ hH,
    const int* __restrict__ src1, const int* __restrict__ dst1,
    const int* __restrict__ src3, const int* __restrict__ dst3,
    int* __restrict__ cu1, int* __restrict__ cu3,
    int* __restrict__ csr1, int* __restrict__ csr3,
    const int* __restrict__ src0, const int* __restrict__ dst0,
    const int* __restrict__ src2, const int* __restrict__ dst2,
    const int* __restrict__ bh0, const int* __restrict__ bh2,
    int* __restrict__ csr0, int* __restrict__ csr2)
{
    __shared__ __align__(16) ushort lds[20480];            // 40960 B
    const int t = threadIdx.x;
    const int b = blockIdx.x;
    if (b >= W_F13_END) {
        // ---- fill02 (512 threads, LDS cursor)
        int bb = b - W_F13_END;
        int* cur = (int*)lds;
        bool isR2 = (bb >= NSL);
        int sl = isR2 ? bb - NSL : bb;
        const int* src = isR2 ? src2 : src0;
        const int* dst = isR2 ? dst2 : dst0;
        const int* bh  = isR2 ? (bh2 + sl * NC) : (bh0 + sl * NA);
        int* csr       = isR2 ? csr2 : csr0;
        int nb = isR2 ? NC : NA;
        for (int i = t; i < nb; i += 512) cur[i] = bh[i];
        __syncthreads();
        int lo = (int)((long long)E * sl / NSL);
        int hi = (int)((long long)E * (sl + 1) / NSL);
        for (int e = lo + t; e < hi; e += 512) {
            int pos = atomicAdd(&cur[dst[e]], 1);
            csr[pos] = src[e];
        }
        return;
    }
    if (b >= W_TAIL_END) {
        // ---- csr_fill13
        int idx = (b - W_TAIL_END) * 512 + t;
        if (idx < 2 * E) {
            if (idx < E) {
                int pos = atomicAdd(&cu1[dst1[idx]], 1);
                csr1[pos] = src1[idx];
            } else {
                int e = idx - E;
                int pos = atomicAdd(&cu3[dst3[e]], 1);
                csr3[pos] = src3[e];
            }
        }
        return;
    }
    if (b >= W_ENC_END) {
        // ---- airports + carriers scalar path
        int c = t & 255;
        int i0 = t >> 8;
        int base = (b - W_ENC_END) * 8;
        for (int i = i0; i < 8; i += 2) {
            int row = base + i;
            if (row >= NA + NC) break;
            float acc;
            if (row < NA) {
                const float* xr = xa + (size_t)row * 16;
                acc = ba[c];
                #pragma unroll
                for (int k = 0; k < 16; ++k) acc += xr[k] * Wa[k * D + c];
            } else {
                const float* xr = xc + (size_t)(row - NA) * 8;
                acc = bc[c];
                #pragma unroll
                for (int k = 0; k < 8; ++k) acc += xr[k] * Wc[k * D + c];
            }
            hH[(size_t)(NF + row) * D + c] = f2bf(fmaxf(acc, 0.f));
        }
        return;
    }
    // ---- flight MFMA encoder
    constexpr int AOFF = 0, WHOFF = 4096, WLOFF = 12288;   // ushort offsets
    const int row0 = b * 128;
    const int w = t >> 6, lane = t & 63;     // 8 waves
    const int wm = w >> 2, wn = w & 3;       // 2x4 grid, 64 rows x 64 cols/wave
    const int lr = lane & 15;
    const int lk = lane >> 4;
    {
        int r = t >> 2;                      // 0..127
        int seg = (t & 3) * 8;               // 0,8,16,24
        int gr = row0 + r; if (gr >= NF) gr = NF - 1;
        const float* xr = xf + (size_t)gr * 32 + seg;
        float4 a0 = *(const float4*)xr;
        float4 a1 = *(const float4*)(xr + 4);
        u16x8 bb;
        bb[0] = f2bf(a0.x); bb[1] = f2bf(a0.y); bb[2] = f2bf(a0.z); bb[3] = f2bf(a0.w);
        bb[4] = f2bf(a1.x); bb[5] = f2bf(a1.y); bb[6] = f2bf(a1.z); bb[7] = f2bf(a1.w);
        int g = r >> 4, rr = r & 15, kg = seg >> 3;
        *(u16x8*)(lds + AOFF + g * 512 + (rr + 16 * kg) * 8) = bb;
    }
    #pragma unroll
    for (int i = 0; i < 4; ++i) {
        int u = w * 4 + i;                   // 0..31
        int plane = u >> 4, g = u & 15;
        const ushort* src = (plane ? WtL8 : WtH8) + ((size_t)(g * 16 + lr)) * 32 + lk * 8;
        ushort* dst = lds + (plane ? WLOFF : WHOFF) + g * 512;
        gload_lds16(src, dst);
    }
    __syncthreads();
    f32x4 acc[4][4] = {};
    bf16x8 bhv[4], blv[4];
    #pragma unroll
    for (int ni = 0; ni < 4; ++ni) {
        int off = (wn * 4 + ni) * 512 + lane * 8;
        bhv[ni] = *(const bf16x8*)(lds + WHOFF + off);
        blv[ni] = *(const bf16x8*)(lds + WLOFF + off);
    }
    #pragma unroll
    for (int mi = 0; mi < 4; ++mi) {
        bf16x8 ah = *(const bf16x8*)(lds + AOFF + (wm * 4 + mi) * 512 + lane * 8);
        #pragma unroll
        for (int ni = 0; ni < 4; ++ni) {
            acc[mi][ni] = __builtin_amdgcn_mfma_f32_16x16x32_bf16(ah, bhv[ni], acc[mi][ni], 0, 0, 0);
            acc[mi][ni] = __builtin_amdgcn_mfma_f32_16x16x32_bf16(ah, blv[ni], acc[mi][ni], 0, 0, 0);
        }
    }
    constexpr int ELDW = 68;
    float* S = (float*)lds + (size_t)w * 16 * ELDW;
    const int rrow = lane >> 3;
    const int grp  = lane & 7;
    #pragma unroll
    for (int mi = 0; mi < 4; ++mi) {
        __syncthreads();
        #pragma unroll
        for (int ni = 0; ni < 4; ++ni)
            #pragma unroll
            for (int reg = 0; reg < 4; ++reg)
                S[(lk * 4 + reg) * ELDW + ni * 16 + lr] = acc[mi][ni][reg];
        __syncthreads();
        #pragma unroll
        for (int it = 0; it < 2; ++it) {
            int row_i = rrow + it * 8;
            int gr = row0 + wm * 64 + mi * 16 + row_i;
            int gc = wn * 64 + grp * 8;
            if (gr >= NF) continue;
            float4 f0 = *(const float4*)(&S[row_i * ELDW + grp * 8]);
            float4 f1 = *(const float4*)(&S[row_i * ELDW + grp * 8 + 4]);
            float4 b0 = *(const float4*)(bfl + gc);
            float4 b1 = *(const float4*)(bfl + gc + 4);
            u16x8 hh;
            hh[0] = f2bf(fmaxf(f0.x + b0.x, 0.f));
            hh[1] = f2bf(fmaxf(f0.y + b0.y, 0.f));
            hh[2] = f2bf(fmaxf(f0.z + b0.z, 0.f));
            hh[3] = f2bf(fmaxf(f0.w + b0.w, 0.f));
            hh[4] = f2bf(fmaxf(f1.x + b1.x, 0.f));
            hh[5] = f2bf(fmaxf(f1.y + b1.y, 0.f));
            hh[6] = f2bf(fmaxf(f1.z + b1.z, 0.f));
            hh[7] = f2bf(fmaxf(f1.w + b1.w, 0.f));
            *(u16x8*)(hH + (size_t)gr * D + gc) = hh;
        }
    }
}

// ==== layer kernel: gemm tiles + (MODE 0: agg chunks) + y rows, co-sched ====
// gemm block decode uses an XCD-pairing swizzle: the two column tiles of one
// row tile get blockIdx values differing by exactly 8 (same XCD under
// round-robin dispatch) so the shared 64 KB A panel is an L2 hit on reuse.
template<int MODE>
__global__ __launch_bounds__(512) void layer_kernel(
    const ushort* __restrict__ A,
    const ushort* __restrict__ WtH, const ushort* __restrict__ WtL,
    const float* __restrict__ bias, ushort* __restrict__ G,
    const float* __restrict__ wr, float* __restrict__ y,
    const int* __restrict__ rp0, const int* __restrict__ csr0,
    const int* __restrict__ rp2, const int* __restrict__ csr2,
    float* __restrict__ agg)
{
    constexpr int BM = 128, BK = 32;
    constexpr int PLANE = BM * BK;          // 4096 ushorts = 8 KB
    constexpr int BUF = 3 * PLANE;          // 12288 ushorts = 24 KB
    constexpr int LDW = 36;                 // fp32 epilogue scratch stride
    constexpr int nrows = (MODE == 0) ? NN : NF;
    constexpr int NT = (nrows + 127) / 128;   // row tiles
    constexpr int NG = NT * 2;
    constexpr int G8 = (NT / 8) * 16;         // full swizzle groups
    constexpr int NAGG = (MODE == 0) ? AGGB : 0;
    __shared__ __align__(16) ushort lds[2 * BUF];   // 49152 B
    const int t = threadIdx.x;
    const int b = blockIdx.x;
    if (b >= NG) {
        int bb = b - NG;
        if (MODE == 0 && bb < NAGG) {
            float* red = (float*)lds;        // 8 x 256 floats
            const int* rp; const int* csr; int dstn, chunk, nch; float* arow;
            if (bb < NA * 4) { dstn = bb >> 2; chunk = bb & 3; nch = 4;  rp = rp0; csr = csr0; arow = agg + (size_t)dstn * D; }
            else { int b2 = bb - NA * 4; dstn = b2 >> 6; chunk = b2 & 63; nch = 64; rp = rp2; csr = csr2; arow = agg + (size_t)(NA + dstn) * D; }
            int s = rp[dstn], e = rp[dstn + 1];
            int cnt = e - s;
            int lo = s + (int)((long long)cnt * chunk / nch);
            int hi = s + (int)((long long)cnt * (chunk + 1) / nch);
            int w8 = t >> 6, lane = t & 63;
            int span = hi - lo;
            int wlo = lo + (int)((long long)span * w8 / 8);
            int whi = lo + (int)((long long)span * (w8 + 1) / 8);
            int half = lane >> 5;
            int ch8 = (lane & 31) * 8;
            float acc[8] = {};
            int p = wlo;
            for (; p + 1 < whi; p += 2) {
                int r = csr[p + half];
                u16x8 v = *(const u16x8*)(A + (size_t)r * D + ch8);
                #pragma unroll
                for (int j = 0; j < 8; ++j) acc[j] += bf2f(v[j]);
            }
            if (p < whi && half == 0) {
                int r = csr[p];
                u16x8 v = *(const u16x8*)(A + (size_t)r * D + ch8);
                #pragma unroll
                for (int j = 0; j < 8; ++j) acc[j] += bf2f(v[j]);
            }
            #pragma unroll
            for (int j = 0; j < 8; ++j) acc[j] += __shfl_xor(acc[j], 32);
            if (lane < 32) {
                #pragma unroll
                for (int j = 0; j < 8; ++j) red[w8 * 256 + ch8 + j] = acc[j];
            }
            __syncthreads();
            if (t < 256) {
                float total = 0.f;
                #pragma unroll
                for (int j = 0; j < 8; ++j) total += red[j * 256 + t];
                atomicAdd(arow + t, total);
            }
            return;
        }
        int yb = bb - NAGG;
        int row = yb * 2 + (t >> 8);
        if (row < NA + NC) {
            int c = t & 255;
            const ushort* sH = A + (size_t)(NF + row) * D;
            const float* W = wr + (size_t)((row < NA) ? 1 : 3) * DD;
            float acc = 0.f;
            #pragma unroll 8
            for (int k = 0; k < D; ++k) acc += bf2f(sH[k]) * W[k * D + c];
            y[(size_t)row * D + c] = acc;
        }
        return;
    }
    // ---- gemm tile with XCD-pairing swizzle (bijective incl. tail) ----
    int rtile, ctile;
    if (b < G8) {
        int g = b >> 4, j = b & 15;
        rtile = g * 8 + (j & 7);
        ctile = j >> 3;
    } else {
        int j = b - G8;
        rtile = (NT / 8) * 8 + (j >> 1);
        ctile = j & 1;
    }
    const int row0 = rtile * BM;
    const int col0 = ctile * BM;
    const int w = t >> 6, lane = t & 63;    // 8 waves
    const int wm = w >> 2, wn = w & 3;      // 2x4 wave grid, 64x32 per wave
    const int lr = lane & 15;
    const int lk = lane >> 4;
    f32x4 acc[4][2] = {};

    const ushort* sp[3];
    int dofs[3];
    #pragma unroll
    for (int i = 0; i < 3; ++i) {
        int idx = w * 3 + i;
        int plane = idx >> 3, g = idx & 7;
        const ushort* base = (plane == 0) ? A : (plane == 1) ? WtH : WtL;
        int r = ((plane == 0) ? row0 : col0) + g * 16 + lr;
        if (plane == 0 && r >= nrows) r = nrows - 1;
        sp[i] = base + (size_t)r * D + lk * 8;
        dofs[i] = plane * PLANE + g * 512;
    }

    auto stage = [&](int kt, int buf) {
        ushort* bb2 = lds + buf * BUF;
        int k0 = kt * BK;
        #pragma unroll
        for (int i = 0; i < 3; ++i)
            gload_lds16(sp[i] + k0, bb2 + dofs[i]);
    };
    auto compute = [&](int buf) {
        const ushort* base = lds + buf * BUF;
        const ushort* As  = base;
        const ushort* WsH = base + PLANE;
        const ushort* WsL = base + 2 * PLANE;
        bf16x8 bh[2], bl[2];
        #pragma unroll
        for (int ni = 0; ni < 2; ++ni) {
            int off = (wn * 2 + ni) * 512 + lane * 8;
            bh[ni] = *(const bf16x8*)(&WsH[off]);
            bl[ni] = *(const bf16x8*)(&WsL[off]);
        }
        #pragma unroll
        for (int mi = 0; mi < 4; ++mi) {
            int off = (wm * 4 + mi) * 512 + lane * 8;
            bf16x8 ah = *(const bf16x8*)(&As[off]);
            #pragma unroll
            for (int ni = 0; ni < 2; ++ni) {
                acc[mi][ni] = __builtin_amdgcn_mfma_f32_16x16x32_bf16(ah, bh[ni], acc[mi][ni], 0, 0, 0);
                acc[mi][ni] = __builtin_amdgcn_mfma_f32_16x16x32_bf16(ah, bl[ni], acc[mi][ni], 0, 0, 0);
            }
        }
    };

    stage(0, 0);
    stage(1, 1);
#define PIPE_ITER(KT, PEND)                                        \
    asm volatile("s_waitcnt vmcnt(" #PEND ")" ::: "memory");       \
    __builtin_amdgcn_s_barrier();                                  \
    __builtin_amdgcn_sched_barrier(0);                             \
    compute((KT) & 1);                                             \
    __builtin_amdgcn_s_barrier();                                  \
    __builtin_amdgcn_sched_barrier(0);                             \
    if ((KT) + 2 < 8) stage((KT) + 2, (KT) & 1);
    PIPE_ITER(0, 3)
    PIPE_ITER(1, 3)
    PIPE_ITER(2, 3)
    PIPE_ITER(3, 3)
    PIPE_ITER(4, 3)
    PIPE_ITER(5, 3)
    PIPE_ITER(6, 3)
    PIPE_ITER(7, 0)
#undef PIPE_ITER

    __syncthreads();
    float* S = (float*)lds + (size_t)w * 16 * LDW;   // per-wave 16x36 fp32
    const int rrow = lane >> 2;            // 0..15 read-back row
    const int grp  = lane & 3;             // col octet (8 bf16)
    #pragma unroll
    for (int mi = 0; mi < 4; ++mi) {
        __syncthreads();
        #pragma unroll
        for (int ni = 0; ni < 2; ++ni)
            #pragma unroll
            for (int reg = 0; reg < 4; ++reg)
                S[(lk * 4 + reg) * LDW + ni * 16 + lr] = acc[mi][ni][reg];
        __syncthreads();
        int gr = row0 + wm * 64 + mi * 16 + rrow;
        int gc = col0 + wn * 32 + grp * 8;
        if (gr >= nrows) continue;
        float4 f0 = *(const float4*)(&S[rrow * LDW + grp * 8]);
        float4 f1 = *(const float4*)(&S[rrow * LDW + grp * 8 + 4]);
        float4 b0 = *(const float4*)(bias + gc);
        float4 b1 = *(const float4*)(bias + gc + 4);
        float v[8] = {f0.x + b0.x, f0.y + b0.y, f0.z + b0.z, f0.w + b0.w,
                      f1.x + b1.x, f1.y + b1.y, f1.z + b1.z, f1.w + b1.w};
        u16x8 hh;
        #pragma unroll
        for (int j = 0; j < 8; ++j) hh[j] = f2bf(v[j]);
        *(u16x8*)(G + (size_t)gr * D + gc) = hh;
    }
}

// ==== finish0: smallT (blocks 0..429) + msg_relu, co-scheduled ==============
__global__ __launch_bounds__(256) void finish0_kernel(
    const float* __restrict__ agg, const float* __restrict__ wr,
    const float* __restrict__ inv0, const float* __restrict__ inv2,
    ushort* __restrict__ G,
    const float* __restrict__ y,
    const int* __restrict__ rp1, const int* __restrict__ csr1, const float* __restrict__ inv1,
    const int* __restrict__ rp3, const int* __restrict__ csr3, const float* __restrict__ inv3)
{
    const int b = blockIdx.x;
    const int t = threadIdx.x;
    if (b < NA + NC) {
        int row = b;
        int c = t;
        const float* a = agg + (size_t)row * D;
        const float* W = wr + (size_t)((row < NA) ? 0 : 2) * DD;
        float scale = (row < NA) ? inv0[row] : inv2[row - NA];
        float acc = 0.f;
        #pragma unroll 8
        for (int k = 0; k < D; ++k) acc += a[k] * W[k * D + c];
        size_t o = (size_t)(NF + row) * D + c;
        G[o] = f2bf(fmaxf(bf2f(G[o]) + scale * acc, 0.f));
        return;
    }
    int wid = ((b - (NA + NC)) * 256 + t) >> 6;
    int lane = t & 63;
    int row = wid * 2 + (lane >> 5);
    if (row >= NF) return;
    int c = (lane & 31) * 8;
    size_t o = (size_t)row * D + c;
    u16x8 gh = *(const u16x8*)(G + o);
    float v[8];
    #pragma unroll
    for (int j = 0; j < 8; ++j) v[j] = bf2f(gh[j]);
    float m[8] = {};
    int e0 = rp1[row], e1 = rp1[row + 1];
    for (int e = e0; e < e1; ++e) {
        const float* yr = y + (size_t)csr1[e] * D + c;
        float4 u0 = *(const float4*)yr;
        float4 u1 = *(const float4*)(yr + 4);
        m[0] += u0.x; m[1] += u0.y; m[2] += u0.z; m[3] += u0.w;
        m[4] += u1.x; m[5] += u1.y; m[6] += u1.z; m[7] += u1.w;
    }
    float s1 = inv1[row];
    #pragma unroll
    for (int j = 0; j < 8; ++j) { v[j] += s1 * m[j]; m[j] = 0.f; }
    e0 = rp3[row]; e1 = rp3[row + 1];
    for (int e = e0; e < e1; ++e) {
        const float* yr = y + (size_t)(NA + csr3[e]) * D + c;
        float4 u0 = *(const float4*)yr;
        float4 u1 = *(const float4*)(yr + 4);
        m[0] += u0.x; m[1] += u0.y; m[2] += u0.z; m[3] += u0.w;
        m[4] += u1.x; m[5] += u1.y; m[6] += u1.z; m[7] += u1.w;
    }
    float s3 = inv3[row];
    u16x8 oh;
    #pragma unroll
    for (int j = 0; j < 8; ++j) oh[j] = f2bf(fmaxf(v[j] + s3 * m[j], 0.f));
    *(u16x8*)(G + o) = oh;
}

// ---- layer-1: out[f] = relu(G2+msgs) . W_out + b_out (fused readout) -------
__global__ __launch_bounds__(256) void msg_readout_kernel(
    const ushort* __restrict__ G,
    const float* __restrict__ y,
    const int* __restrict__ rp1, const int* __restrict__ csr1, const float* __restrict__ inv1,
    const int* __restrict__ rp3, const int* __restrict__ csr3, const float* __restrict__ inv3,
    const float* __restrict__ wout, const float* __restrict__ bout,
    float* __restrict__ out)
{
    int wid = (blockIdx.x * 256 + threadIdx.x) >> 6;
    int lane = threadIdx.x & 63;
    int row = wid * 2 + (lane >> 5);
    if (row >= NF) return;
    int c = (lane & 31) * 8;
    size_t o = (size_t)row * D + c;
    u16x8 gh = *(const u16x8*)(G + o);
    float v[8];
    #pragma unroll
    for (int j = 0; j < 8; ++j) v[j] = bf2f(gh[j]);
    float m[8] = {};
    int e0 = rp1[row], e1 = rp1[row + 1];
    for (int e = e0; e < e1; ++e) {
        const float* yr = y + (size_t)csr1[e] * D + c;
        float4 u0 = *(const float4*)yr;
        float4 u1 = *(const float4*)(yr + 4);
        m[0] += u0.x; m[1] += u0.y; m[2] += u0.z; m[3] += u0.w;
        m[4] += u1.x; m[5] += u1.y; m[6] += u1.z; m[7] += u1.w;
    }
    float s1 = inv1[row];
    #pragma unroll
    for (int j = 0; j < 8; ++j) { v[j] += s1 * m[j]; m[j] = 0.f; }
    e0 = rp3[row]; e1 = rp3[row + 1];
    for (int e = e0; e < e1; ++e) {
        const float* yr = y + (size_t)(NA + csr3[e]) * D + c;
        float4 u0 = *(const float4*)yr;
        float4 u1 = *(const float4*)(yr + 4);
        m[0] += u0.x; m[1] += u0.y; m[2] += u0.z; m[3] += u0.w;
        m[4] += u1.x; m[5] += u1.y; m[6] += u1.z; m[7] += u1.w;
    }
    float s3 = inv3[row];
    float4 w0 = *(const float4*)(wout + c);
    float4 w1 = *(const float4*)(wout + c + 4);
    float wv[8] = {w0.x, w0.y, w0.z, w0.w, w1.x, w1.y, w1.z, w1.w};
    float pr = 0.f;
    #pragma unroll
    for (int j = 0; j < 8; ++j) pr += fmaxf(v[j] + s3 * m[j], 0.f) * wv[j];
    pr += __shfl_xor(pr, 1);
    pr += __shfl_xor(pr, 2);
    pr += __shfl_xor(pr, 4);
    pr += __shfl_xor(pr, 8);
    pr += __shfl_xor(pr, 16);
    if ((lane & 31) == 0) out[row] = pr + bout[0];
}

extern "C" void kernel_launch(void* const* d_in, const int* in_sizes, int n_in,
                              void* d_out, int out_size, void* d_ws, size_t ws_size,
                              hipStream_t stream)
{
    const float* xf = (const float*)d_in[0];
    const float* xa = (const float*)d_in[1];
    const float* xc = (const float*)d_in[2];
    const float* Wf = (const float*)d_in[3];
    const float* bf = (const float*)d_in[4];
    const float* Wa = (const float*)d_in[5];
    const float* ba = (const float*)d_in[6];
    const float* Wc = (const float*)d_in[7];
    const float* bc = (const float*)d_in[8];
    const float* basis0 = (const float*)d_in[9];
    const float* comp0  = (const float*)d_in[10];
    const float* root0  = (const float*)d_in[11];
    const float* bias0  = (const float*)d_in[12];
    const float* basis1 = (const float*)d_in[13];
    const float* comp1  = (const float*)d_in[14];
    const float* root1  = (const float*)d_in[15];
    const float* bias1  = (const float*)d_in[16];
    const float* Wout = (const float*)d_in[17];
    const float* bout = (const float*)d_in[18];
    const int* src0 = (const int*)d_in[19];
    const int* dst0 = (const int*)d_in[20];
    const int* src1 = (const int*)d_in[21];
    const int* dst1 = (const int*)d_in[22];
    const int* src2 = (const int*)d_in[23];
    const int* dst2 = (const int*)d_in[24];
    const int* src3 = (const int*)d_in[25];
    const int* dst3 = (const int*)d_in[26];
    float* out = (float*)d_out;

    char* ws = (char*)d_ws;
    size_t off = 0;
    auto alloc = [&](size_t bytes) -> char* {
        char* p = ws + off;
        off = (off + bytes + 255) & ~(size_t)255;
        return p;
    };
    ushort* hH  = (ushort*)alloc((size_t)NN * D * 2);
    ushort* gH  = (ushort*)alloc((size_t)NN * D * 2);
    // layer-1 GEMM output reuses hH (dead after layer-0 consumers)
    ushort* g2H = hH;
    ushort* WtH0 = (ushort*)alloc((size_t)DD * 2);
    ushort* WtL0 = (ushort*)alloc((size_t)DD * 2);
    ushort* WtH1 = (ushort*)alloc((size_t)DD * 2);
    ushort* WtL1 = (ushort*)alloc((size_t)DD * 2);
    ushort* WfTH = (ushort*)alloc((size_t)D * 32 * 2);
    ushort* WfTL = (ushort*)alloc((size_t)D * 32 * 2);
    float* wr0    = (float*)alloc((size_t)4 * DD * 4);
    float* wr1    = (float*)alloc((size_t)4 * DD * 4);
    float* ybuf   = (float*)alloc((size_t)(NA + NC) * D * 4);
    float* aggbuf = (float*)alloc((size_t)(NA + NC) * D * 4);
    int*   deg13  = (int*)  alloc((size_t)2 * NF * 4);
    int* deg1 = deg13; int* deg3 = deg13 + NF;
    float* inv1 = (float*)alloc((size_t)NF * 4);
    float* inv3 = (float*)alloc((size_t)NF * 4);
    float* inv0 = (float*)alloc((size_t)NA * 4);
    float* inv2 = (float*)alloc((size_t)NC * 4);
    int* rp0 = (int*)alloc((NA + 1) * 4);
    int* rp1 = (int*)alloc((size_t)(NF + 1) * 4);
    int* rp2 = (int*)alloc((NC + 1) * 4);
    int* rp3 = (int*)alloc((size_t)(NF + 1) * 4);
    int* cu1 = (int*)alloc((size_t)(NF + 1) * 4);
    int* cu3 = (int*)alloc((size_t)(NF + 1) * 4);
    int* csr0 = (int*)alloc((size_t)E * 4);
    int* csr1 = (int*)alloc((size_t)E * 4);
    int* csr2 = (int*)alloc((size_t)E * 4);
    int* csr3 = (int*)alloc((size_t)E * 4);
    int* bsum = (int*)alloc(256 * 4);
    int* bh0  = (int*)alloc((size_t)NSL * NA * 4);
    int* bh2  = (int*)alloc((size_t)NSL * NC * 4);
    (void)ws_size; (void)in_sizes; (void)n_in; (void)out_size;

    // deg13 must be zero before prep_kernel's deg_count blocks (stream order)
    hipMemsetAsync(deg13, 0, (size_t)2 * NF * 4, stream);

    // K1: hist02 + deg_count + wsplit(x2) + wr(x2)
    prep_kernel<<<K1_WR1_END, 256, 0, stream>>>(
        dst0, dst2, bh0, bh2, aggbuf, Wf, WfTH, WfTL,
        dst1, dst3, deg1, deg3,
        root0, WtH0, WtL0, root1, WtH1, WtL1,
        basis0, comp0, wr0, basis1, comp1, wr1);

    // K2: scanA + scan02
    scan_kernel<<<197, 1024, 0, stream>>>(
        deg1, deg3, bsum, bh0, bh2, rp0, rp2, inv0, inv2);

    // scanC (standalone: produces cu1/cu3 for fill13)
    scanC_kernel<<<196, 1024, 0, stream>>>(
        deg1, deg3, bsum, rp1, rp3, cu1, cu3, inv1, inv3);

    // work: encoder + tail + csr_fill13 + fill02, all co-scheduled
    work_kernel<<<W_TOTAL, 512, 0, stream>>>(
        xf, WfTH, WfTL, bf, xa, Wa, ba, xc, Wc, bc, hH,
        src1, dst1, src3, dst3, cu1, cu3, csr1, csr3,
        src0, dst0, src2, dst2, bh0, bh2, csr0, csr2);

    // ---- layer 0: {gemm + agg + y} co-scheduled, then finishers
    constexpr int NG0 = ((NN + 127) / 128) * 2;
    layer_kernel<0><<<NG0 + AGGB + YB, 512, 0, stream>>>(
        hH, WtH0, WtL0, bias0, gH, wr0, ybuf,
        rp0, csr0, rp2, csr2, aggbuf);
    finish0_kernel<<<(NA + NC) + (NF / 2 * 64 + 255) / 256, 256, 0, stream>>>(
        aggbuf, wr0, inv0, inv2, gH,
        ybuf, rp1, csr1, inv1, rp3, csr3, inv3);

    // ---- layer 1: {gemm + y} co-scheduled, then fused readout
    constexpr int NG1 = ((NF + 127) / 128) * 2;
    layer_kernel<1><<<NG1 + YB, 512, 0, stream>>>(
        gH, WtH1, WtL1, bias1, g2H, wr1, ybuf,
        nullptr, nullptr, nullptr, nullptr, nullptr);
    msg_readout_kernel<<<(NF / 2 * 64 + 255) / 256, 256, 0, stream>>>(
        g2H, ybuf, rp1, csr1, inv1, rp3, csr3, inv3, Wout, bout, out);
}